// Round 15
// baseline (353.132 us; speedup 1.0000x reference)
//
#include <hip/hip_runtime.h>
#include <cmath>

#define BATCH 64
#define SEQL  32
#define EMBD  300
#define HIDD  500
#define NOBJ  64
#define GHID  100
#define ANSN  1000

// partition: 4 batch-groups x 25 unit-blocks
#define GRP    4
#define GBATCH 16
#define BPG    25
#define UPB8   20
#define NBLK   (GRP*BPG)   // 100
#define SLOTP  32          // slot padding in ints (128 B)
#define KPX    328         // xg-phase LDS f16 row stride

typedef _Float16 half8 __attribute__((ext_vector_type(8)));
typedef float    f32x4 __attribute__((ext_vector_type(4)));

__device__ __forceinline__ float sigmf(float x){ return 1.f/(1.f+expf(-x)); }

// sc1 (coherence-point) primitives: RELAXED agent-scope atomics, no cache-wide fences
__device__ __forceinline__ float2 ld_cc2(const unsigned long long* p){
    union { unsigned long long u; float2 f; } c;
    c.u = __hip_atomic_load(p, __ATOMIC_RELAXED, __HIP_MEMORY_SCOPE_AGENT);
    return c.f;
}
__device__ __forceinline__ void st_cc8(_Float16* p, unsigned long long v){
    __hip_atomic_store((unsigned long long*)p, v, __ATOMIC_RELAXED, __HIP_MEMORY_SCOPE_AGENT);
}

// group-local all-to-all barrier (one hop, fence-free; proven r8-r14)
__device__ __forceinline__ void gbarA(int* slots, int grp, int ub, int seq)
{
    __syncthreads();
    if (threadIdx.x == 0)
        __hip_atomic_store(slots + (grp*BPG + ub)*SLOTP, seq,
                           __ATOMIC_RELAXED, __HIP_MEMORY_SCOPE_AGENT);
    if (threadIdx.x < BPG){
        int* s = slots + (grp*BPG + threadIdx.x)*SLOTP;
        while (__hip_atomic_load(s, __ATOMIC_RELAXED, __HIP_MEMORY_SCOPE_AGENT) < seq)
            __builtin_amdgcn_s_sleep(1);
    }
    asm volatile("" ::: "memory");
    __syncthreads();
}

// ---------------- k_lstm_f: xg prologue (r12-proven) + LSTM (r14-proven) ----------------
__global__ __launch_bounds__(320, 1) void k_lstm_f(
    const int* __restrict__ sent, const float* __restrict__ table,
    const float* __restrict__ Wih, const float* __restrict__ b_ih, const float* __restrict__ b_hh,
    _Float16* __restrict__ hF, float* __restrict__ hqB, float* __restrict__ xgP,
    const float* __restrict__ Whh, const float* __restrict__ h0, const float* __restrict__ c0,
    const int* __restrict__ lens, int* __restrict__ slots)
{
    __shared__ __align__(16) char smem[119424];

    int tid = threadIdx.x, bid = blockIdx.x;
    int grp = bid / BPG, ub = bid - grp*BPG;
    int u0  = ub * UPB8;
    int w   = tid >> 6, lane = tid & 63;
    int rA  = lane & 15, kb = lane >> 4;

    // pointwise identity: 320 threads = 20 units x 16 batch
    int pb  = tid & 15, puu = tid >> 4;        // puu 0..19
    int pu  = u0 + puu;
    int gb  = grp*GBATCH + pb;
    float cprev = c0[gb*HIDD + pu];
    float hprev = h0[gb*HIDD + pu];
    int   mylen = lens[gb];
    float biasP[4];
    #pragma unroll
    for (int g = 0; g < 4; ++g) biasP[g] = b_ih[g*HIDD + pu] + b_hh[g*HIDD + pu];

    float* xgp = xgP + (size_t)bid * (80*512);   // private xg slice [80 rows][512 (t,b) cols]

    // ======== phase 1: private xg GEMM (own 80 gate-rows x group's 512 cols; r12-proven) ========
    {
        _Float16* WA = (_Float16*)smem;                 // [80][KPX]
        _Float16* SB = (_Float16*)(smem + 81920);       // [32][KPX]
        int* sidxL   = (int*)(smem + 102912);           // [512], m = t*16+bl
        for (int i = tid; i < 512; i += 320){
            int t = i >> 4, bl = i & 15;
            sidxL[i] = sent[(grp*GBATCH + bl)*SEQL + t];
        }
        for (int i = tid; i < 80*75; i += 320){
            int rl = i / 75, c4 = i - rl*75;
            int n = (rl/UPB8)*HIDD + u0 + (rl - (rl/UPB8)*UPB8);
            float4 v = *(const float4*)(Wih + (size_t)n*EMBD + c4*4);
            _Float16* d = WA + rl*KPX + c4*4;
            d[0]=(_Float16)v.x; d[1]=(_Float16)v.y; d[2]=(_Float16)v.z; d[3]=(_Float16)v.w;
        }
        for (int i = tid; i < 80*20; i += 320){
            int rl = i / 20;
            WA[rl*KPX + 300 + (i - rl*20)] = (_Float16)0.f;
        }
        __syncthreads();
        for (int ch = 0; ch < 16; ++ch){
            for (int i = tid; i < 32*75; i += 320){
                int ml = i / 75, c4 = i - ml*75;
                float4 v = *(const float4*)(table + (size_t)sidxL[ch*32+ml]*EMBD + c4*4);
                _Float16* d = SB + ml*KPX + c4*4;
                d[0]=(_Float16)v.x; d[1]=(_Float16)v.y; d[2]=(_Float16)v.z; d[3]=(_Float16)v.w;
            }
            for (int i = tid; i < 32*20; i += 320){
                int ml = i / 20;
                SB[ml*KPX + 300 + (i - ml*20)] = (_Float16)0.f;
            }
            __syncthreads();
            if (w < 4){
                for (int j = w; j < 10; j += 4){     // jobs: rt = j>>1 (5 row-tiles), mc = j&1
                    int rt = j >> 1, mc = j & 1;
                    f32x4 acc = {0.f,0.f,0.f,0.f};
                    #pragma unroll
                    for (int ks = 0; ks < 10; ++ks){
                        half8 af = *(const half8*)&WA[(rt*16 + rA)*KPX + ks*32 + kb*8];
                        half8 bf = *(const half8*)&SB[(mc*16 + rA)*KPX + ks*32 + kb*8];
                        acc = __builtin_amdgcn_mfma_f32_16x16x32_f16(af, bf, acc, 0, 0, 0);
                    }
                    #pragma unroll
                    for (int r = 0; r < 4; ++r)
                        xgp[(size_t)(rt*16 + kb*4 + r)*512 + ch*32 + mc*16 + rA] = acc[r];
                }
            }
            __syncthreads();
        }
    }

    // ======== phase 2: Whh -> Wl (swizzled), h(-1) init, pads, group barrier ========
    _Float16* Wl  = (_Float16*)smem;                 // [80*512], swizzled
    _Float16* hls = (_Float16*)(smem + 81920);       // [16*512], swizzled
    float*    gl  = (float*)(smem + 98304);          // [4*80*16]
    _Float16* hout= (_Float16*)(smem + 118784);      // [16*UPB8]

    for (int i = tid; i < 80*512; i += 320){
        int m = i >> 9, k = i & 511;
        int g = m / UPB8, uu = m - g*UPB8;
        float v = (k < HIDD) ? Whh[(size_t)(g*HIDD + u0 + uu)*HIDD + k] : 0.f;
        int off = (i*2) ^ ((m & 7) << 4);
        *(_Float16*)((char*)Wl + off) = (_Float16)v;
    }
    hout[pb*UPB8 + puu] = (_Float16)hprev;
    __syncthreads();
    if (tid < 80){
        int b = tid / 5, q = tid - (tid/5)*5;
        unsigned long long v = *(const unsigned long long*)((const char*)hout + b*40 + q*8);
        st_cc8(hF + ((size_t)(1*GRP + grp)*GBATCH + b)*512 + u0 + q*4, v);
    }
    if (ub == 0 && tid >= 128 && tid < 224){   // zero k-pad 500..511, both buffers
        int j = tid - 128;
        int buf = j / 48, r = j - buf*48;
        int b = r / 3, q = r - (r/3)*3;
        st_cc8(hF + ((size_t)(buf*GRP + grp)*GBATCH + b)*512 + 500 + q*4, 0ULL);
    }
    gbarA(slots, grp, ub, 1);

    // ======== phase 3: LSTM t-loop (r14 verbatim; xg read from private slice) ========
    for (int t = 0; t < SEQL; ++t){
        {
            const char* src = (const char*)(hF + (size_t)(((t&1)^1)*GRP + grp)*GBATCH*512);
            for (int idx = tid; idx < 2048; idx += 320){
                int o = idx*8;
                float2 v = ld_cc2((const unsigned long long*)(src + o));
                *(float2*)((char*)hls + (o ^ (((o >> 10) & 7) << 4))) = v;
            }
        }
        __syncthreads();

        if (w < 4){
            f32x4 acc[5] = {};
            half8 bf[4];
            #pragma unroll
            for (int ks4 = 0; ks4 < 4; ++ks4){
                int kByte = (w*4 + ks4)*64 + kb*16;
                int bOff  = (rA*1024 + kByte) ^ ((rA & 7) << 4);
                bf[ks4] = *(const half8*)((const char*)hls + bOff);
            }
            #pragma unroll
            for (int rt = 0; rt < 5; ++rt){
                #pragma unroll
                for (int ks4 = 0; ks4 < 4; ++ks4){
                    int kByte = (w*4 + ks4)*64 + kb*16;
                    int m = rt*16 + rA;
                    int aOff = (m*1024 + kByte) ^ ((m & 7) << 4);
                    half8 af = *(const half8*)((const char*)Wl + aOff);
                    acc[rt] = __builtin_amdgcn_mfma_f32_16x16x32_f16(af, bf[ks4], acc[rt], 0, 0, 0);
                }
            }
            #pragma unroll
            for (int rt = 0; rt < 5; ++rt)
                #pragma unroll
                for (int r = 0; r < 4; ++r)
                    gl[(w*80 + rt*16 + kb*4 + r)*16 + rA] = acc[rt][r];
        }
        __syncthreads();

        {
            float g4[4];
            #pragma unroll
            for (int g = 0; g < 4; ++g){
                int row = g*UPB8 + puu;
                float s = gl[(0*80 + row)*16 + pb] + gl[(1*80 + row)*16 + pb]
                        + gl[(2*80 + row)*16 + pb] + gl[(3*80 + row)*16 + pb];
                s += xgp[(size_t)row*512 + t*16 + pb] + biasP[g];
                g4[g] = s;
            }
            float si = sigmf(g4[0]), sf = sigmf(g4[1]);
            float tg = tanhf(g4[2]), so = sigmf(g4[3]);
            float cn = sf*cprev + si*tg;
            float hn = so*tanhf(cn);
            if (t < mylen){ cprev = cn; hprev = hn; }
            hout[pb*UPB8 + puu] = (_Float16)hprev;
            if (t == SEQL-1) hqB[(size_t)gb*512 + pu] = hprev;   // final h, [b][512] f32
        }
        if (t < SEQL-1){
            __syncthreads();
            if (tid < 80){
                int b = tid / 5, q = tid - (tid/5)*5;
                unsigned long long v = *(const unsigned long long*)((const char*)hout + b*40 + q*8);
                st_cc8(hF + ((size_t)((t&1)*GRP + grp)*GBATCH + b)*512 + u0 + q*4, v);
            }
            gbarA(slots, grp, ub, t + 2);
        }
    }
}

// ---------------- k_tail: qp + ip/jp + pair-MFMA + f1/f2 + log_softmax, one block per b (r14 verbatim) ----------------
__global__ __launch_bounds__(256, 1) void k_tail(
    const float* __restrict__ hqB, const float* __restrict__ conv,
    const float* __restrict__ g1w, const float* __restrict__ g1b,
    const float* __restrict__ g2w, const float* __restrict__ g2b,
    const float* __restrict__ f1w, const float* __restrict__ f1b,
    const float* __restrict__ f2w, const float* __restrict__ f2b,
    float* __restrict__ out)
{
    __shared__ float    convl[24][64];     //  6 KB
    __shared__ float    g1ij[100][48];     // 19.2 KB
    __shared__ float    hb[512];           //  2 KB
    __shared__ float    qpl[112];
    __shared__ float    ipl[NOBJ][104];    // 26.6 KB
    __shared__ float    jpl[NOBJ][132];    // 33.8 KB
    __shared__ float    basel[16][132];    //  8.4 KB
    __shared__ _Float16 g2h[112][136];     // 30.5 KB
    __shared__ float    redx[4][112];
    __shared__ float    gs[112], fh[112];
    __shared__ float    lg[ANSN];          //  4 KB
    __shared__ float    red[4], red2[4];

    int b = blockIdx.x, tid = threadIdx.x;
    int w = tid >> 6, lane = tid & 63;
    int ncol = lane & 15, kb = lane >> 4;

    for (int i = tid; i < 24*64; i += 256)
        convl[i>>6][i&63] = conv[((size_t)b*24 + (i>>6))*64 + (i&63)];
    for (int i = tid; i < 100*48; i += 256){
        int n = i/48, c = i - (i/48)*48;
        g1ij[n][c] = g1w[(size_t)n*548 + 500 + c];
    }
    for (int i = tid; i < 512; i += 256) hb[i] = hqB[(size_t)b*512 + i];
    for (int i = tid; i < 112*136; i += 256){
        int n = i/136, k = i - (i/136)*136;
        g2h[n][k] = (n < 100 && k < 100) ? (_Float16)g2w[n*GHID + k] : (_Float16)0.f;
    }
    __syncthreads();

    if (tid < 100){
        const float4* wr = (const float4*)(g1w + (size_t)tid*548);
        float s = g1b[tid];
        #pragma unroll 5
        for (int k4 = 0; k4 < 125; ++k4){
            float4 v = wr[k4];
            s += v.x*hb[k4*4] + v.y*hb[k4*4+1] + v.z*hb[k4*4+2] + v.w*hb[k4*4+3];
        }
        qpl[tid] = s;
    }
    for (int i = tid; i < NOBJ*100; i += 256){
        int o = i / 100, n = i - (i/100)*100;
        float sj = 0.f, si = 0.f;
        #pragma unroll
        for (int c = 0; c < 24; ++c){
            float v = convl[c][o];
            sj += v * g1ij[n][c];
            si += v * g1ij[n][24+c];
        }
        ipl[o][n] = si;
        jpl[o][n] = sj;
    }
    for (int i = tid; i < NOBJ*32; i += 256) jpl[i>>5][100 + (i&31)] = 0.f;

    float gb7[7];
    #pragma unroll
    for (int nt = 0; nt < 7; ++nt){
        int n = nt*16 + ncol;
        gb7[nt] = (n < 100) ? g2b[n] : 0.f;
    }

    f32x4 sacc[7] = {};
    for (int ic = 0; ic < 4; ++ic){
        __syncthreads();
        for (int i = tid; i < 16*132; i += 256){
            int il = i / 132, k = i - (i/132)*132;
            basel[il][k] = (k < 100) ? qpl[k] + ipl[ic*16 + il][k] : 0.f;
        }
        __syncthreads();
        #pragma unroll
        for (int it = 0; it < 4; ++it){
            int il = w*4 + it;
            #pragma unroll
            for (int jc = 0; jc < 4; ++jc){
                f32x4 acc[7] = {};
                int jrow = jc*16 + ncol;
                #pragma unroll
                for (int ks = 0; ks < 4; ++ks){
                    int k0 = ks*32 + kb*8;
                    const float* jpp = &jpl[jrow][k0];
                    const float* bpp = &basel[il][k0];
                    half8 af;
                    #pragma unroll
                    for (int e = 0; e < 8; ++e)
                        af[e] = (_Float16)fmaxf(jpp[e] + bpp[e], 0.f);
                    #pragma unroll
                    for (int nt = 0; nt < 7; ++nt){
                        half8 bf = *(const half8*)&g2h[nt*16 + ncol][k0];
                        acc[nt] = __builtin_amdgcn_mfma_f32_16x16x32_f16(af, bf, acc[nt], 0, 0, 0);
                    }
                }
                #pragma unroll
                for (int nt = 0; nt < 7; ++nt)
                    #pragma unroll
                    for (int r = 0; r < 4; ++r)
                        sacc[nt][r] += fmaxf(acc[nt][r] + gb7[nt], 0.f);
            }
        }
    }
    #pragma unroll
    for (int nt = 0; nt < 7; ++nt){
        float s = sacc[nt][0] + sacc[nt][1] + sacc[nt][2] + sacc[nt][3];
        s += __shfl_xor(s, 16);
        s += __shfl_xor(s, 32);
        if (lane < 16) redx[w][nt*16 + lane] = s;
    }
    __syncthreads();
    if (tid < 100) gs[tid] = redx[0][tid] + redx[1][tid] + redx[2][tid] + redx[3][tid];
    __syncthreads();

    if (tid < 100){
        const float4* wr = (const float4*)(f1w + (size_t)tid*GHID);
        float s = f1b[tid];
        #pragma unroll 5
        for (int k4 = 0; k4 < 25; ++k4){
            float4 v = wr[k4];
            s += v.x*gs[k4*4] + v.y*gs[k4*4+1] + v.z*gs[k4*4+2] + v.w*gs[k4*4+3];
        }
        fh[tid] = fmaxf(s, 0.f);
    }
    __syncthreads();

    for (int n = tid; n < ANSN; n += 256){
        const float4* wr = (const float4*)(f2w + (size_t)n*GHID);
        float s = f2b[n];
        #pragma unroll 5
        for (int k4 = 0; k4 < 25; ++k4){
            float4 v = wr[k4];
            s += v.x*fh[k4*4] + v.y*fh[k4*4+1] + v.z*fh[k4*4+2] + v.w*fh[k4*4+3];
        }
        lg[n] = fmaxf(s, 0.f);
    }
    __syncthreads();
    float mx = -1e30f;
    for (int n = tid; n < ANSN; n += 256) mx = fmaxf(mx, lg[n]);
    #pragma unroll
    for (int off = 32; off > 0; off >>= 1) mx = fmaxf(mx, __shfl_xor(mx, off));
    if ((tid & 63) == 0) red[tid >> 6] = mx;
    __syncthreads();
    mx = fmaxf(fmaxf(red[0], red[1]), fmaxf(red[2], red[3]));
    float se = 0.f;
    for (int n = tid; n < ANSN; n += 256) se += expf(lg[n]-mx);
    #pragma unroll
    for (int off = 32; off > 0; off >>= 1) se += __shfl_xor(se, off);
    if ((tid & 63) == 0) red2[tid >> 6] = se;
    __syncthreads();
    se = red2[0]+red2[1]+red2[2]+red2[3];
    float lse = logf(se);
    for (int n = tid; n < ANSN; n += 256) out[(size_t)b*ANSN + n] = lg[n] - mx - lse;
}

extern "C" void kernel_launch(void* const* d_in, const int* in_sizes, int n_in,
                              void* d_out, int out_size, void* d_ws, size_t ws_size,
                              hipStream_t stream)
{
    const int*   sent  = (const int*)  d_in[0];
    const float* conv  = (const float*)d_in[1];
    const int*   lens  = (const int*)  d_in[2];
    const float* table = (const float*)d_in[3];
    const float* W_ih  = (const float*)d_in[4];
    const float* W_hh  = (const float*)d_in[5];
    const float* b_ih  = (const float*)d_in[6];
    const float* b_hh  = (const float*)d_in[7];
    const float* h0    = (const float*)d_in[8];
    const float* c0    = (const float*)d_in[9];
    const float* g1_w  = (const float*)d_in[10];
    const float* g1_b  = (const float*)d_in[11];
    const float* g2_w  = (const float*)d_in[12];
    const float* g2_b  = (const float*)d_in[13];
    const float* f1_w  = (const float*)d_in[14];
    const float* f1_b  = (const float*)d_in[15];
    const float* f2_w  = (const float*)d_in[16];
    const float* f2_b  = (const float*)d_in[17];
    float* out = (float*)d_out;

    float* ws   = (float*)d_ws;
    int*   slots= (int*)d_ws;                          // 100 slots * 32 ints
    _Float16* hF = (_Float16*)(ws + 16384);            // 2*4*16*512 f16 = 128 KB
    float* hqB  = ws + 16384 + 32768;                  // 64*512 f32
    float* xgP  = hqB + 64*512;                        // 100 * 80*512 f32 = 16.4 MB

    // 0. zero barrier slots (deterministic across graph replays)
    hipMemsetAsync(slots, 0, NBLK*SLOTP*sizeof(int), stream);

    // 1. fused xg + LSTM, regular launch (100 blocks, 1/CU -> co-resident)
    k_lstm_f<<<NBLK, 320, 0, stream>>>(sent, table, W_ih, b_ih, b_hh,
                                       hF, hqB, xgP, W_hh, h0, c0, lens, slots);

    // 2. fused tail: qp/ipjp + pair MFMA + f1/f2 + log_softmax
    k_tail<<<BATCH, 256, 0, stream>>>(hqB, conv, g1_w, g1_b, g2_w, g2_b,
                                      f1_w, f1_b, f2_w, f2_b, out);
}

// Round 16
// 302.989 us; speedup vs baseline: 1.1655x; 1.1655x over previous
//
#include <hip/hip_runtime.h>
#include <cmath>

#define BATCH 64
#define SEQL  32
#define EMBD  300
#define HIDD  500
#define NOBJ  64
#define GHID  100
#define ANSN  1000
#define MCOL  2048   // t*64+b column dimension

// partition: 4 batch-groups x 25 unit-blocks
#define GRP    4
#define GBATCH 16
#define BPG    25
#define UPB8   20
#define NBLK   (GRP*BPG)   // 100
#define SLOTP  32          // slot padding in ints (128 B)

#define KPADX  328         // xg LDS row stride in f16 (656 B)
#define TCH    4           // timesteps per xg block

typedef _Float16 half8 __attribute__((ext_vector_type(8)));
typedef float    f32x4 __attribute__((ext_vector_type(4)));

__device__ __forceinline__ float sigmf(float x){ return 1.f/(1.f+expf(-x)); }

// sc1 (coherence-point) primitives: RELAXED agent-scope atomics, no cache-wide fences
__device__ __forceinline__ float2 ld_cc2(const unsigned long long* p){
    union { unsigned long long u; float2 f; } c;
    c.u = __hip_atomic_load(p, __ATOMIC_RELAXED, __HIP_MEMORY_SCOPE_AGENT);
    return c.f;
}
__device__ __forceinline__ void st_cc8(_Float16* p, unsigned long long v){
    __hip_atomic_store((unsigned long long*)p, v, __ATOMIC_RELAXED, __HIP_MEMORY_SCOPE_AGENT);
}

// ---------------- k_xg2: xgT = W_ih @ emb + bias (MFMA f16, r14-proven) + slot zeroing ----------------
__global__ __launch_bounds__(256, 1) void k_xg2(
    const int* __restrict__ sent, const float* __restrict__ table,
    const float* __restrict__ Wih, const float* __restrict__ b_ih,
    const float* __restrict__ b_hh, float* __restrict__ xgT, int* __restrict__ slots)
{
    __shared__ _Float16 Sh[64*KPADX];   // 41984 B, A then B
    __shared__ int sidx[TCH][64];
    int tid = threadIdx.x;
    int tc = blockIdx.x;                // t-chunk (0..7)
    int n0 = blockIdx.y * 64;
    int w = tid >> 6, lane = tid & 63;
    int rA = lane & 15, kb = lane >> 4;

    // zero barrier slots for the following kernel (fresh every launch/replay)
    if (tc == 0 && blockIdx.y == 0 && tid < NBLK)
        __hip_atomic_store(slots + tid*SLOTP, 0, __ATOMIC_RELAXED, __HIP_MEMORY_SCOPE_AGENT);

    for (int i = tid; i < TCH*64; i += 256){
        int tt = i >> 6, b = i & 63;
        sidx[tt][b] = sent[b*SEQL + tc*TCH + tt];
    }
    for (int i = tid; i < 64*75; i += 256){
        int n = i / 75, c4 = i - (i/75)*75;
        float4 v = {0.f,0.f,0.f,0.f};
        if (n0 + n < 2000)
            v = *(const float4*)(Wih + (size_t)(n0+n)*300 + c4*4);
        _Float16* dst = &Sh[n*KPADX + c4*4];
        dst[0]=(_Float16)v.x; dst[1]=(_Float16)v.y; dst[2]=(_Float16)v.z; dst[3]=(_Float16)v.w;
    }
    for (int i = tid; i < 64*20; i += 256){   // zero pad k 300..319
        int n = i / 20, k = 300 + (i - (i/20)*20);
        Sh[n*KPADX + k] = (_Float16)0.f;
    }
    __syncthreads();
    half8 areg[10];
    #pragma unroll
    for (int ks = 0; ks < 10; ++ks)
        areg[ks] = *(const half8*)&Sh[(w*16 + rA)*KPADX + ks*32 + kb*8];
    float biasr[4];
    #pragma unroll
    for (int r = 0; r < 4; ++r){
        int n = n0 + w*16 + kb*4 + r;
        biasr[r] = (n < 2000) ? b_ih[n] + b_hh[n] : 0.f;
    }
    __syncthreads();   // all A reads done before B overwrites Sh

    for (int tt = 0; tt < TCH; ++tt){
        for (int i = tid; i < 64*75; i += 256){
            int m = i / 75, c4 = i - (i/75)*75;
            float4 v = *(const float4*)(table + (size_t)sidx[tt][m]*300 + c4*4);
            _Float16* dst = &Sh[m*KPADX + c4*4];
            dst[0]=(_Float16)v.x; dst[1]=(_Float16)v.y; dst[2]=(_Float16)v.z; dst[3]=(_Float16)v.w;
        }
        for (int i = tid; i < 64*20; i += 256){
            int m = i / 20, k = 300 + (i - (i/20)*20);
            Sh[m*KPADX + k] = (_Float16)0.f;
        }
        __syncthreads();

        f32x4 acc[4] = {};
        #pragma unroll
        for (int ks = 0; ks < 10; ++ks){
            #pragma unroll
            for (int mc = 0; mc < 4; ++mc){
                half8 bf = *(const half8*)&Sh[(mc*16 + rA)*KPADX + ks*32 + kb*8];
                acc[mc] = __builtin_amdgcn_mfma_f32_16x16x32_f16(areg[ks], bf, acc[mc], 0, 0, 0);
            }
        }
        #pragma unroll
        for (int r = 0; r < 4; ++r){
            int n = n0 + w*16 + kb*4 + r;
            if (n < 2000){
                #pragma unroll
                for (int mc = 0; mc < 4; ++mc)
                    xgT[(size_t)n*MCOL + (tc*TCH+tt)*64 + mc*16 + rA] = acc[mc][r] + biasr[r];
            }
        }
        __syncthreads();
    }
}

// group-local all-to-all barrier (one hop, fence-free; proven r8-r15)
__device__ __forceinline__ void gbarA(int* slots, int grp, int ub, int seq)
{
    __syncthreads();
    if (threadIdx.x == 0)
        __hip_atomic_store(slots + (grp*BPG + ub)*SLOTP, seq,
                           __ATOMIC_RELAXED, __HIP_MEMORY_SCOPE_AGENT);
    if (threadIdx.x < BPG){
        int* s = slots + (grp*BPG + threadIdx.x)*SLOTP;
        while (__hip_atomic_load(s, __ATOMIC_RELAXED, __HIP_MEMORY_SCOPE_AGENT) < seq)
            __builtin_amdgcn_s_sleep(1);
    }
    asm volatile("" ::: "memory");
    __syncthreads();
}

// ---------------- LSTM v8: MFMA f16, batch-grouped, sc1 h exchange (r14 verbatim) ----------------
__global__ __launch_bounds__(320, 1) void k_lstm_v8(
    _Float16* __restrict__ hF, float* __restrict__ hqB,
    const float* __restrict__ xgT, const float* __restrict__ Whh,
    const float* __restrict__ h0, const float* __restrict__ c0,
    const int* __restrict__ lens, int* __restrict__ slots)
{
    __shared__ _Float16 Wl[80*512];    // 80 KB
    __shared__ _Float16 hls[16*512];   // 16 KB
    __shared__ float    gl[4*80*16];   // 20 KB
    __shared__ _Float16 hout[16*UPB8]; // 640 B

    int tid = threadIdx.x, bid = blockIdx.x;
    int grp = bid / BPG, ub = bid - grp*BPG;
    int u0  = ub * UPB8;
    int w   = tid >> 6, lane = tid & 63;

    int pb  = tid & 15, puu = tid >> 4;        // puu 0..19
    int pu  = u0 + puu;
    int gb  = grp*GBATCH + pb;                 // global batch row
    float cprev = c0[gb*HIDD + pu];
    float hprev = h0[gb*HIDD + pu];
    int   mylen = lens[gb];
    hout[pb*UPB8 + puu] = (_Float16)hprev;

    for (int i = tid; i < 80*512; i += 320){
        int m = i >> 9, k = i & 511;
        int g = m / UPB8, uu = m - g*UPB8;
        float v = (k < HIDD) ? Whh[(size_t)(g*HIDD + u0 + uu)*HIDD + k] : 0.f;
        int off = (i*2) ^ ((m & 7) << 4);
        *(_Float16*)((char*)Wl + off) = (_Float16)v;
    }
    __syncthreads();
    if (tid < 80){
        int b = tid / 5, q = tid - (tid/5)*5;
        unsigned long long v = *(const unsigned long long*)((const char*)hout + b*40 + q*8);
        st_cc8(hF + ((size_t)(1*GRP + grp)*GBATCH + b)*512 + u0 + q*4, v);
    }
    if (ub == 0 && tid >= 128 && tid < 224){   // zero k-pad 500..511, both buffers
        int j = tid - 128;
        int buf = j / 48, r = j - buf*48;
        int b = r / 3, q = r - (r/3)*3;
        st_cc8(hF + ((size_t)(buf*GRP + grp)*GBATCH + b)*512 + 500 + q*4, 0ULL);
    }
    gbarA(slots, grp, ub, 1);

    const int mA = lane & 15, kb = lane >> 4;

    for (int t = 0; t < SEQL; ++t){
        {
            const char* src = (const char*)(hF + (size_t)(((t&1)^1)*GRP + grp)*GBATCH*512);
            for (int idx = tid; idx < 2048; idx += 320){
                int o = idx*8;
                float2 v = ld_cc2((const unsigned long long*)(src + o));
                *(float2*)((char*)hls + (o ^ (((o >> 10) & 7) << 4))) = v;
            }
        }
        __syncthreads();

        if (w < 4){
            f32x4 acc[5] = {};
            half8 bf[4];
            #pragma unroll
            for (int ks4 = 0; ks4 < 4; ++ks4){
                int kByte = (w*4 + ks4)*64 + kb*16;
                int bOff  = (mA*1024 + kByte) ^ ((mA & 7) << 4);
                bf[ks4] = *(const half8*)((const char*)hls + bOff);
            }
            #pragma unroll
            for (int rt = 0; rt < 5; ++rt){
                #pragma unroll
                for (int ks4 = 0; ks4 < 4; ++ks4){
                    int kByte = (w*4 + ks4)*64 + kb*16;
                    int m = rt*16 + mA;
                    int aOff = (m*1024 + kByte) ^ ((m & 7) << 4);
                    half8 af = *(const half8*)((const char*)Wl + aOff);
                    acc[rt] = __builtin_amdgcn_mfma_f32_16x16x32_f16(af, bf[ks4], acc[rt], 0, 0, 0);
                }
            }
            #pragma unroll
            for (int rt = 0; rt < 5; ++rt)
                #pragma unroll
                for (int r = 0; r < 4; ++r)
                    gl[(w*80 + rt*16 + kb*4 + r)*16 + mA] = acc[rt][r];
        }
        __syncthreads();

        {
            float g4[4];
            #pragma unroll
            for (int g = 0; g < 4; ++g){
                int row = g*UPB8 + puu;
                float s = gl[(0*80 + row)*16 + pb] + gl[(1*80 + row)*16 + pb]
                        + gl[(2*80 + row)*16 + pb] + gl[(3*80 + row)*16 + pb];
                s += xgT[(size_t)(g*HIDD + pu)*MCOL + t*64 + gb];
                g4[g] = s;
            }
            float si = sigmf(g4[0]), sf = sigmf(g4[1]);
            float tg = tanhf(g4[2]), so = sigmf(g4[3]);
            float cn = sf*cprev + si*tg;
            float hn = so*tanhf(cn);
            if (t < mylen){ cprev = cn; hprev = hn; }
            hout[pb*UPB8 + puu] = (_Float16)hprev;
            if (t == SEQL-1) hqB[(size_t)gb*512 + pu] = hprev;   // final h, [b][512] f32
        }
        if (t < SEQL-1){
            __syncthreads();
            if (tid < 80){
                int b = tid / 5, q = tid - (tid/5)*5;
                unsigned long long v = *(const unsigned long long*)((const char*)hout + b*40 + q*8);
                st_cc8(hF + ((size_t)((t&1)*GRP + grp)*GBATCH + b)*512 + u0 + q*4, v);
            }
            gbarA(slots, grp, ub, t + 2);
        }
    }
}

// ---------------- q_part: qp[b][n] = sum_k hqB[b][k]*g1w[n][k] + g1b[n] ----------------
__global__ void k_qp(const float* __restrict__ hqB, const float* __restrict__ g1w,
                     const float* __restrict__ g1b, float* __restrict__ qp)
{
    int idx = blockIdx.x*blockDim.x + threadIdx.x;
    if (idx >= BATCH*GHID) return;
    int b = idx / GHID, n = idx % GHID;
    const float* wr = g1w + n*548;
    const float* hb = hqB + (size_t)b*512;
    float s = g1b[n];
    for (int k = 0; k < HIDD; ++k) s += hb[k]*wr[k];
    qp[idx] = s;
}

// ---------------- i_part/j_part (r9 verbatim) ----------------
__global__ void k_ipjp(const float* __restrict__ conv, const float* __restrict__ g1w,
                       float* __restrict__ ip, float* __restrict__ jp)
{
    int idx = blockIdx.x*blockDim.x + threadIdx.x;
    if (idx >= BATCH*NOBJ*GHID) return;
    int b = idx / (NOBJ*GHID);
    int rem = idx - b*(NOBJ*GHID);
    int o = rem / GHID, n = rem % GHID;
    const float* wj = g1w + n*548 + 500;
    const float* wi = g1w + n*548 + 524;
    float si = 0.f, sj = 0.f;
    #pragma unroll
    for (int c = 0; c < 24; ++c){
        float v = conv[((size_t)b*24 + c)*NOBJ + o];
        sj += v*wj[c];
        si += v*wi[c];
    }
    ip[idx] = si;
    jp[idx] = sj;
}

// ---------------- MFMA pair kernel (r9 verbatim): grid 256 = b(64) x ic(4) ----------------
__global__ __launch_bounds__(256, 1) void k_pair_mfma(
    const float* __restrict__ qp, const float* __restrict__ ip,
    const float* __restrict__ jp, const float* __restrict__ g2w,
    const float* __restrict__ g2b, float* __restrict__ part)
{
    __shared__ float    jpl[NOBJ][132];     // 33792 B
    __shared__ float    basel[16][132];     //  8448 B
    __shared__ _Float16 g2h[112][136];      // 30464 B
    __shared__ float    redx[4][112];       //  1792 B

    int b  = blockIdx.x >> 2;
    int ic = blockIdx.x & 3;
    int tid = threadIdx.x;
    int w = tid >> 6, lane = tid & 63;
    int ncol = lane & 15, kb = lane >> 4;

    for (int i = tid; i < NOBJ*100; i += 256){
        int j = i / 100, k = i - (i/100)*100;
        jpl[j][k] = jp[((size_t)b*NOBJ + j)*GHID + k];
    }
    for (int i = tid; i < NOBJ*32; i += 256)
        jpl[i >> 5][100 + (i & 31)] = 0.f;
    for (int i = tid; i < 16*100; i += 256){
        int il = i / 100, k = i - (i/100)*100;
        basel[il][k] = qp[b*GHID + k] + ip[((size_t)b*NOBJ + ic*16 + il)*GHID + k];
    }
    for (int i = tid; i < 16*32; i += 256)
        basel[i >> 5][100 + (i & 31)] = 0.f;
    for (int i = tid; i < 112*136; i += 256){
        int n = i / 136, k = i - (i/136)*136;
        g2h[n][k] = (n < 100 && k < 100) ? (_Float16)g2w[n*GHID + k] : (_Float16)0.f;
    }
    float gb7[7];
    #pragma unroll
    for (int nt = 0; nt < 7; ++nt){
        int n = nt*16 + ncol;
        gb7[nt] = (n < 100) ? g2b[n] : 0.f;
    }
    __syncthreads();

    f32x4 sacc[7] = {};
    #pragma unroll
    for (int it = 0; it < 4; ++it){
        int il = w*4 + it;
        #pragma unroll
        for (int jc = 0; jc < 4; ++jc){
            f32x4 acc[7] = {};
            int jrow = jc*16 + ncol;
            #pragma unroll
            for (int ks = 0; ks < 4; ++ks){
                int k0 = ks*32 + kb*8;
                const float* jpp = &jpl[jrow][k0];
                const float* bpp = &basel[il][k0];
                half8 af;
                #pragma unroll
                for (int e = 0; e < 8; ++e)
                    af[e] = (_Float16)fmaxf(jpp[e] + bpp[e], 0.f);
                #pragma unroll
                for (int nt = 0; nt < 7; ++nt){
                    half8 bf = *(const half8*)&g2h[nt*16 + ncol][k0];
                    acc[nt] = __builtin_amdgcn_mfma_f32_16x16x32_f16(af, bf, acc[nt], 0, 0, 0);
                }
            }
            #pragma unroll
            for (int nt = 0; nt < 7; ++nt)
                #pragma unroll
                for (int r = 0; r < 4; ++r)
                    sacc[nt][r] += fmaxf(acc[nt][r] + gb7[nt], 0.f);
        }
    }
    #pragma unroll
    for (int nt = 0; nt < 7; ++nt){
        float s = sacc[nt][0] + sacc[nt][1] + sacc[nt][2] + sacc[nt][3];
        s += __shfl_xor(s, 16);
        s += __shfl_xor(s, 32);
        if (lane < 16) redx[w][nt*16 + lane] = s;
    }
    __syncthreads();
    if (tid < 100){
        float p = redx[0][tid] + redx[1][tid] + redx[2][tid] + redx[3][tid];
        part[(size_t)(b*4 + ic)*GHID + tid] = p;
    }
}

// ---------------- final: reduce partials, f1, f2, log_softmax (r9 verbatim) ----------------
__global__ __launch_bounds__(256) void k_final(const float* __restrict__ part, const float* __restrict__ f1w,
               const float* __restrict__ f1b, const float* __restrict__ f2w,
               const float* __restrict__ f2b, float* __restrict__ out)
{
    int b = blockIdx.x;
    int tid = threadIdx.x;
    __shared__ float gs[GHID];
    __shared__ float fh[GHID];
    __shared__ float lg[ANSN];
    __shared__ float red[4], red2[4];
    if (tid < GHID){
        float s = 0.f;
        for (int ic = 0; ic < 4; ++ic) s += part[((size_t)b*4 + ic)*GHID + tid];
        gs[tid] = s;
    }
    __syncthreads();
    if (tid < GHID){
        float s = f1b[tid];
        const float* w = f1w + tid*GHID;
        for (int k = 0; k < GHID; ++k) s += gs[k]*w[k];
        fh[tid] = fmaxf(s, 0.f);
    }
    __syncthreads();
    for (int n = tid; n < ANSN; n += 256){
        float s = f2b[n];
        const float* w = f2w + (size_t)n*GHID;
        for (int k = 0; k < GHID; ++k) s += fh[k]*w[k];
        lg[n] = fmaxf(s, 0.f);
    }
    __syncthreads();
    float mx = -1e30f;
    for (int n = tid; n < ANSN; n += 256) mx = fmaxf(mx, lg[n]);
    #pragma unroll
    for (int off = 32; off > 0; off >>= 1) mx = fmaxf(mx, __shfl_xor(mx, off));
    if ((tid & 63) == 0) red[tid >> 6] = mx;
    __syncthreads();
    mx = fmaxf(fmaxf(red[0], red[1]), fmaxf(red[2], red[3]));
    float se = 0.f;
    for (int n = tid; n < ANSN; n += 256) se += expf(lg[n]-mx);
    #pragma unroll
    for (int off = 32; off > 0; off >>= 1) se += __shfl_xor(se, off);
    if ((tid & 63) == 0) red2[tid >> 6] = se;
    __syncthreads();
    se = red2[0]+red2[1]+red2[2]+red2[3];
    float lse = logf(se);
    for (int n = tid; n < ANSN; n += 256) out[(size_t)b*ANSN + n] = lg[n] - mx - lse;
}

extern "C" void kernel_launch(void* const* d_in, const int* in_sizes, int n_in,
                              void* d_out, int out_size, void* d_ws, size_t ws_size,
                              hipStream_t stream)
{
    const int*   sent  = (const int*)  d_in[0];
    const float* conv  = (const float*)d_in[1];
    const int*   lens  = (const int*)  d_in[2];
    const float* table = (const float*)d_in[3];
    const float* W_ih  = (const float*)d_in[4];
    const float* W_hh  = (const float*)d_in[5];
    const float* b_ih  = (const float*)d_in[6];
    const float* b_hh  = (const float*)d_in[7];
    const float* h0    = (const float*)d_in[8];
    const float* c0    = (const float*)d_in[9];
    const float* g1_w  = (const float*)d_in[10];
    const float* g1_b  = (const float*)d_in[11];
    const float* g2_w  = (const float*)d_in[12];
    const float* g2_b  = (const float*)d_in[13];
    const float* f1_w  = (const float*)d_in[14];
    const float* f1_b  = (const float*)d_in[15];
    const float* f2_w  = (const float*)d_in[16];
    const float* f2_b  = (const float*)d_in[17];
    float* out = (float*)d_out;

    float* ws   = (float*)d_ws;
    int*   slots= (int*)d_ws;                          // 100 slots * 32 ints (64 KB region)
    _Float16* hF = (_Float16*)(ws + 16384);            // 2*4*16*512 f16 = 128 KB
    float* hqB  = ws + 16384 + 32768;                  // 64*512 f32
    float* xgT  = hqB + 64*512;                        // 2000*2048 f32
    float* qp   = xgT + (size_t)4*HIDD*MCOL;           // 64*100
    float* ip   = qp  + BATCH*GHID;                    // 64*64*100
    float* jp   = ip  + BATCH*NOBJ*GHID;
    float* part = jp  + BATCH*NOBJ*GHID;               // 256*100

    // 1. xgT = W_ih @ emb + bias (MFMA f16) — also zeroes barrier slots for kernel 2
    {
        dim3 g(SEQL/TCH, 32);   // x = t-chunk, y = n-tile
        k_xg2<<<g, 256, 0, stream>>>(sent, table, W_ih, b_ih, b_hh, xgT, slots);
    }

    // 2. MFMA LSTM, regular launch (100 blocks, 1/CU -> trivially co-resident)
    k_lstm_v8<<<NBLK, 320, 0, stream>>>(hF, hqB, xgT, W_hh, h0, c0, lens, slots);

    // 3. g_mlp layer-1 partials
    k_qp<<<(BATCH*GHID + 255)/256, 256, 0, stream>>>(hqB, g1_w, g1_b, qp);
    k_ipjp<<<(BATCH*NOBJ*GHID + 255)/256, 256, 0, stream>>>(conv, g1_w, ip, jp);

    // 4. MFMA pair kernel (256 blocks) -> part[256][100]
    k_pair_mfma<<<BATCH*4, 256, 0, stream>>>(qp, ip, jp, g2_w, g2_b, part);

    // 5. final MLP + log_softmax
    k_final<<<BATCH, 256, 0, stream>>>(part, f1_w, f1_b, f2_w, f2_b, out);
}

// Round 17
// 262.398 us; speedup vs baseline: 1.3458x; 1.1547x over previous
//
#include <hip/hip_runtime.h>
#include <cmath>

#define BATCH 64
#define SEQL  32
#define EMBD  300
#define HIDD  500
#define NOBJ  64
#define GHID  100
#define ANSN  1000
#define MCOL  2048   // t*64+b column dimension

// partition: 4 batch-groups x 25 unit-blocks
#define GRP    4
#define GBATCH 16
#define BPG    25
#define UPB8   20
#define NBLK   (GRP*BPG)   // 100
#define SLOTP  32          // slot padding in ints (128 B)

#define KPADX  328         // xg LDS row stride in f16 (656 B)
#define TCH    4           // timesteps per xg block

typedef _Float16 half8 __attribute__((ext_vector_type(8)));
typedef float    f32x4 __attribute__((ext_vector_type(4)));

__device__ __forceinline__ float sigmf(float x){ return 1.f/(1.f+expf(-x)); }

// sc1 (coherence-point) primitives: RELAXED agent-scope atomics, no cache-wide fences
__device__ __forceinline__ unsigned long long ld_cc8(const unsigned long long* p){
    return __hip_atomic_load(p, __ATOMIC_RELAXED, __HIP_MEMORY_SCOPE_AGENT);
}
__device__ __forceinline__ void st_cc8(_Float16* p, unsigned long long v){
    __hip_atomic_store((unsigned long long*)p, v, __ATOMIC_RELAXED, __HIP_MEMORY_SCOPE_AGENT);
}

// ---------------- k_xg2: xgT = W_ih @ emb + bias (MFMA f16, r14-proven) + slot zeroing ----------------
__global__ __launch_bounds__(256, 1) void k_xg2(
    const int* __restrict__ sent, const float* __restrict__ table,
    const float* __restrict__ Wih, const float* __restrict__ b_ih,
    const float* __restrict__ b_hh, float* __restrict__ xgT, int* __restrict__ slots)
{
    __shared__ _Float16 Sh[64*KPADX];   // 41984 B, A then B
    __shared__ int sidx[TCH][64];
    int tid = threadIdx.x;
    int tc = blockIdx.x;                // t-chunk (0..7)
    int n0 = blockIdx.y * 64;
    int w = tid >> 6, lane = tid & 63;
    int rA = lane & 15, kb = lane >> 4;

    // zero barrier slots for the following kernel (fresh every launch/replay)
    if (tc == 0 && blockIdx.y == 0 && tid < NBLK)
        __hip_atomic_store(slots + tid*SLOTP, 0, __ATOMIC_RELAXED, __HIP_MEMORY_SCOPE_AGENT);

    for (int i = tid; i < TCH*64; i += 256){
        int tt = i >> 6, b = i & 63;
        sidx[tt][b] = sent[b*SEQL + tc*TCH + tt];
    }
    for (int i = tid; i < 64*75; i += 256){
        int n = i / 75, c4 = i - (i/75)*75;
        float4 v = {0.f,0.f,0.f,0.f};
        if (n0 + n < 2000)
            v = *(const float4*)(Wih + (size_t)(n0+n)*300 + c4*4);
        _Float16* dst = &Sh[n*KPADX + c4*4];
        dst[0]=(_Float16)v.x; dst[1]=(_Float16)v.y; dst[2]=(_Float16)v.z; dst[3]=(_Float16)v.w;
    }
    for (int i = tid; i < 64*20; i += 256){   // zero pad k 300..319
        int n = i / 20, k = 300 + (i - (i/20)*20);
        Sh[n*KPADX + k] = (_Float16)0.f;
    }
    __syncthreads();
    half8 areg[10];
    #pragma unroll
    for (int ks = 0; ks < 10; ++ks)
        areg[ks] = *(const half8*)&Sh[(w*16 + rA)*KPADX + ks*32 + kb*8];
    float biasr[4];
    #pragma unroll
    for (int r = 0; r < 4; ++r){
        int n = n0 + w*16 + kb*4 + r;
        biasr[r] = (n < 2000) ? b_ih[n] + b_hh[n] : 0.f;
    }
    __syncthreads();   // all A reads done before B overwrites Sh

    for (int tt = 0; tt < TCH; ++tt){
        for (int i = tid; i < 64*75; i += 256){
            int m = i / 75, c4 = i - (i/75)*75;
            float4 v = *(const float4*)(table + (size_t)sidx[tt][m]*300 + c4*4);
            _Float16* dst = &Sh[m*KPADX + c4*4];
            dst[0]=(_Float16)v.x; dst[1]=(_Float16)v.y; dst[2]=(_Float16)v.z; dst[3]=(_Float16)v.w;
        }
        for (int i = tid; i < 64*20; i += 256){
            int m = i / 20, k = 300 + (i - (i/20)*20);
            Sh[m*KPADX + k] = (_Float16)0.f;
        }
        __syncthreads();

        f32x4 acc[4] = {};
        #pragma unroll
        for (int ks = 0; ks < 10; ++ks){
            #pragma unroll
            for (int mc = 0; mc < 4; ++mc){
                half8 bf = *(const half8*)&Sh[(mc*16 + rA)*KPADX + ks*32 + kb*8];
                acc[mc] = __builtin_amdgcn_mfma_f32_16x16x32_f16(areg[ks], bf, acc[mc], 0, 0, 0);
            }
        }
        #pragma unroll
        for (int r = 0; r < 4; ++r){
            int n = n0 + w*16 + kb*4 + r;
            if (n < 2000){
                #pragma unroll
                for (int mc = 0; mc < 4; ++mc)
                    xgT[(size_t)n*MCOL + (tc*TCH+tt)*64 + mc*16 + rA] = acc[mc][r] + biasr[r];
            }
        }
        __syncthreads();
    }
}

// group-local all-to-all barrier (one hop, fence-free; proven r8-r16)
__device__ __forceinline__ void gbarA(int* slots, int grp, int ub, int seq)
{
    __syncthreads();
    if (threadIdx.x == 0)
        __hip_atomic_store(slots + (grp*BPG + ub)*SLOTP, seq,
                           __ATOMIC_RELAXED, __HIP_MEMORY_SCOPE_AGENT);
    if (threadIdx.x < BPG){
        int* s = slots + (grp*BPG + threadIdx.x)*SLOTP;
        while (__hip_atomic_load(s, __ATOMIC_RELAXED, __HIP_MEMORY_SCOPE_AGENT) < seq)
            __builtin_amdgcn_s_sleep(1);
    }
    asm volatile("" ::: "memory");
    __syncthreads();
}

// ---------------- LSTM v9: MFMA f16, h B-fragments loaded DIRECTLY to registers (no LDS bounce) ----------------
__global__ __launch_bounds__(320, 1) void k_lstm_v9(
    _Float16* __restrict__ hF, float* __restrict__ hqB,
    const float* __restrict__ xgT, const float* __restrict__ Whh,
    const float* __restrict__ h0, const float* __restrict__ c0,
    const int* __restrict__ lens, int* __restrict__ slots)
{
    __shared__ _Float16 Wl[80*512];    // 80 KB, swizzled
    __shared__ float    gl[4*80*16];   // 20 KB
    __shared__ _Float16 hout[16*UPB8]; // 640 B

    int tid = threadIdx.x, bid = blockIdx.x;
    int grp = bid / BPG, ub = bid - grp*BPG;
    int u0  = ub * UPB8;
    int w   = tid >> 6, lane = tid & 63;

    int pb  = tid & 15, puu = tid >> 4;        // puu 0..19
    int pu  = u0 + puu;
    int gb  = grp*GBATCH + pb;                 // global batch row
    float cprev = c0[gb*HIDD + pu];
    float hprev = h0[gb*HIDD + pu];
    int   mylen = lens[gb];
    hout[pb*UPB8 + puu] = (_Float16)hprev;

    for (int i = tid; i < 80*512; i += 320){
        int m = i >> 9, k = i & 511;
        int g = m / UPB8, uu = m - g*UPB8;
        float v = (k < HIDD) ? Whh[(size_t)(g*HIDD + u0 + uu)*HIDD + k] : 0.f;
        int off = (i*2) ^ ((m & 7) << 4);
        *(_Float16*)((char*)Wl + off) = (_Float16)v;
    }
    __syncthreads();
    if (tid < 80){
        int b = tid / 5, q = tid - (tid/5)*5;
        unsigned long long v = *(const unsigned long long*)((const char*)hout + b*40 + q*8);
        st_cc8(hF + ((size_t)(1*GRP + grp)*GBATCH + b)*512 + u0 + q*4, v);
    }
    if (ub == 0 && tid >= 128 && tid < 224){   // zero k-pad 500..511, both buffers
        int j = tid - 128;
        int buf = j / 48, r = j - buf*48;
        int b = r / 3, q = r - (r/3)*3;
        st_cc8(hF + ((size_t)(buf*GRP + grp)*GBATCH + b)*512 + 500 + q*4, 0ULL);
    }
    gbarA(slots, grp, ub, 1);

    const int mA = lane & 15, kb = lane >> 4;

    for (int t = 0; t < SEQL; ++t){
        const _Float16* hsrc = hF + (size_t)(((t&1)^1)*GRP + grp)*GBATCH*512;

        // prefetch xg for this step (all 320 threads; hides under MFMA)
        float xgv[4];
        #pragma unroll
        for (int g = 0; g < 4; ++g)
            xgv[g] = xgT[(size_t)(g*HIDD + pu)*MCOL + t*64 + gb];

        if (w < 4){
            // B-fragments straight from global (sc1 u64 pairs) -> registers
            half8 bf[4];
            #pragma unroll
            for (int ks4 = 0; ks4 < 4; ++ks4){
                int ke = (w*4 + ks4)*32 + kb*8;            // f16 element offset in row
                const unsigned long long* p =
                    (const unsigned long long*)(hsrc + mA*512 + ke);
                union { unsigned long long q[2]; half8 h; } u;
                u.q[0] = ld_cc8(p);
                u.q[1] = ld_cc8(p + 1);
                bf[ks4] = u.h;
            }
            f32x4 acc[5] = {};
            #pragma unroll
            for (int rt = 0; rt < 5; ++rt){
                #pragma unroll
                for (int ks4 = 0; ks4 < 4; ++ks4){
                    int kByte = (w*4 + ks4)*64 + kb*16;
                    int m = rt*16 + mA;
                    int aOff = (m*1024 + kByte) ^ ((m & 7) << 4);
                    half8 af = *(const half8*)((const char*)Wl + aOff);
                    acc[rt] = __builtin_amdgcn_mfma_f32_16x16x32_f16(af, bf[ks4], acc[rt], 0, 0, 0);
                }
            }
            #pragma unroll
            for (int rt = 0; rt < 5; ++rt)
                #pragma unroll
                for (int r = 0; r < 4; ++r)
                    gl[(w*80 + rt*16 + kb*4 + r)*16 + mA] = acc[rt][r];
        }
        __syncthreads();

        {
            float g4[4];
            #pragma unroll
            for (int g = 0; g < 4; ++g){
                int row = g*UPB8 + puu;
                float s = gl[(0*80 + row)*16 + pb] + gl[(1*80 + row)*16 + pb]
                        + gl[(2*80 + row)*16 + pb] + gl[(3*80 + row)*16 + pb];
                s += xgv[g];
                g4[g] = s;
            }
            float si = sigmf(g4[0]), sf = sigmf(g4[1]);
            float tg = tanhf(g4[2]), so = sigmf(g4[3]);
            float cn = sf*cprev + si*tg;
            float hn = so*tanhf(cn);
            if (t < mylen){ cprev = cn; hprev = hn; }
            hout[pb*UPB8 + puu] = (_Float16)hprev;
            if (t == SEQL-1) hqB[(size_t)gb*512 + pu] = hprev;   // final h, [b][512] f32
        }
        if (t < SEQL-1){
            __syncthreads();
            if (tid < 80){
                int b = tid / 5, q = tid - (tid/5)*5;
                unsigned long long v = *(const unsigned long long*)((const char*)hout + b*40 + q*8);
                st_cc8(hF + ((size_t)((t&1)*GRP + grp)*GBATCH + b)*512 + u0 + q*4, v);
            }
            gbarA(slots, grp, ub, t + 2);
        }
    }
}

// ---------------- q_part: qp[b][n] = sum_k hqB[b][k]*g1w[n][k] + g1b[n] ----------------
__global__ void k_qp(const float* __restrict__ hqB, const float* __restrict__ g1w,
                     const float* __restrict__ g1b, float* __restrict__ qp)
{
    int idx = blockIdx.x*blockDim.x + threadIdx.x;
    if (idx >= BATCH*GHID) return;
    int b = idx / GHID, n = idx % GHID;
    const float* wr = g1w + n*548;
    const float* hb = hqB + (size_t)b*512;
    float s = g1b[n];
    for (int k = 0; k < HIDD; ++k) s += hb[k]*wr[k];
    qp[idx] = s;
}

// ---------------- i_part/j_part (r9 verbatim) ----------------
__global__ void k_ipjp(const float* __restrict__ conv, const float* __restrict__ g1w,
                       float* __restrict__ ip, float* __restrict__ jp)
{
    int idx = blockIdx.x*blockDim.x + threadIdx.x;
    if (idx >= BATCH*NOBJ*GHID) return;
    int b = idx / (NOBJ*GHID);
    int rem = idx - b*(NOBJ*GHID);
    int o = rem / GHID, n = rem % GHID;
    const float* wj = g1w + n*548 + 500;
    const float* wi = g1w + n*548 + 524;
    float si = 0.f, sj = 0.f;
    #pragma unroll
    for (int c = 0; c < 24; ++c){
        float v = conv[((size_t)b*24 + c)*NOBJ + o];
        sj += v*wj[c];
        si += v*wi[c];
    }
    ip[idx] = si;
    jp[idx] = sj;
}

// ---------------- MFMA pair kernel (r9 verbatim): grid 256 = b(64) x ic(4) ----------------
__global__ __launch_bounds__(256, 1) void k_pair_mfma(
    const float* __restrict__ qp, const float* __restrict__ ip,
    const float* __restrict__ jp, const float* __restrict__ g2w,
    const float* __restrict__ g2b, float* __restrict__ part)
{
    __shared__ float    jpl[NOBJ][132];     // 33792 B
    __shared__ float    basel[16][132];     //  8448 B
    __shared__ _Float16 g2h[112][136];      // 30464 B
    __shared__ float    redx[4][112];       //  1792 B

    int b  = blockIdx.x >> 2;
    int ic = blockIdx.x & 3;
    int tid = threadIdx.x;
    int w = tid >> 6, lane = tid & 63;
    int ncol = lane & 15, kb = lane >> 4;

    for (int i = tid; i < NOBJ*100; i += 256){
        int j = i / 100, k = i - (i/100)*100;
        jpl[j][k] = jp[((size_t)b*NOBJ + j)*GHID + k];
    }
    for (int i = tid; i < NOBJ*32; i += 256)
        jpl[i >> 5][100 + (i & 31)] = 0.f;
    for (int i = tid; i < 16*100; i += 256){
        int il = i / 100, k = i - (i/100)*100;
        basel[il][k] = qp[b*GHID + k] + ip[((size_t)b*NOBJ + ic*16 + il)*GHID + k];
    }
    for (int i = tid; i < 16*32; i += 256)
        basel[i >> 5][100 + (i & 31)] = 0.f;
    for (int i = tid; i < 112*136; i += 256){
        int n = i / 136, k = i - (i/136)*136;
        g2h[n][k] = (n < 100 && k < 100) ? (_Float16)g2w[n*GHID + k] : (_Float16)0.f;
    }
    float gb7[7];
    #pragma unroll
    for (int nt = 0; nt < 7; ++nt){
        int n = nt*16 + ncol;
        gb7[nt] = (n < 100) ? g2b[n] : 0.f;
    }
    __syncthreads();

    f32x4 sacc[7] = {};
    #pragma unroll
    for (int it = 0; it < 4; ++it){
        int il = w*4 + it;
        #pragma unroll
        for (int jc = 0; jc < 4; ++jc){
            f32x4 acc[7] = {};
            int jrow = jc*16 + ncol;
            #pragma unroll
            for (int ks = 0; ks < 4; ++ks){
                int k0 = ks*32 + kb*8;
                const float* jpp = &jpl[jrow][k0];
                const float* bpp = &basel[il][k0];
                half8 af;
                #pragma unroll
                for (int e = 0; e < 8; ++e)
                    af[e] = (_Float16)fmaxf(jpp[e] + bpp[e], 0.f);
                #pragma unroll
                for (int nt = 0; nt < 7; ++nt){
                    half8 bf = *(const half8*)&g2h[nt*16 + ncol][k0];
                    acc[nt] = __builtin_amdgcn_mfma_f32_16x16x32_f16(af, bf, acc[nt], 0, 0, 0);
                }
            }
            #pragma unroll
            for (int nt = 0; nt < 7; ++nt)
                #pragma unroll
                for (int r = 0; r < 4; ++r)
                    sacc[nt][r] += fmaxf(acc[nt][r] + gb7[nt], 0.f);
        }
    }
    #pragma unroll
    for (int nt = 0; nt < 7; ++nt){
        float s = sacc[nt][0] + sacc[nt][1] + sacc[nt][2] + sacc[nt][3];
        s += __shfl_xor(s, 16);
        s += __shfl_xor(s, 32);
        if (lane < 16) redx[w][nt*16 + lane] = s;
    }
    __syncthreads();
    if (tid < 100){
        float p = redx[0][tid] + redx[1][tid] + redx[2][tid] + redx[3][tid];
        part[(size_t)(b*4 + ic)*GHID + tid] = p;
    }
}

// ---------------- final: reduce partials, f1, f2, log_softmax (r9 verbatim) ----------------
__global__ __launch_bounds__(256) void k_final(const float* __restrict__ part, const float* __restrict__ f1w,
               const float* __restrict__ f1b, const float* __restrict__ f2w,
               const float* __restrict__ f2b, float* __restrict__ out)
{
    int b = blockIdx.x;
    int tid = threadIdx.x;
    __shared__ float gs[GHID];
    __shared__ float fh[GHID];
    __shared__ float lg[ANSN];
    __shared__ float red[4], red2[4];
    if (tid < GHID){
        float s = 0.f;
        for (int ic = 0; ic < 4; ++ic) s += part[((size_t)b*4 + ic)*GHID + tid];
        gs[tid] = s;
    }
    __syncthreads();
    if (tid < GHID){
        float s = f1b[tid];
        const float* w = f1w + tid*GHID;
        for (int k = 0; k < GHID; ++k) s += gs[k]*w[k];
        fh[tid] = fmaxf(s, 0.f);
    }
    __syncthreads();
    for (int n = tid; n < ANSN; n += 256){
        float s = f2b[n];
        const float* w = f2w + (size_t)n*GHID;
        for (int k = 0; k < GHID; ++k) s += fh[k]*w[k];
        lg[n] = fmaxf(s, 0.f);
    }
    __syncthreads();
    float mx = -1e30f;
    for (int n = tid; n < ANSN; n += 256) mx = fmaxf(mx, lg[n]);
    #pragma unroll
    for (int off = 32; off > 0; off >>= 1) mx = fmaxf(mx, __shfl_xor(mx, off));
    if ((tid & 63) == 0) red[tid >> 6] = mx;
    __syncthreads();
    mx = fmaxf(fmaxf(red[0], red[1]), fmaxf(red[2], red[3]));
    float se = 0.f;
    for (int n = tid; n < ANSN; n += 256) se += expf(lg[n]-mx);
    #pragma unroll
    for (int off = 32; off > 0; off >>= 1) se += __shfl_xor(se, off);
    if ((tid & 63) == 0) red2[tid >> 6] = se;
    __syncthreads();
    se = red2[0]+red2[1]+red2[2]+red2[3];
    float lse = logf(se);
    for (int n = tid; n < ANSN; n += 256) out[(size_t)b*ANSN + n] = lg[n] - mx - lse;
}

extern "C" void kernel_launch(void* const* d_in, const int* in_sizes, int n_in,
                              void* d_out, int out_size, void* d_ws, size_t ws_size,
                              hipStream_t stream)
{
    const int*   sent  = (const int*)  d_in[0];
    const float* conv  = (const float*)d_in[1];
    const int*   lens  = (const int*)  d_in[2];
    const float* table = (const float*)d_in[3];
    const float* W_ih  = (const float*)d_in[4];
    const float* W_hh  = (const float*)d_in[5];
    const float* b_ih  = (const float*)d_in[6];
    const float* b_hh  = (const float*)d_in[7];
    const float* h0    = (const float*)d_in[8];
    const float* c0    = (const float*)d_in[9];
    const float* g1_w  = (const float*)d_in[10];
    const float* g1_b  = (const float*)d_in[11];
    const float* g2_w  = (const float*)d_in[12];
    const float* g2_b  = (const float*)d_in[13];
    const float* f1_w  = (const float*)d_in[14];
    const float* f1_b  = (const float*)d_in[15];
    const float* f2_w  = (const float*)d_in[16];
    const float* f2_b  = (const float*)d_in[17];
    float* out = (float*)d_out;

    float* ws   = (float*)d_ws;
    int*   slots= (int*)d_ws;                          // 100 slots * 32 ints (64 KB region)
    _Float16* hF = (_Float16*)(ws + 16384);            // 2*4*16*512 f16 = 128 KB
    float* hqB  = ws + 16384 + 32768;                  // 64*512 f32
    float* xgT  = hqB + 64*512;                        // 2000*2048 f32
    float* qp   = xgT + (size_t)4*HIDD*MCOL;           // 64*100
    float* ip   = qp  + BATCH*GHID;                    // 64*64*100
    float* jp   = ip  + BATCH*NOBJ*GHID;
    float* part = jp  + BATCH*NOBJ*GHID;               // 256*100

    // 1. xgT = W_ih @ emb + bias (MFMA f16) — also zeroes barrier slots for kernel 2
    {
        dim3 g(SEQL/TCH, 32);   // x = t-chunk, y = n-tile
        k_xg2<<<g, 256, 0, stream>>>(sent, table, W_ih, b_ih, b_hh, xgT, slots);
    }

    // 2. MFMA LSTM v9 (direct-to-register h fragments), regular launch
    k_lstm_v9<<<NBLK, 320, 0, stream>>>(hF, hqB, xgT, W_hh, h0, c0, lens, slots);

    // 3. g_mlp layer-1 partials
    k_qp<<<(BATCH*GHID + 255)/256, 256, 0, stream>>>(hqB, g1_w, g1_b, qp);
    k_ipjp<<<(BATCH*NOBJ*GHID + 255)/256, 256, 0, stream>>>(conv, g1_w, ip, jp);

    // 4. MFMA pair kernel (256 blocks) -> part[256][100]
    k_pair_mfma<<<BATCH*4, 256, 0, stream>>>(qp, ip, jp, g2_w, g2_b, part);

    // 5. final MLP + log_softmax
    k_final<<<BATCH, 256, 0, stream>>>(part, f1_w, f1_b, f2_w, f2_b, out);
}

// Round 18
// 258.301 us; speedup vs baseline: 1.3671x; 1.0159x over previous
//
#include <hip/hip_runtime.h>
#include <cmath>

#define BATCH 64
#define SEQL  32
#define EMBD  300
#define HIDD  500
#define NOBJ  64
#define GHID  100
#define ANSN  1000
#define MCOL  2048   // t*64+b column dimension

// partition: 4 batch-groups x 25 unit-blocks
#define GRP    4
#define GBATCH 16
#define BPG    25
#define UPB8   20
#define NBLK   (GRP*BPG)   // 100
#define SLOTP  32          // slot padding in ints (128 B)

#define KPADX  328         // xg LDS row stride in f16 (656 B)
#define TCH    4           // timesteps per xg block

typedef _Float16 half8 __attribute__((ext_vector_type(8)));
typedef float    f32x4 __attribute__((ext_vector_type(4)));

__device__ __forceinline__ float sigmf(float x){ return 1.f/(1.f+expf(-x)); }

// sc1 (coherence-point) primitives: RELAXED agent-scope atomics, no cache-wide fences
__device__ __forceinline__ unsigned long long ld_cc8(const unsigned long long* p){
    return __hip_atomic_load(p, __ATOMIC_RELAXED, __HIP_MEMORY_SCOPE_AGENT);
}
__device__ __forceinline__ void st_cc8(_Float16* p, unsigned long long v){
    __hip_atomic_store((unsigned long long*)p, v, __ATOMIC_RELAXED, __HIP_MEMORY_SCOPE_AGENT);
}

// ---------------- k_xg2: xgT = W_ih @ emb + bias (MFMA f16, r14-proven) + slot zeroing ----------------
__global__ __launch_bounds__(256, 1) void k_xg2(
    const int* __restrict__ sent, const float* __restrict__ table,
    const float* __restrict__ Wih, const float* __restrict__ b_ih,
    const float* __restrict__ b_hh, float* __restrict__ xgT, int* __restrict__ slots)
{
    __shared__ _Float16 Sh[64*KPADX];   // 41984 B, A then B
    __shared__ int sidx[TCH][64];
    int tid = threadIdx.x;
    int tc = blockIdx.x;                // t-chunk (0..7)
    int n0 = blockIdx.y * 64;
    int w = tid >> 6, lane = tid & 63;
    int rA = lane & 15, kb = lane >> 4;

    // zero barrier slots for the following kernel (fresh every launch/replay)
    if (tc == 0 && blockIdx.y == 0 && tid < NBLK)
        __hip_atomic_store(slots + tid*SLOTP, 0, __ATOMIC_RELAXED, __HIP_MEMORY_SCOPE_AGENT);

    for (int i = tid; i < TCH*64; i += 256){
        int tt = i >> 6, b = i & 63;
        sidx[tt][b] = sent[b*SEQL + tc*TCH + tt];
    }
    for (int i = tid; i < 64*75; i += 256){
        int n = i / 75, c4 = i - (i/75)*75;
        float4 v = {0.f,0.f,0.f,0.f};
        if (n0 + n < 2000)
            v = *(const float4*)(Wih + (size_t)(n0+n)*300 + c4*4);
        _Float16* dst = &Sh[n*KPADX + c4*4];
        dst[0]=(_Float16)v.x; dst[1]=(_Float16)v.y; dst[2]=(_Float16)v.z; dst[3]=(_Float16)v.w;
    }
    for (int i = tid; i < 64*20; i += 256){   // zero pad k 300..319
        int n = i / 20, k = 300 + (i - (i/20)*20);
        Sh[n*KPADX + k] = (_Float16)0.f;
    }
    __syncthreads();
    half8 areg[10];
    #pragma unroll
    for (int ks = 0; ks < 10; ++ks)
        areg[ks] = *(const half8*)&Sh[(w*16 + rA)*KPADX + ks*32 + kb*8];
    float biasr[4];
    #pragma unroll
    for (int r = 0; r < 4; ++r){
        int n = n0 + w*16 + kb*4 + r;
        biasr[r] = (n < 2000) ? b_ih[n] + b_hh[n] : 0.f;
    }
    __syncthreads();   // all A reads done before B overwrites Sh

    for (int tt = 0; tt < TCH; ++tt){
        for (int i = tid; i < 64*75; i += 256){
            int m = i / 75, c4 = i - (i/75)*75;
            float4 v = *(const float4*)(table + (size_t)sidx[tt][m]*300 + c4*4);
            _Float16* dst = &Sh[m*KPADX + c4*4];
            dst[0]=(_Float16)v.x; dst[1]=(_Float16)v.y; dst[2]=(_Float16)v.z; dst[3]=(_Float16)v.w;
        }
        for (int i = tid; i < 64*20; i += 256){
            int m = i / 20, k = 300 + (i - (i/20)*20);
            Sh[m*KPADX + k] = (_Float16)0.f;
        }
        __syncthreads();

        f32x4 acc[4] = {};
        #pragma unroll
        for (int ks = 0; ks < 10; ++ks){
            #pragma unroll
            for (int mc = 0; mc < 4; ++mc){
                half8 bf = *(const half8*)&Sh[(mc*16 + rA)*KPADX + ks*32 + kb*8];
                acc[mc] = __builtin_amdgcn_mfma_f32_16x16x32_f16(areg[ks], bf, acc[mc], 0, 0, 0);
            }
        }
        #pragma unroll
        for (int r = 0; r < 4; ++r){
            int n = n0 + w*16 + kb*4 + r;
            if (n < 2000){
                #pragma unroll
                for (int mc = 0; mc < 4; ++mc)
                    xgT[(size_t)n*MCOL + (tc*TCH+tt)*64 + mc*16 + rA] = acc[mc][r] + biasr[r];
            }
        }
        __syncthreads();
    }
}

// group-local all-to-all barrier (one hop, fence-free; proven r8-r17)
__device__ __forceinline__ void gbarA(int* slots, int grp, int ub, int seq)
{
    __syncthreads();
    if (threadIdx.x == 0)
        __hip_atomic_store(slots + (grp*BPG + ub)*SLOTP, seq,
                           __ATOMIC_RELAXED, __HIP_MEMORY_SCOPE_AGENT);
    if (threadIdx.x < BPG){
        int* s = slots + (grp*BPG + threadIdx.x)*SLOTP;
        while (__hip_atomic_load(s, __ATOMIC_RELAXED, __HIP_MEMORY_SCOPE_AGENT) < seq)
            __builtin_amdgcn_s_sleep(1);
    }
    asm volatile("" ::: "memory");
    __syncthreads();
}

// ---------------- LSTM v9: MFMA f16, h B-fragments direct to registers (r17 verbatim) ----------------
__global__ __launch_bounds__(320, 1) void k_lstm_v9(
    _Float16* __restrict__ hF, float* __restrict__ hqB,
    const float* __restrict__ xgT, const float* __restrict__ Whh,
    const float* __restrict__ h0, const float* __restrict__ c0,
    const int* __restrict__ lens, int* __restrict__ slots)
{
    __shared__ _Float16 Wl[80*512];    // 80 KB, swizzled
    __shared__ float    gl[4*80*16];   // 20 KB
    __shared__ _Float16 hout[16*UPB8]; // 640 B

    int tid = threadIdx.x, bid = blockIdx.x;
    int grp = bid / BPG, ub = bid - grp*BPG;
    int u0  = ub * UPB8;
    int w   = tid >> 6, lane = tid & 63;

    int pb  = tid & 15, puu = tid >> 4;        // puu 0..19
    int pu  = u0 + puu;
    int gb  = grp*GBATCH + pb;                 // global batch row
    float cprev = c0[gb*HIDD + pu];
    float hprev = h0[gb*HIDD + pu];
    int   mylen = lens[gb];
    hout[pb*UPB8 + puu] = (_Float16)hprev;

    for (int i = tid; i < 80*512; i += 320){
        int m = i >> 9, k = i & 511;
        int g = m / UPB8, uu = m - g*UPB8;
        float v = (k < HIDD) ? Whh[(size_t)(g*HIDD + u0 + uu)*HIDD + k] : 0.f;
        int off = (i*2) ^ ((m & 7) << 4);
        *(_Float16*)((char*)Wl + off) = (_Float16)v;
    }
    __syncthreads();
    if (tid < 80){
        int b = tid / 5, q = tid - (tid/5)*5;
        unsigned long long v = *(const unsigned long long*)((const char*)hout + b*40 + q*8);
        st_cc8(hF + ((size_t)(1*GRP + grp)*GBATCH + b)*512 + u0 + q*4, v);
    }
    if (ub == 0 && tid >= 128 && tid < 224){   // zero k-pad 500..511, both buffers
        int j = tid - 128;
        int buf = j / 48, r = j - buf*48;
        int b = r / 3, q = r - (r/3)*3;
        st_cc8(hF + ((size_t)(buf*GRP + grp)*GBATCH + b)*512 + 500 + q*4, 0ULL);
    }
    gbarA(slots, grp, ub, 1);

    const int mA = lane & 15, kb = lane >> 4;

    for (int t = 0; t < SEQL; ++t){
        const _Float16* hsrc = hF + (size_t)(((t&1)^1)*GRP + grp)*GBATCH*512;

        // prefetch xg for this step (hides under MFMA)
        float xgv[4];
        #pragma unroll
        for (int g = 0; g < 4; ++g)
            xgv[g] = xgT[(size_t)(g*HIDD + pu)*MCOL + t*64 + gb];

        if (w < 4){
            half8 bf[4];
            #pragma unroll
            for (int ks4 = 0; ks4 < 4; ++ks4){
                int ke = (w*4 + ks4)*32 + kb*8;            // f16 element offset in row
                const unsigned long long* p =
                    (const unsigned long long*)(hsrc + mA*512 + ke);
                union { unsigned long long q[2]; half8 h; } u;
                u.q[0] = ld_cc8(p);
                u.q[1] = ld_cc8(p + 1);
                bf[ks4] = u.h;
            }
            f32x4 acc[5] = {};
            #pragma unroll
            for (int rt = 0; rt < 5; ++rt){
                #pragma unroll
                for (int ks4 = 0; ks4 < 4; ++ks4){
                    int kByte = (w*4 + ks4)*64 + kb*16;
                    int m = rt*16 + mA;
                    int aOff = (m*1024 + kByte) ^ ((m & 7) << 4);
                    half8 af = *(const half8*)((const char*)Wl + aOff);
                    acc[rt] = __builtin_amdgcn_mfma_f32_16x16x32_f16(af, bf[ks4], acc[rt], 0, 0, 0);
                }
            }
            #pragma unroll
            for (int rt = 0; rt < 5; ++rt)
                #pragma unroll
                for (int r = 0; r < 4; ++r)
                    gl[(w*80 + rt*16 + kb*4 + r)*16 + mA] = acc[rt][r];
        }
        __syncthreads();

        {
            float g4[4];
            #pragma unroll
            for (int g = 0; g < 4; ++g){
                int row = g*UPB8 + puu;
                float s = gl[(0*80 + row)*16 + pb] + gl[(1*80 + row)*16 + pb]
                        + gl[(2*80 + row)*16 + pb] + gl[(3*80 + row)*16 + pb];
                s += xgv[g];
                g4[g] = s;
            }
            float si = sigmf(g4[0]), sf = sigmf(g4[1]);
            float tg = tanhf(g4[2]), so = sigmf(g4[3]);
            float cn = sf*cprev + si*tg;
            float hn = so*tanhf(cn);
            if (t < mylen){ cprev = cn; hprev = hn; }
            hout[pb*UPB8 + puu] = (_Float16)hprev;
            if (t == SEQL-1) hqB[(size_t)gb*512 + pu] = hprev;   // final h, [b][512] f32
        }
        if (t < SEQL-1){
            __syncthreads();
            if (tid < 80){
                int b = tid / 5, q = tid - (tid/5)*5;
                unsigned long long v = *(const unsigned long long*)((const char*)hout + b*40 + q*8);
                st_cc8(hF + ((size_t)((t&1)*GRP + grp)*GBATCH + b)*512 + u0 + q*4, v);
            }
            gbarA(slots, grp, ub, t + 2);
        }
    }
}

// ---------------- k_pair2: fused qp + ip/jp + pair MFMA -> part[256][100] ----------------
// grid 256 = b(64) x ic(4). Staging from k_tail (r11/r14-proven); pair loop r9/r17-verbatim.
__global__ __launch_bounds__(256, 1) void k_pair2(
    const float* __restrict__ hqB, const float* __restrict__ conv,
    const float* __restrict__ g1w, const float* __restrict__ g1b,
    const float* __restrict__ g2w, const float* __restrict__ g2b,
    float* __restrict__ part)
{
    __shared__ float    convl[24][64];      //  6 KB
    __shared__ float    g1ij[100][48];      // 19.2 KB (cols 500..547 of g1w)
    __shared__ float    hb[512];            //  2 KB
    __shared__ float    qpl[112];           //  0.45 KB
    __shared__ float    jpl[NOBJ][132];     // 33.8 KB
    __shared__ float    basel[16][132];     //  8.4 KB
    __shared__ _Float16 g2h[112][136];      // 30.5 KB
    __shared__ float    redx[4][112];       //  1.8 KB

    int b  = blockIdx.x >> 2;
    int ic = blockIdx.x & 3;
    int tid = threadIdx.x;
    int w = tid >> 6, lane = tid & 63;
    int ncol = lane & 15, kb = lane >> 4;

    // phase 1: stage shared inputs
    for (int i = tid; i < 24*64; i += 256)
        convl[i>>6][i&63] = conv[((size_t)b*24 + (i>>6))*64 + (i&63)];
    for (int i = tid; i < 100*48; i += 256){
        int n = i/48, c = i - (i/48)*48;
        g1ij[n][c] = g1w[(size_t)n*548 + 500 + c];
    }
    for (int i = tid; i < 512; i += 256) hb[i] = hqB[(size_t)b*512 + i];
    for (int i = tid; i < 112*136; i += 256){
        int n = i/136, k = i - (i/136)*136;
        g2h[n][k] = (n < 100 && k < 100) ? (_Float16)g2w[n*GHID + k] : (_Float16)0.f;
    }
    __syncthreads();

    // phase 2: qpl (k_tail-proven float4 dots) + jpl for all 64 j's
    if (tid < 100){
        const float4* wr = (const float4*)(g1w + (size_t)tid*548);
        float s = g1b[tid];
        #pragma unroll 5
        for (int k4 = 0; k4 < 125; ++k4){
            float4 v = wr[k4];
            s += v.x*hb[k4*4] + v.y*hb[k4*4+1] + v.z*hb[k4*4+2] + v.w*hb[k4*4+3];
        }
        qpl[tid] = s;
    }
    for (int i = tid; i < NOBJ*100; i += 256){
        int o = i / 100, n = i - (i/100)*100;
        float sj = 0.f;
        #pragma unroll
        for (int c = 0; c < 24; ++c) sj += convl[c][o] * g1ij[n][c];
        jpl[o][n] = sj;
    }
    for (int i = tid; i < NOBJ*32; i += 256) jpl[i>>5][100 + (i&31)] = 0.f;
    __syncthreads();   // qpl ready

    // phase 3: basel = qpl + ip for own 16 i-rows
    for (int i = tid; i < 16*132; i += 256){
        int il = i / 132, k = i - (i/132)*132;
        float v = 0.f;
        if (k < 100){
            float si = 0.f;
            int o = ic*16 + il;
            #pragma unroll
            for (int c = 0; c < 24; ++c) si += convl[c][o] * g1ij[k][24+c];
            v = qpl[k] + si;
        }
        basel[il][k] = v;
    }
    float gb7[7];
    #pragma unroll
    for (int nt = 0; nt < 7; ++nt){
        int n = nt*16 + ncol;
        gb7[nt] = (n < 100) ? g2b[n] : 0.f;
    }
    __syncthreads();

    // phase 4: pair MFMA loop (r9/r17-verbatim)
    f32x4 sacc[7] = {};
    #pragma unroll
    for (int it = 0; it < 4; ++it){
        int il = w*4 + it;
        #pragma unroll
        for (int jc = 0; jc < 4; ++jc){
            f32x4 acc[7] = {};
            int jrow = jc*16 + ncol;
            #pragma unroll
            for (int ks = 0; ks < 4; ++ks){
                int k0 = ks*32 + kb*8;
                const float* jpp = &jpl[jrow][k0];
                const float* bpp = &basel[il][k0];
                half8 af;
                #pragma unroll
                for (int e = 0; e < 8; ++e)
                    af[e] = (_Float16)fmaxf(jpp[e] + bpp[e], 0.f);
                #pragma unroll
                for (int nt = 0; nt < 7; ++nt){
                    half8 bf = *(const half8*)&g2h[nt*16 + ncol][k0];
                    acc[nt] = __builtin_amdgcn_mfma_f32_16x16x32_f16(af, bf, acc[nt], 0, 0, 0);
                }
            }
            #pragma unroll
            for (int nt = 0; nt < 7; ++nt)
                #pragma unroll
                for (int r = 0; r < 4; ++r)
                    sacc[nt][r] += fmaxf(acc[nt][r] + gb7[nt], 0.f);
        }
    }
    #pragma unroll
    for (int nt = 0; nt < 7; ++nt){
        float s = sacc[nt][0] + sacc[nt][1] + sacc[nt][2] + sacc[nt][3];
        s += __shfl_xor(s, 16);
        s += __shfl_xor(s, 32);
        if (lane < 16) redx[w][nt*16 + lane] = s;
    }
    __syncthreads();
    if (tid < 100){
        float p = redx[0][tid] + redx[1][tid] + redx[2][tid] + redx[3][tid];
        part[(size_t)(b*4 + ic)*GHID + tid] = p;
    }
}

// ---------------- final: reduce partials, f1, f2, log_softmax (r9 verbatim) ----------------
__global__ __launch_bounds__(256) void k_final(const float* __restrict__ part, const float* __restrict__ f1w,
               const float* __restrict__ f1b, const float* __restrict__ f2w,
               const float* __restrict__ f2b, float* __restrict__ out)
{
    int b = blockIdx.x;
    int tid = threadIdx.x;
    __shared__ float gs[GHID];
    __shared__ float fh[GHID];
    __shared__ float lg[ANSN];
    __shared__ float red[4], red2[4];
    if (tid < GHID){
        float s = 0.f;
        for (int ic = 0; ic < 4; ++ic) s += part[((size_t)b*4 + ic)*GHID + tid];
        gs[tid] = s;
    }
    __syncthreads();
    if (tid < GHID){
        float s = f1b[tid];
        const float* w = f1w + tid*GHID;
        for (int k = 0; k < GHID; ++k) s += gs[k]*w[k];
        fh[tid] = fmaxf(s, 0.f);
    }
    __syncthreads();
    for (int n = tid; n < ANSN; n += 256){
        float s = f2b[n];
        const float* w = f2w + (size_t)n*GHID;
        for (int k = 0; k < GHID; ++k) s += fh[k]*w[k];
        lg[n] = fmaxf(s, 0.f);
    }
    __syncthreads();
    float mx = -1e30f;
    for (int n = tid; n < ANSN; n += 256) mx = fmaxf(mx, lg[n]);
    #pragma unroll
    for (int off = 32; off > 0; off >>= 1) mx = fmaxf(mx, __shfl_xor(mx, off));
    if ((tid & 63) == 0) red[tid >> 6] = mx;
    __syncthreads();
    mx = fmaxf(fmaxf(red[0], red[1]), fmaxf(red[2], red[3]));
    float se = 0.f;
    for (int n = tid; n < ANSN; n += 256) se += expf(lg[n]-mx);
    #pragma unroll
    for (int off = 32; off > 0; off >>= 1) se += __shfl_xor(se, off);
    if ((tid & 63) == 0) red2[tid >> 6] = se;
    __syncthreads();
    se = red2[0]+red2[1]+red2[2]+red2[3];
    float lse = logf(se);
    for (int n = tid; n < ANSN; n += 256) out[(size_t)b*ANSN + n] = lg[n] - mx - lse;
}

extern "C" void kernel_launch(void* const* d_in, const int* in_sizes, int n_in,
                              void* d_out, int out_size, void* d_ws, size_t ws_size,
                              hipStream_t stream)
{
    const int*   sent  = (const int*)  d_in[0];
    const float* conv  = (const float*)d_in[1];
    const int*   lens  = (const int*)  d_in[2];
    const float* table = (const float*)d_in[3];
    const float* W_ih  = (const float*)d_in[4];
    const float* W_hh  = (const float*)d_in[5];
    const float* b_ih  = (const float*)d_in[6];
    const float* b_hh  = (const float*)d_in[7];
    const float* h0    = (const float*)d_in[8];
    const float* c0    = (const float*)d_in[9];
    const float* g1_w  = (const float*)d_in[10];
    const float* g1_b  = (const float*)d_in[11];
    const float* g2_w  = (const float*)d_in[12];
    const float* g2_b  = (const float*)d_in[13];
    const float* f1_w  = (const float*)d_in[14];
    const float* f1_b  = (const float*)d_in[15];
    const float* f2_w  = (const float*)d_in[16];
    const float* f2_b  = (const float*)d_in[17];
    float* out = (float*)d_out;

    float* ws   = (float*)d_ws;
    int*   slots= (int*)d_ws;                          // 100 slots * 32 ints (64 KB region)
    _Float16* hF = (_Float16*)(ws + 16384);            // 2*4*16*512 f16 = 128 KB
    float* hqB  = ws + 16384 + 32768;                  // 64*512 f32
    float* xgT  = hqB + 64*512;                        // 2000*2048 f32
    float* part = xgT + (size_t)4*HIDD*MCOL;           // 256*100

    // 1. xgT = W_ih @ emb + bias (MFMA f16) — also zeroes barrier slots for kernel 2
    {
        dim3 g(SEQL/TCH, 32);   // x = t-chunk, y = n-tile
        k_xg2<<<g, 256, 0, stream>>>(sent, table, W_ih, b_ih, b_hh, xgT, slots);
    }

    // 2. MFMA LSTM v9 (direct-to-register h fragments), regular launch
    k_lstm_v9<<<NBLK, 320, 0, stream>>>(hF, hqB, xgT, W_hh, h0, c0, lens, slots);

    // 3. fused qp/ipjp + pair MFMA (256 blocks) -> part[256][100]
    k_pair2<<<BATCH*4, 256, 0, stream>>>(hqB, conv, g1_w, g1_b, g2_w, g2_b, part);

    // 4. final MLP + log_softmax
    k_final<<<BATCH, 256, 0, stream>>>(part, f1_w, f1_b, f2_w, f2_b, out);
}

// Round 19
// 226.598 us; speedup vs baseline: 1.5584x; 1.1399x over previous
//
#include <hip/hip_runtime.h>
#include <cmath>

#define BATCH 64
#define SEQL  32
#define EMBD  300
#define HIDD  500
#define NOBJ  64
#define GHID  100
#define ANSN  1000
#define MCOL  2048   // t*64+b column dimension

// partition: 4 batch-groups x 25 unit-blocks
#define GRP    4
#define GBATCH 16
#define BPG    25
#define UPB8   20
#define NBLK   (GRP*BPG)   // 100 lstm blocks
#define NXG    256         // xg worker blocks (8 tc x 32 n-tiles)
#define SLOTP  32          // slot padding in ints (128 B)

#define KPADX  328         // xg LDS row stride in f16 (656 B)
#define TCH    4           // timesteps per xg block

typedef _Float16 half8 __attribute__((ext_vector_type(8)));
typedef float    f32x4 __attribute__((ext_vector_type(4)));

__device__ __forceinline__ float sigmf(float x){ return 1.f/(1.f+expf(-x)); }

// sc1 (coherence-point) primitives: RELAXED agent-scope atomics, no cache-wide fences
__device__ __forceinline__ unsigned long long ld_cc8(const unsigned long long* p){
    return __hip_atomic_load(p, __ATOMIC_RELAXED, __HIP_MEMORY_SCOPE_AGENT);
}
__device__ __forceinline__ void st_cc8(_Float16* p, unsigned long long v){
    __hip_atomic_store((unsigned long long*)p, v, __ATOMIC_RELAXED, __HIP_MEMORY_SCOPE_AGENT);
}
__device__ __forceinline__ float ld_cc4(const float* p){
    return __hip_atomic_load(p, __ATOMIC_RELAXED, __HIP_MEMORY_SCOPE_AGENT);
}
__device__ __forceinline__ void st_cc4(float* p, float v){
    __hip_atomic_store(p, v, __ATOMIC_RELAXED, __HIP_MEMORY_SCOPE_AGENT);
}

// group-local all-to-all barrier (one hop, fence-free; proven r8-r18)
__device__ __forceinline__ void gbarA(int* slots, int grp, int ub, int seq)
{
    __syncthreads();
    if (threadIdx.x == 0)
        __hip_atomic_store(slots + (grp*BPG + ub)*SLOTP, seq,
                           __ATOMIC_RELAXED, __HIP_MEMORY_SCOPE_AGENT);
    if (threadIdx.x < BPG){
        int* s = slots + (grp*BPG + threadIdx.x)*SLOTP;
        while (__hip_atomic_load(s, __ATOMIC_RELAXED, __HIP_MEMORY_SCOPE_AGENT) < seq)
            __builtin_amdgcn_s_sleep(1);
    }
    asm volatile("" ::: "memory");
    __syncthreads();
}

// ---------------- k_mega: blocks 0..99 = LSTM (r17 path), 100..355 = xg workers (r18 path) ----------------
__global__ __launch_bounds__(320, 1) void k_mega(
    const int* __restrict__ sent, const float* __restrict__ table,
    const float* __restrict__ Wih, const float* __restrict__ b_ih, const float* __restrict__ b_hh,
    _Float16* __restrict__ hF, float* __restrict__ hqB, float* __restrict__ xgT,
    const float* __restrict__ Whh, const float* __restrict__ h0, const float* __restrict__ c0,
    const int* __restrict__ lens, int* __restrict__ slots, int* __restrict__ xgdone)
{
    __shared__ __align__(16) char smem[103040];

    int tid = threadIdx.x, bid = blockIdx.x;
    int w = tid >> 6, lane = tid & 63;

    if (bid >= NBLK){
        // ======== xg worker (r18 k_xg2 body; stores via sc1; 320-thread strides) ========
        _Float16* Sh  = (_Float16*)smem;                 // [64*KPADX] = 41984 B
        int*      sidx= (int*)(smem + 41984);            // [TCH][64]
        int xb = bid - NBLK;
        int tc = xb >> 5;                 // 0..7
        int n0 = (xb & 31) * 64;
        int rA = lane & 15, kb = lane >> 4;

        for (int i = tid; i < TCH*64; i += 320){
            int tt = i >> 6, b = i & 63;
            sidx[tt*64 + b] = sent[b*SEQL + tc*TCH + tt];
        }
        for (int i = tid; i < 64*75; i += 320){
            int n = i / 75, c4 = i - (i/75)*75;
            float4 v = {0.f,0.f,0.f,0.f};
            if (n0 + n < 2000)
                v = *(const float4*)(Wih + (size_t)(n0+n)*300 + c4*4);
            _Float16* dst = &Sh[n*KPADX + c4*4];
            dst[0]=(_Float16)v.x; dst[1]=(_Float16)v.y; dst[2]=(_Float16)v.z; dst[3]=(_Float16)v.w;
        }
        for (int i = tid; i < 64*20; i += 320){   // zero pad k 300..319
            int n = i / 20, k = 300 + (i - (i/20)*20);
            Sh[n*KPADX + k] = (_Float16)0.f;
        }
        __syncthreads();
        half8 areg[10];
        float biasr[4];
        if (w < 4){
            #pragma unroll
            for (int ks = 0; ks < 10; ++ks)
                areg[ks] = *(const half8*)&Sh[(w*16 + rA)*KPADX + ks*32 + kb*8];
            #pragma unroll
            for (int r = 0; r < 4; ++r){
                int n = n0 + w*16 + kb*4 + r;
                biasr[r] = (n < 2000) ? b_ih[n] + b_hh[n] : 0.f;
            }
        }
        __syncthreads();   // all A reads done before B overwrites Sh

        for (int tt = 0; tt < TCH; ++tt){
            for (int i = tid; i < 64*75; i += 320){
                int m = i / 75, c4 = i - (i/75)*75;
                float4 v = *(const float4*)(table + (size_t)sidx[tt*64 + m]*300 + c4*4);
                _Float16* dst = &Sh[m*KPADX + c4*4];
                dst[0]=(_Float16)v.x; dst[1]=(_Float16)v.y; dst[2]=(_Float16)v.z; dst[3]=(_Float16)v.w;
            }
            for (int i = tid; i < 64*20; i += 320){
                int m = i / 20, k = 300 + (i - (i/20)*20);
                Sh[m*KPADX + k] = (_Float16)0.f;
            }
            __syncthreads();

            if (w < 4){
                f32x4 acc[4] = {};
                #pragma unroll
                for (int ks = 0; ks < 10; ++ks){
                    #pragma unroll
                    for (int mc = 0; mc < 4; ++mc){
                        half8 bf = *(const half8*)&Sh[(mc*16 + rA)*KPADX + ks*32 + kb*8];
                        acc[mc] = __builtin_amdgcn_mfma_f32_16x16x32_f16(areg[ks], bf, acc[mc], 0, 0, 0);
                    }
                }
                #pragma unroll
                for (int r = 0; r < 4; ++r){
                    int n = n0 + w*16 + kb*4 + r;
                    if (n < 2000){
                        #pragma unroll
                        for (int mc = 0; mc < 4; ++mc)
                            st_cc4(xgT + (size_t)n*MCOL + (tc*TCH+tt)*64 + mc*16 + rA,
                                   acc[mc][r] + biasr[r]);
                    }
                }
            }
            __syncthreads();
        }
        // all sc1 stores drained by the loop's trailing __syncthreads -> signal tc done
        if (tid == 0)
            __hip_atomic_fetch_add(xgdone + tc*SLOTP, 1,
                                   __ATOMIC_RELAXED, __HIP_MEMORY_SCOPE_AGENT);
        return;
    }

    // ======== LSTM (r17 k_lstm_v9 path; xg via sc1 + per-tc flag polls) ========
    _Float16* Wl  = (_Float16*)smem;                 // [80*512] swizzled, 81920 B
    float*    gl  = (float*)(smem + 81920);          // [4*80*16], 20480 B
    _Float16* hout= (_Float16*)(smem + 102400);      // [16*UPB8], 640 B

    int grp = bid / BPG, ub = bid - grp*BPG;
    int u0  = ub * UPB8;

    int pb  = tid & 15, puu = tid >> 4;        // puu 0..19
    int pu  = u0 + puu;
    int gb  = grp*GBATCH + pb;                 // global batch row
    float cprev = c0[gb*HIDD + pu];
    float hprev = h0[gb*HIDD + pu];
    int   mylen = lens[gb];
    hout[pb*UPB8 + puu] = (_Float16)hprev;

    for (int i = tid; i < 80*512; i += 320){
        int m = i >> 9, k = i & 511;
        int g = m / UPB8, uu = m - g*UPB8;
        float v = (k < HIDD) ? Whh[(size_t)(g*HIDD + u0 + uu)*HIDD + k] : 0.f;
        int off = (i*2) ^ ((m & 7) << 4);
        *(_Float16*)((char*)Wl + off) = (_Float16)v;
    }
    __syncthreads();
    if (tid < 80){
        int b = tid / 5, q = tid - (tid/5)*5;
        unsigned long long v = *(const unsigned long long*)((const char*)hout + b*40 + q*8);
        st_cc8(hF + ((size_t)(1*GRP + grp)*GBATCH + b)*512 + u0 + q*4, v);
    }
    if (ub == 0 && tid >= 128 && tid < 224){   // zero k-pad 500..511, both buffers
        int j = tid - 128;
        int buf = j / 48, r = j - buf*48;
        int b = r / 3, q = r - (r/3)*3;
        st_cc8(hF + ((size_t)(buf*GRP + grp)*GBATCH + b)*512 + 500 + q*4, 0ULL);
    }
    gbarA(slots, grp, ub, 1);

    const int mA = lane & 15, kb = lane >> 4;

    for (int t = 0; t < SEQL; ++t){
        // wait for this tc-chunk of xg (once per 4 steps)
        if ((t & 3) == 0){
            if (tid == 0){
                const int* f = xgdone + (t >> 2)*SLOTP;
                while (__hip_atomic_load(f, __ATOMIC_RELAXED, __HIP_MEMORY_SCOPE_AGENT) < 32)
                    __builtin_amdgcn_s_sleep(1);
            }
            asm volatile("" ::: "memory");
            __syncthreads();
        }

        const _Float16* hsrc = hF + (size_t)(((t&1)^1)*GRP + grp)*GBATCH*512;

        // prefetch xg for this step via sc1 (hides under MFMA)
        float xgv[4];
        #pragma unroll
        for (int g = 0; g < 4; ++g)
            xgv[g] = ld_cc4(xgT + (size_t)(g*HIDD + pu)*MCOL + t*64 + gb);

        if (w < 4){
            half8 bf[4];
            #pragma unroll
            for (int ks4 = 0; ks4 < 4; ++ks4){
                int ke = (w*4 + ks4)*32 + kb*8;            // f16 element offset in row
                const unsigned long long* p =
                    (const unsigned long long*)(hsrc + mA*512 + ke);
                union { unsigned long long q[2]; half8 h; } u;
                u.q[0] = ld_cc8(p);
                u.q[1] = ld_cc8(p + 1);
                bf[ks4] = u.h;
            }
            f32x4 acc[5] = {};
            #pragma unroll
            for (int rt = 0; rt < 5; ++rt){
                #pragma unroll
                for (int ks4 = 0; ks4 < 4; ++ks4){
                    int kByte = (w*4 + ks4)*64 + kb*16;
                    int m = rt*16 + mA;
                    int aOff = (m*1024 + kByte) ^ ((m & 7) << 4);
                    half8 af = *(const half8*)((const char*)Wl + aOff);
                    acc[rt] = __builtin_amdgcn_mfma_f32_16x16x32_f16(af, bf[ks4], acc[rt], 0, 0, 0);
                }
            }
            #pragma unroll
            for (int rt = 0; rt < 5; ++rt)
                #pragma unroll
                for (int r = 0; r < 4; ++r)
                    gl[(w*80 + rt*16 + kb*4 + r)*16 + mA] = acc[rt][r];
        }
        __syncthreads();

        {
            float g4[4];
            #pragma unroll
            for (int g = 0; g < 4; ++g){
                int row = g*UPB8 + puu;
                float s = gl[(0*80 + row)*16 + pb] + gl[(1*80 + row)*16 + pb]
                        + gl[(2*80 + row)*16 + pb] + gl[(3*80 + row)*16 + pb];
                s += xgv[g];
                g4[g] = s;
            }
            float si = sigmf(g4[0]), sf = sigmf(g4[1]);
            float tg = tanhf(g4[2]), so = sigmf(g4[3]);
            float cn = sf*cprev + si*tg;
            float hn = so*tanhf(cn);
            if (t < mylen){ cprev = cn; hprev = hn; }
            hout[pb*UPB8 + puu] = (_Float16)hprev;
            if (t == SEQL-1) hqB[(size_t)gb*512 + pu] = hprev;   // final h, [b][512] f32
        }
        if (t < SEQL-1){
            __syncthreads();
            if (tid < 80){
                int b = tid / 5, q = tid - (tid/5)*5;
                unsigned long long v = *(const unsigned long long*)((const char*)hout + b*40 + q*8);
                st_cc8(hF + ((size_t)((t&1)*GRP + grp)*GBATCH + b)*512 + u0 + q*4, v);
            }
            gbarA(slots, grp, ub, t + 2);
        }
    }
}

// ---------------- k_pair2: fused qp + ip/jp + pair MFMA -> part[256][100] (r18 verbatim) ----------------
__global__ __launch_bounds__(256, 1) void k_pair2(
    const float* __restrict__ hqB, const float* __restrict__ conv,
    const float* __restrict__ g1w, const float* __restrict__ g1b,
    const float* __restrict__ g2w, const float* __restrict__ g2b,
    float* __restrict__ part)
{
    __shared__ float    convl[24][64];      //  6 KB
    __shared__ float    g1ij[100][48];      // 19.2 KB
    __shared__ float    hb[512];            //  2 KB
    __shared__ float    qpl[112];
    __shared__ float    jpl[NOBJ][132];     // 33.8 KB
    __shared__ float    basel[16][132];     //  8.4 KB
    __shared__ _Float16 g2h[112][136];      // 30.5 KB
    __shared__ float    redx[4][112];

    int b  = blockIdx.x >> 2;
    int ic = blockIdx.x & 3;
    int tid = threadIdx.x;
    int w = tid >> 6, lane = tid & 63;
    int ncol = lane & 15, kb = lane >> 4;

    for (int i = tid; i < 24*64; i += 256)
        convl[i>>6][i&63] = conv[((size_t)b*24 + (i>>6))*64 + (i&63)];
    for (int i = tid; i < 100*48; i += 256){
        int n = i/48, c = i - (i/48)*48;
        g1ij[n][c] = g1w[(size_t)n*548 + 500 + c];
    }
    for (int i = tid; i < 512; i += 256) hb[i] = hqB[(size_t)b*512 + i];
    for (int i = tid; i < 112*136; i += 256){
        int n = i/136, k = i - (i/136)*136;
        g2h[n][k] = (n < 100 && k < 100) ? (_Float16)g2w[n*GHID + k] : (_Float16)0.f;
    }
    __syncthreads();

    if (tid < 100){
        const float4* wr = (const float4*)(g1w + (size_t)tid*548);
        float s = g1b[tid];
        #pragma unroll 5
        for (int k4 = 0; k4 < 125; ++k4){
            float4 v = wr[k4];
            s += v.x*hb[k4*4] + v.y*hb[k4*4+1] + v.z*hb[k4*4+2] + v.w*hb[k4*4+3];
        }
        qpl[tid] = s;
    }
    for (int i = tid; i < NOBJ*100; i += 256){
        int o = i / 100, n = i - (i/100)*100;
        float sj = 0.f;
        #pragma unroll
        for (int c = 0; c < 24; ++c) sj += convl[c][o] * g1ij[n][c];
        jpl[o][n] = sj;
    }
    for (int i = tid; i < NOBJ*32; i += 256) jpl[i>>5][100 + (i&31)] = 0.f;
    __syncthreads();

    for (int i = tid; i < 16*132; i += 256){
        int il = i / 132, k = i - (i/132)*132;
        float v = 0.f;
        if (k < 100){
            float si = 0.f;
            int o = ic*16 + il;
            #pragma unroll
            for (int c = 0; c < 24; ++c) si += convl[c][o] * g1ij[k][24+c];
            v = qpl[k] + si;
        }
        basel[il][k] = v;
    }
    float gb7[7];
    #pragma unroll
    for (int nt = 0; nt < 7; ++nt){
        int n = nt*16 + ncol;
        gb7[nt] = (n < 100) ? g2b[n] : 0.f;
    }
    __syncthreads();

    f32x4 sacc[7] = {};
    #pragma unroll
    for (int it = 0; it < 4; ++it){
        int il = w*4 + it;
        #pragma unroll
        for (int jc = 0; jc < 4; ++jc){
            f32x4 acc[7] = {};
            int jrow = jc*16 + ncol;
            #pragma unroll
            for (int ks = 0; ks < 4; ++ks){
                int k0 = ks*32 + kb*8;
                const float* jpp = &jpl[jrow][k0];
                const float* bpp = &basel[il][k0];
                half8 af;
                #pragma unroll
                for (int e = 0; e < 8; ++e)
                    af[e] = (_Float16)fmaxf(jpp[e] + bpp[e], 0.f);
                #pragma unroll
                for (int nt = 0; nt < 7; ++nt){
                    half8 bf = *(const half8*)&g2h[nt*16 + ncol][k0];
                    acc[nt] = __builtin_amdgcn_mfma_f32_16x16x32_f16(af, bf, acc[nt], 0, 0, 0);
                }
            }
            #pragma unroll
            for (int nt = 0; nt < 7; ++nt)
                #pragma unroll
                for (int r = 0; r < 4; ++r)
                    sacc[nt][r] += fmaxf(acc[nt][r] + gb7[nt], 0.f);
        }
    }
    #pragma unroll
    for (int nt = 0; nt < 7; ++nt){
        float s = sacc[nt][0] + sacc[nt][1] + sacc[nt][2] + sacc[nt][3];
        s += __shfl_xor(s, 16);
        s += __shfl_xor(s, 32);
        if (lane < 16) redx[w][nt*16 + lane] = s;
    }
    __syncthreads();
    if (tid < 100){
        float p = redx[0][tid] + redx[1][tid] + redx[2][tid] + redx[3][tid];
        part[(size_t)(b*4 + ic)*GHID + tid] = p;
    }
}

// ---------------- final: reduce partials, f1, f2, log_softmax (r9 verbatim) ----------------
__global__ __launch_bounds__(256) void k_final(const float* __restrict__ part, const float* __restrict__ f1w,
               const float* __restrict__ f1b, const float* __restrict__ f2w,
               const float* __restrict__ f2b, float* __restrict__ out)
{
    int b = blockIdx.x;
    int tid = threadIdx.x;
    __shared__ float gs[GHID];
    __shared__ float fh[GHID];
    __shared__ float lg[ANSN];
    __shared__ float red[4], red2[4];
    if (tid < GHID){
        float s = 0.f;
        for (int ic = 0; ic < 4; ++ic) s += part[((size_t)b*4 + ic)*GHID + tid];
        gs[tid] = s;
    }
    __syncthreads();
    if (tid < GHID){
        float s = f1b[tid];
        const float* w = f1w + tid*GHID;
        for (int k = 0; k < GHID; ++k) s += gs[k]*w[k];
        fh[tid] = fmaxf(s, 0.f);
    }
    __syncthreads();
    for (int n = tid; n < ANSN; n += 256){
        float s = f2b[n];
        const float* w = f2w + (size_t)n*GHID;
        for (int k = 0; k < GHID; ++k) s += fh[k]*w[k];
        lg[n] = fmaxf(s, 0.f);
    }
    __syncthreads();
    float mx = -1e30f;
    for (int n = tid; n < ANSN; n += 256) mx = fmaxf(mx, lg[n]);
    #pragma unroll
    for (int off = 32; off > 0; off >>= 1) mx = fmaxf(mx, __shfl_xor(mx, off));
    if ((tid & 63) == 0) red[tid >> 6] = mx;
    __syncthreads();
    mx = fmaxf(fmaxf(red[0], red[1]), fmaxf(red[2], red[3]));
    float se = 0.f;
    for (int n = tid; n < ANSN; n += 256) se += expf(lg[n]-mx);
    #pragma unroll
    for (int off = 32; off > 0; off >>= 1) se += __shfl_xor(se, off);
    if ((tid & 63) == 0) red2[tid >> 6] = se;
    __syncthreads();
    se = red2[0]+red2[1]+red2[2]+red2[3];
    float lse = logf(se);
    for (int n = tid; n < ANSN; n += 256) out[(size_t)b*ANSN + n] = lg[n] - mx - lse;
}

extern "C" void kernel_launch(void* const* d_in, const int* in_sizes, int n_in,
                              void* d_out, int out_size, void* d_ws, size_t ws_size,
                              hipStream_t stream)
{
    const int*   sent  = (const int*)  d_in[0];
    const float* conv  = (const float*)d_in[1];
    const int*   lens  = (const int*)  d_in[2];
    const float* table = (const float*)d_in[3];
    const float* W_ih  = (const float*)d_in[4];
    const float* W_hh  = (const float*)d_in[5];
    const float* b_ih  = (const float*)d_in[6];
    const float* b_hh  = (const float*)d_in[7];
    const float* h0    = (const float*)d_in[8];
    const float* c0    = (const float*)d_in[9];
    const float* g1_w  = (const float*)d_in[10];
    const float* g1_b  = (const float*)d_in[11];
    const float* g2_w  = (const float*)d_in[12];
    const float* g2_b  = (const float*)d_in[13];
    const float* f1_w  = (const float*)d_in[14];
    const float* f1_b  = (const float*)d_in[15];
    const float* f2_w  = (const float*)d_in[16];
    const float* f2_b  = (const float*)d_in[17];
    float* out = (float*)d_out;

    float* ws    = (float*)d_ws;
    int*   slots = (int*)d_ws;                          // 100 slots * 32 ints
    int*   xgdone= (int*)d_ws + NBLK*SLOTP;             // 8 flags * 32 ints
    _Float16* hF = (_Float16*)(ws + 16384);             // 2*4*16*512 f16 = 128 KB
    float* hqB  = ws + 16384 + 32768;                   // 64*512 f32
    float* xgT  = hqB + 64*512;                         // 2000*2048 f32
    float* part = xgT + (size_t)4*HIDD*MCOL;            // 256*100

    // 0. zero barrier slots + xg flags (deterministic across graph replays)
    hipMemsetAsync(slots, 0, 16384, stream);

    // 1. fused xg + LSTM: 356 blocks (100 lstm + 256 xg workers)
    k_mega<<<NBLK + NXG, 320, 0, stream>>>(sent, table, W_ih, b_ih, b_hh,
                                           hF, hqB, xgT, W_hh, h0, c0, lens,
                                           slots, xgdone);

    // 2. fused qp/ipjp + pair MFMA (256 blocks) -> part[256][100]
    k_pair2<<<BATCH*4, 256, 0, stream>>>(hqB, conv, g1_w, g1_b, g2_w, g2_b, part);

    // 3. final MLP + log_softmax
    k_final<<<BATCH, 256, 0, stream>>>(part, f1_w, f1_b, f2_w, f2_b, out);
}

// Round 20
// 223.875 us; speedup vs baseline: 1.5774x; 1.0122x over previous
//
#include <hip/hip_runtime.h>
#include <cmath>

#define BATCH 64
#define SEQL  32
#define EMBD  300
#define HIDD  500
#define NOBJ  64
#define GHID  100
#define ANSN  1000
#define MCOL  2048   // t*64+b column dimension

// partition: 4 batch-groups x 25 unit-blocks
#define GRP    4
#define GBATCH 16
#define BPG    25
#define UPB8   20
#define NBLK   (GRP*BPG)   // 100 lstm blocks
#define NXG    256         // xg worker blocks (8 tc x 32 n-tiles)
#define SLOTP  32          // slot padding in ints (128 B)

#define KPADX  328         // xg LDS row stride in f16 (656 B)
#define TCH    4           // timesteps per xg block

typedef _Float16 half8 __attribute__((ext_vector_type(8)));
typedef float    f32x4 __attribute__((ext_vector_type(4)));

__device__ __forceinline__ float sigmf(float x){ return 1.f/(1.f+expf(-x)); }

// sc1 (coherence-point) primitives: RELAXED agent-scope atomics, no cache-wide fences
__device__ __forceinline__ unsigned long long ld_cc8(const unsigned long long* p){
    return __hip_atomic_load(p, __ATOMIC_RELAXED, __HIP_MEMORY_SCOPE_AGENT);
}
__device__ __forceinline__ void st_cc8(_Float16* p, unsigned long long v){
    __hip_atomic_store((unsigned long long*)p, v, __ATOMIC_RELAXED, __HIP_MEMORY_SCOPE_AGENT);
}
__device__ __forceinline__ float ld_cc4(const float* p){
    return __hip_atomic_load(p, __ATOMIC_RELAXED, __HIP_MEMORY_SCOPE_AGENT);
}
__device__ __forceinline__ void st_cc4(float* p, float v){
    __hip_atomic_store(p, v, __ATOMIC_RELAXED, __HIP_MEMORY_SCOPE_AGENT);
}

// group-local all-to-all barrier (one hop, fence-free; proven r8-r19)
__device__ __forceinline__ void gbarA(int* slots, int grp, int ub, int seq)
{
    __syncthreads();
    if (threadIdx.x == 0)
        __hip_atomic_store(slots + (grp*BPG + ub)*SLOTP, seq,
                           __ATOMIC_RELAXED, __HIP_MEMORY_SCOPE_AGENT);
    if (threadIdx.x < BPG){
        int* s = slots + (grp*BPG + threadIdx.x)*SLOTP;
        while (__hip_atomic_load(s, __ATOMIC_RELAXED, __HIP_MEMORY_SCOPE_AGENT) < seq)
            __builtin_amdgcn_s_sleep(1);
    }
    asm volatile("" ::: "memory");
    __syncthreads();
}

// wave-local h pack: thread (pb,puu)=tid holds h (f32); 4 units (b, 4w..4w+3) live at
// lanes b,b+16,b+32,b+48 of wave w -> lanes<16 assemble u64, store sc1.
__device__ __forceinline__ void pack_store_h(
    _Float16* hF, int buf, int grp, int u0, int w, int lane, float hval)
{
    union { _Float16 f; unsigned short s; } cv;
    cv.f = (_Float16)hval;
    unsigned int h2 = cv.s;
    int base = lane & 15;
    unsigned int x0 = (unsigned int)__shfl((int)h2, base +  0, 64);
    unsigned int x1 = (unsigned int)__shfl((int)h2, base + 16, 64);
    unsigned int x2 = (unsigned int)__shfl((int)h2, base + 32, 64);
    unsigned int x3 = (unsigned int)__shfl((int)h2, base + 48, 64);
    if (lane < 16){
        unsigned long long v = (unsigned long long)(x0 & 0xFFFFu)
                             | ((unsigned long long)(x1 & 0xFFFFu) << 16)
                             | ((unsigned long long)(x2 & 0xFFFFu) << 32)
                             | ((unsigned long long)(x3 & 0xFFFFu) << 48);
        st_cc8(hF + ((size_t)(buf*GRP + grp)*GBATCH + lane)*512 + u0 + w*4, v);
    }
}

// ---------------- k_mega: blocks 0..99 = LSTM, 100..355 = xg workers (r19 structure) ----------------
__global__ __launch_bounds__(320, 1) void k_mega(
    const int* __restrict__ sent, const float* __restrict__ table,
    const float* __restrict__ Wih, const float* __restrict__ b_ih, const float* __restrict__ b_hh,
    _Float16* __restrict__ hF, float* __restrict__ hqB, float* __restrict__ xgT,
    const float* __restrict__ Whh, const float* __restrict__ h0, const float* __restrict__ c0,
    const int* __restrict__ lens, int* __restrict__ slots, int* __restrict__ xgdone)
{
    __shared__ __align__(16) char smem[102400];

    int tid = threadIdx.x, bid = blockIdx.x;
    int w = tid >> 6, lane = tid & 63;

    if (bid >= NBLK){
        // ======== xg worker (r19 verbatim) ========
        _Float16* Sh  = (_Float16*)smem;                 // [64*KPADX] = 41984 B
        int*      sidx= (int*)(smem + 41984);            // [TCH][64]
        int xb = bid - NBLK;
        int tc = xb >> 5;                 // 0..7
        int n0 = (xb & 31) * 64;
        int rA = lane & 15, kb = lane >> 4;

        for (int i = tid; i < TCH*64; i += 320){
            int tt = i >> 6, b = i & 63;
            sidx[tt*64 + b] = sent[b*SEQL + tc*TCH + tt];
        }
        for (int i = tid; i < 64*75; i += 320){
            int n = i / 75, c4 = i - (i/75)*75;
            float4 v = {0.f,0.f,0.f,0.f};
            if (n0 + n < 2000)
                v = *(const float4*)(Wih + (size_t)(n0+n)*300 + c4*4);
            _Float16* dst = &Sh[n*KPADX + c4*4];
            dst[0]=(_Float16)v.x; dst[1]=(_Float16)v.y; dst[2]=(_Float16)v.z; dst[3]=(_Float16)v.w;
        }
        for (int i = tid; i < 64*20; i += 320){   // zero pad k 300..319
            int n = i / 20, k = 300 + (i - (i/20)*20);
            Sh[n*KPADX + k] = (_Float16)0.f;
        }
        __syncthreads();
        half8 areg[10];
        float biasr[4];
        if (w < 4){
            #pragma unroll
            for (int ks = 0; ks < 10; ++ks)
                areg[ks] = *(const half8*)&Sh[(w*16 + rA)*KPADX + ks*32 + kb*8];
            #pragma unroll
            for (int r = 0; r < 4; ++r){
                int n = n0 + w*16 + kb*4 + r;
                biasr[r] = (n < 2000) ? b_ih[n] + b_hh[n] : 0.f;
            }
        }
        __syncthreads();   // all A reads done before B overwrites Sh

        for (int tt = 0; tt < TCH; ++tt){
            for (int i = tid; i < 64*75; i += 320){
                int m = i / 75, c4 = i - (i/75)*75;
                float4 v = *(const float4*)(table + (size_t)sidx[tt*64 + m]*300 + c4*4);
                _Float16* dst = &Sh[m*KPADX + c4*4];
                dst[0]=(_Float16)v.x; dst[1]=(_Float16)v.y; dst[2]=(_Float16)v.z; dst[3]=(_Float16)v.w;
            }
            for (int i = tid; i < 64*20; i += 320){
                int m = i / 20, k = 300 + (i - (i/20)*20);
                Sh[m*KPADX + k] = (_Float16)0.f;
            }
            __syncthreads();

            if (w < 4){
                f32x4 acc[4] = {};
                #pragma unroll
                for (int ks = 0; ks < 10; ++ks){
                    #pragma unroll
                    for (int mc = 0; mc < 4; ++mc){
                        half8 bf = *(const half8*)&Sh[(mc*16 + rA)*KPADX + ks*32 + kb*8];
                        acc[mc] = __builtin_amdgcn_mfma_f32_16x16x32_f16(areg[ks], bf, acc[mc], 0, 0, 0);
                    }
                }
                #pragma unroll
                for (int r = 0; r < 4; ++r){
                    int n = n0 + w*16 + kb*4 + r;
                    if (n < 2000){
                        #pragma unroll
                        for (int mc = 0; mc < 4; ++mc)
                            st_cc4(xgT + (size_t)n*MCOL + (tc*TCH+tt)*64 + mc*16 + rA,
                                   acc[mc][r] + biasr[r]);
                    }
                }
            }
            __syncthreads();
        }
        if (tid == 0)
            __hip_atomic_fetch_add(xgdone + tc*SLOTP, 1,
                                   __ATOMIC_RELAXED, __HIP_MEMORY_SCOPE_AGENT);
        return;
    }

    // ======== LSTM (r17/r19 path + shuffle-pack h stores) ========
    _Float16* Wl  = (_Float16*)smem;                 // [80*512] swizzled, 81920 B
    float*    gl  = (float*)(smem + 81920);          // [4*80*16], 20480 B

    int grp = bid / BPG, ub = bid - grp*BPG;
    int u0  = ub * UPB8;

    int pb  = tid & 15, puu = tid >> 4;        // puu 0..19
    int pu  = u0 + puu;
    int gb  = grp*GBATCH + pb;                 // global batch row
    float cprev = c0[gb*HIDD + pu];
    float hprev = h0[gb*HIDD + pu];
    int   mylen = lens[gb];

    for (int i = tid; i < 80*512; i += 320){
        int m = i >> 9, k = i & 511;
        int g = m / UPB8, uu = m - g*UPB8;
        float v = (k < HIDD) ? Whh[(size_t)(g*HIDD + u0 + uu)*HIDD + k] : 0.f;
        int off = (i*2) ^ ((m & 7) << 4);
        *(_Float16*)((char*)Wl + off) = (_Float16)v;
    }
    // h(-1) -> buf1 via shuffle-pack (no LDS bounce)
    pack_store_h(hF, 1, grp, u0, w, lane, hprev);
    if (ub == 0 && tid >= 128 && tid < 224){   // zero k-pad 500..511, both buffers
        int j = tid - 128;
        int buf = j / 48, r = j - buf*48;
        int b = r / 3, q = r - (r/3)*3;
        st_cc8(hF + ((size_t)(buf*GRP + grp)*GBATCH + b)*512 + 500 + q*4, 0ULL);
    }
    gbarA(slots, grp, ub, 1);

    const int mA = lane & 15, kb = lane >> 4;

    for (int t = 0; t < SEQL; ++t){
        // wait for this tc-chunk of xg (once per 4 steps)
        if ((t & 3) == 0){
            if (tid == 0){
                const int* f = xgdone + (t >> 2)*SLOTP;
                while (__hip_atomic_load(f, __ATOMIC_RELAXED, __HIP_MEMORY_SCOPE_AGENT) < 32)
                    __builtin_amdgcn_s_sleep(1);
            }
            asm volatile("" ::: "memory");
            __syncthreads();
        }

        const _Float16* hsrc = hF + (size_t)(((t&1)^1)*GRP + grp)*GBATCH*512;

        // prefetch xg for this step via sc1 (hides under MFMA)
        float xgv[4];
        #pragma unroll
        for (int g = 0; g < 4; ++g)
            xgv[g] = ld_cc4(xgT + (size_t)(g*HIDD + pu)*MCOL + t*64 + gb);

        if (w < 4){
            half8 bf[4];
            #pragma unroll
            for (int ks4 = 0; ks4 < 4; ++ks4){
                int ke = (w*4 + ks4)*32 + kb*8;            // f16 element offset in row
                const unsigned long long* p =
                    (const unsigned long long*)(hsrc + mA*512 + ke);
                union { unsigned long long q[2]; half8 h; } u;
                u.q[0] = ld_cc8(p);
                u.q[1] = ld_cc8(p + 1);
                bf[ks4] = u.h;
            }
            f32x4 acc[5] = {};
            #pragma unroll
            for (int rt = 0; rt < 5; ++rt){
                #pragma unroll
                for (int ks4 = 0; ks4 < 4; ++ks4){
                    int kByte = (w*4 + ks4)*64 + kb*16;
                    int m = rt*16 + mA;
                    int aOff = (m*1024 + kByte) ^ ((m & 7) << 4);
                    half8 af = *(const half8*)((const char*)Wl + aOff);
                    acc[rt] = __builtin_amdgcn_mfma_f32_16x16x32_f16(af, bf[ks4], acc[rt], 0, 0, 0);
                }
            }
            #pragma unroll
            for (int rt = 0; rt < 5; ++rt)
                #pragma unroll
                for (int r = 0; r < 4; ++r)
                    gl[(w*80 + rt*16 + kb*4 + r)*16 + mA] = acc[rt][r];
        }
        __syncthreads();

        {
            float g4[4];
            #pragma unroll
            for (int g = 0; g < 4; ++g){
                int row = g*UPB8 + puu;
                float s = gl[(0*80 + row)*16 + pb] + gl[(1*80 + row)*16 + pb]
                        + gl[(2*80 + row)*16 + pb] + gl[(3*80 + row)*16 + pb];
                s += xgv[g];
                g4[g] = s;
            }
            float si = sigmf(g4[0]), sf = sigmf(g4[1]);
            float tg = tanhf(g4[2]), so = sigmf(g4[3]);
            float cn = sf*cprev + si*tg;
            float hn = so*tanhf(cn);
            if (t < mylen){ cprev = cn; hprev = hn; }
        }
        if (t == SEQL-1){
            hqB[(size_t)gb*512 + pu] = hprev;   // final h, [b][512] f32
        } else {
            pack_store_h(hF, t & 1, grp, u0, w, lane, hprev);
            gbarA(slots, grp, ub, t + 2);       // entry sync drains vmcnt -> stores acked
        }
    }
}

// ---------------- k_pair3: qp + ip/jp + pair MFMA + fused final epilogue ----------------
// grid 256 = b(64) x ic(4). Last-arriving block per b runs f1/f2/log_softmax.
__global__ __launch_bounds__(256, 1) void k_pair3(
    const float* __restrict__ hqB, const float* __restrict__ conv,
    const float* __restrict__ g1w, const float* __restrict__ g1b,
    const float* __restrict__ g2w, const float* __restrict__ g2b,
    const float* __restrict__ f1w, const float* __restrict__ f1b,
    const float* __restrict__ f2w, const float* __restrict__ f2b,
    float* __restrict__ part, int* __restrict__ pcnt, float* __restrict__ out)
{
    __shared__ float    convl[24][64];      //  6 KB
    __shared__ float    g1ij[100][48];      // 19.2 KB
    __shared__ float    hb[512];            //  2 KB
    __shared__ float    qpl[112];
    __shared__ float    jpl[NOBJ][132];     // 33.8 KB
    __shared__ float    basel[16][132];     //  8.4 KB
    __shared__ _Float16 g2h[112][136];      // 30.5 KB
    __shared__ float    redx[4][112];
    __shared__ float    gs[112], fh[112];
    __shared__ float    lg[ANSN];           //  4 KB
    __shared__ float    red[4], red2[4];
    __shared__ int      lastf;

    int b  = blockIdx.x >> 2;
    int ic = blockIdx.x & 3;
    int tid = threadIdx.x;
    int w = tid >> 6, lane = tid & 63;
    int ncol = lane & 15, kb = lane >> 4;

    for (int i = tid; i < 24*64; i += 256)
        convl[i>>6][i&63] = conv[((size_t)b*24 + (i>>6))*64 + (i&63)];
    for (int i = tid; i < 100*48; i += 256){
        int n = i/48, c = i - (i/48)*48;
        g1ij[n][c] = g1w[(size_t)n*548 + 500 + c];
    }
    for (int i = tid; i < 512; i += 256) hb[i] = hqB[(size_t)b*512 + i];
    for (int i = tid; i < 112*136; i += 256){
        int n = i/136, k = i - (i/136)*136;
        g2h[n][k] = (n < 100 && k < 100) ? (_Float16)g2w[n*GHID + k] : (_Float16)0.f;
    }
    __syncthreads();

    if (tid < 100){
        const float4* wr = (const float4*)(g1w + (size_t)tid*548);
        float s = g1b[tid];
        #pragma unroll 5
        for (int k4 = 0; k4 < 125; ++k4){
            float4 v = wr[k4];
            s += v.x*hb[k4*4] + v.y*hb[k4*4+1] + v.z*hb[k4*4+2] + v.w*hb[k4*4+3];
        }
        qpl[tid] = s;
    }
    for (int i = tid; i < NOBJ*100; i += 256){
        int o = i / 100, n = i - (i/100)*100;
        float sj = 0.f;
        #pragma unroll
        for (int c = 0; c < 24; ++c) sj += convl[c][o] * g1ij[n][c];
        jpl[o][n] = sj;
    }
    for (int i = tid; i < NOBJ*32; i += 256) jpl[i>>5][100 + (i&31)] = 0.f;
    __syncthreads();

    for (int i = tid; i < 16*132; i += 256){
        int il = i / 132, k = i - (i/132)*132;
        float v = 0.f;
        if (k < 100){
            float si = 0.f;
            int o = ic*16 + il;
            #pragma unroll
            for (int c = 0; c < 24; ++c) si += convl[c][o] * g1ij[k][24+c];
            v = qpl[k] + si;
        }
        basel[il][k] = v;
    }
    float gb7[7];
    #pragma unroll
    for (int nt = 0; nt < 7; ++nt){
        int n = nt*16 + ncol;
        gb7[nt] = (n < 100) ? g2b[n] : 0.f;
    }
    __syncthreads();

    f32x4 sacc[7] = {};
    #pragma unroll
    for (int it = 0; it < 4; ++it){
        int il = w*4 + it;
        #pragma unroll
        for (int jc = 0; jc < 4; ++jc){
            f32x4 acc[7] = {};
            int jrow = jc*16 + ncol;
            #pragma unroll
            for (int ks = 0; ks < 4; ++ks){
                int k0 = ks*32 + kb*8;
                const float* jpp = &jpl[jrow][k0];
                const float* bpp = &basel[il][k0];
                half8 af;
                #pragma unroll
                for (int e = 0; e < 8; ++e)
                    af[e] = (_Float16)fmaxf(jpp[e] + bpp[e], 0.f);
                #pragma unroll
                for (int nt = 0; nt < 7; ++nt){
                    half8 bf = *(const half8*)&g2h[nt*16 + ncol][k0];
                    acc[nt] = __builtin_amdgcn_mfma_f32_16x16x32_f16(af, bf, acc[nt], 0, 0, 0);
                }
            }
            #pragma unroll
            for (int nt = 0; nt < 7; ++nt)
                #pragma unroll
                for (int r = 0; r < 4; ++r)
                    sacc[nt][r] += fmaxf(acc[nt][r] + gb7[nt], 0.f);
        }
    }
    #pragma unroll
    for (int nt = 0; nt < 7; ++nt){
        float s = sacc[nt][0] + sacc[nt][1] + sacc[nt][2] + sacc[nt][3];
        s += __shfl_xor(s, 16);
        s += __shfl_xor(s, 32);
        if (lane < 16) redx[w][nt*16 + lane] = s;
    }
    __syncthreads();
    if (tid < 100){
        float p = redx[0][tid] + redx[1][tid] + redx[2][tid] + redx[3][tid];
        st_cc4(part + (size_t)(b*4 + ic)*GHID + tid, p);
    }
    __syncthreads();   // drain part stores before counter RMW

    if (tid == 0){
        int old = __hip_atomic_fetch_add(pcnt + b*SLOTP, 1,
                                         __ATOMIC_ACQ_REL, __HIP_MEMORY_SCOPE_AGENT);
        lastf = (old == 3);
    }
    __syncthreads();
    if (!lastf) return;

    // ---- epilogue (last block for this b): gs -> f1 -> f2 -> log_softmax ----
    if (tid < 100){
        float s = 0.f;
        #pragma unroll
        for (int ic2 = 0; ic2 < 4; ++ic2)
            s += ld_cc4(part + (size_t)(b*4 + ic2)*GHID + tid);
        gs[tid] = s;
    }
    __syncthreads();
    if (tid < 100){
        const float4* wr = (const float4*)(f1w + (size_t)tid*GHID);
        float s = f1b[tid];
        #pragma unroll 5
        for (int k4 = 0; k4 < 25; ++k4){
            float4 v = wr[k4];
            s += v.x*gs[k4*4] + v.y*gs[k4*4+1] + v.z*gs[k4*4+2] + v.w*gs[k4*4+3];
        }
        fh[tid] = fmaxf(s, 0.f);
    }
    __syncthreads();
    for (int n = tid; n < ANSN; n += 256){
        const float4* wr = (const float4*)(f2w + (size_t)n*GHID);
        float s = f2b[n];
        #pragma unroll 5
        for (int k4 = 0; k4 < 25; ++k4){
            float4 v = wr[k4];
            s += v.x*fh[k4*4] + v.y*fh[k4*4+1] + v.z*fh[k4*4+2] + v.w*fh[k4*4+3];
        }
        lg[n] = fmaxf(s, 0.f);
    }
    __syncthreads();
    float mx = -1e30f;
    for (int n = tid; n < ANSN; n += 256) mx = fmaxf(mx, lg[n]);
    #pragma unroll
    for (int off = 32; off > 0; off >>= 1) mx = fmaxf(mx, __shfl_xor(mx, off));
    if ((tid & 63) == 0) red[tid >> 6] = mx;
    __syncthreads();
    mx = fmaxf(fmaxf(red[0], red[1]), fmaxf(red[2], red[3]));
    float se = 0.f;
    for (int n = tid; n < ANSN; n += 256) se += expf(lg[n]-mx);
    #pragma unroll
    for (int off = 32; off > 0; off >>= 1) se += __shfl_xor(se, off);
    if ((tid & 63) == 0) red2[tid >> 6] = se;
    __syncthreads();
    se = red2[0]+red2[1]+red2[2]+red2[3];
    float lse = logf(se);
    for (int n = tid; n < ANSN; n += 256) out[(size_t)b*ANSN + n] = lg[n] - mx - lse;
}

extern "C" void kernel_launch(void* const* d_in, const int* in_sizes, int n_in,
                              void* d_out, int out_size, void* d_ws, size_t ws_size,
                              hipStream_t stream)
{
    const int*   sent  = (const int*)  d_in[0];
    const float* conv  = (const float*)d_in[1];
    const int*   lens  = (const int*)  d_in[2];
    const float* table = (const float*)d_in[3];
    const float* W_ih  = (const float*)d_in[4];
    const float* W_hh  = (const float*)d_in[5];
    const float* b_ih  = (const float*)d_in[6];
    const float* b_hh  = (const float*)d_in[7];
    const float* h0    = (const float*)d_in[8];
    const float* c0    = (const float*)d_in[9];
    const float* g1_w  = (const float*)d_in[10];
    const float* g1_b  = (const float*)d_in[11];
    const float* g2_w  = (const float*)d_in[12];
    const float* g2_b  = (const float*)d_in[13];
    const float* f1_w  = (const float*)d_in[14];
    const float* f1_b  = (const float*)d_in[15];
    const float* f2_w  = (const float*)d_in[16];
    const float* f2_b  = (const float*)d_in[17];
    float* out = (float*)d_out;

    float* ws    = (float*)d_ws;
    int*   slots = (int*)d_ws;                          // [0, 3200) ints
    int*   xgdone= (int*)d_ws + NBLK*SLOTP;             // [3200, 3456) ints
    int*   pcnt  = (int*)d_ws + NBLK*SLOTP + 8*SLOTP;   // [3456, 5504) ints
    _Float16* hF = (_Float16*)(ws + 16384);             // 2*4*16*512 f16 = 128 KB
    float* hqB  = ws + 16384 + 32768;                   // 64*512 f32
    float* xgT  = hqB + 64*512;                         // 2000*2048 f32
    float* part = xgT + (size_t)4*HIDD*MCOL;            // 256*100

    // 0. zero barrier slots + xg flags + pair counters (deterministic across replays)
    hipMemsetAsync(slots, 0, (NBLK + 8 + BATCH)*SLOTP*sizeof(int), stream);

    // 1. fused xg + LSTM: 356 blocks (100 lstm + 256 xg workers)
    k_mega<<<NBLK + NXG, 320, 0, stream>>>(sent, table, W_ih, b_ih, b_hh,
                                           hF, hqB, xgT, W_hh, h0, c0, lens,
                                           slots, xgdone);

    // 2. fused qp/ipjp + pair MFMA + final epilogue (256 blocks)
    k_pair3<<<BATCH*4, 256, 0, stream>>>(hqB, conv, g1_w, g1_b, g2_w, g2_b,
                                         f1_w, f1_b, f2_w, f2_b, part, pcnt, out);
}

// Round 21
// 215.025 us; speedup vs baseline: 1.6423x; 1.0412x over previous
//
#include <hip/hip_runtime.h>
#include <cmath>

#define BATCH 64
#define SEQL  32
#define EMBD  300
#define HIDD  500
#define NOBJ  64
#define GHID  100
#define ANSN  1000
#define MCOL  2048   // t*64+b column dimension

// partition: 4 batch-groups x 25 unit-blocks
#define GRP    4
#define GBATCH 16
#define BPG    25
#define UPB8   20
#define NBLK   (GRP*BPG)   // 100 lstm blocks
#define NXG    256         // xg worker blocks (8 tc x 32 n-tiles)
#define SLOTP  32          // slot padding in ints (128 B)

#define KPADX  328         // xg LDS row stride in f16 (656 B)
#define TCH    4           // timesteps per xg block

// k_pair4 LDS layout (pre-MFMA staging region aliased by epilogue arrays)
#define SM_CONV   0        // float [24][64]   = 6144
#define SM_G1IJ   6144     // float [100][48]  = 19200
#define SM_HB     25344    // float [512]      = 2048
#define SM_QPL    27392    // float [112]      = 448   (pre total 27840)
#define SM_REDX   0        // float [4][112]   = 1792  (post, aliases conv)
#define SM_GS     1792     // float [112]
#define SM_FH     2240     // float [112]
#define SM_LG     2688     // float [1000]
#define SM_RED    6688     // float [4]
#define SM_RED2   6704     // float [4]
#define SM_LASTF  6720     // int
#define SM_JPL    27840    // f16 [64][136]    = 17408
#define SM_BASEL  45248    // f16 [16][136]    = 4352
#define SM_G2H    49600    // f16 [112][136]   = 30464
#define SM_TOTAL  80064

typedef _Float16 half8 __attribute__((ext_vector_type(8)));
typedef float    f32x4 __attribute__((ext_vector_type(4)));

__device__ __forceinline__ float sigmf(float x){ return 1.f/(1.f+expf(-x)); }

// sc1 (coherence-point) primitives: RELAXED agent-scope atomics, no cache-wide fences
__device__ __forceinline__ unsigned long long ld_cc8(const unsigned long long* p){
    return __hip_atomic_load(p, __ATOMIC_RELAXED, __HIP_MEMORY_SCOPE_AGENT);
}
__device__ __forceinline__ void st_cc8(_Float16* p, unsigned long long v){
    __hip_atomic_store((unsigned long long*)p, v, __ATOMIC_RELAXED, __HIP_MEMORY_SCOPE_AGENT);
}
__device__ __forceinline__ float ld_cc4(const float* p){
    return __hip_atomic_load(p, __ATOMIC_RELAXED, __HIP_MEMORY_SCOPE_AGENT);
}
__device__ __forceinline__ void st_cc4(float* p, float v){
    __hip_atomic_store(p, v, __ATOMIC_RELAXED, __HIP_MEMORY_SCOPE_AGENT);
}

// group-local all-to-all barrier (one hop, fence-free; proven r8-r20)
__device__ __forceinline__ void gbarA(int* slots, int grp, int ub, int seq)
{
    __syncthreads();
    if (threadIdx.x == 0)
        __hip_atomic_store(slots + (grp*BPG + ub)*SLOTP, seq,
                           __ATOMIC_RELAXED, __HIP_MEMORY_SCOPE_AGENT);
    if (threadIdx.x < BPG){
        int* s = slots + (grp*BPG + threadIdx.x)*SLOTP;
        while (__hip_atomic_load(s, __ATOMIC_RELAXED, __HIP_MEMORY_SCOPE_AGENT) < seq)
            __builtin_amdgcn_s_sleep(1);
    }
    asm volatile("" ::: "memory");
    __syncthreads();
}

// wave-local h pack (r20-proven)
__device__ __forceinline__ void pack_store_h(
    _Float16* hF, int buf, int grp, int u0, int w, int lane, float hval)
{
    union { _Float16 f; unsigned short s; } cv;
    cv.f = (_Float16)hval;
    unsigned int h2 = cv.s;
    int base = lane & 15;
    unsigned int x0 = (unsigned int)__shfl((int)h2, base +  0, 64);
    unsigned int x1 = (unsigned int)__shfl((int)h2, base + 16, 64);
    unsigned int x2 = (unsigned int)__shfl((int)h2, base + 32, 64);
    unsigned int x3 = (unsigned int)__shfl((int)h2, base + 48, 64);
    if (lane < 16){
        unsigned long long v = (unsigned long long)(x0 & 0xFFFFu)
                             | ((unsigned long long)(x1 & 0xFFFFu) << 16)
                             | ((unsigned long long)(x2 & 0xFFFFu) << 32)
                             | ((unsigned long long)(x3 & 0xFFFFu) << 48);
        st_cc8(hF + ((size_t)(buf*GRP + grp)*GBATCH + lane)*512 + u0 + w*4, v);
    }
}

// ---------------- k_mega: blocks 0..99 = LSTM, 100..355 = xg workers (r20 verbatim) ----------------
__global__ __launch_bounds__(320, 1) void k_mega(
    const int* __restrict__ sent, const float* __restrict__ table,
    const float* __restrict__ Wih, const float* __restrict__ b_ih, const float* __restrict__ b_hh,
    _Float16* __restrict__ hF, float* __restrict__ hqB, float* __restrict__ xgT,
    const float* __restrict__ Whh, const float* __restrict__ h0, const float* __restrict__ c0,
    const int* __restrict__ lens, int* __restrict__ slots, int* __restrict__ xgdone)
{
    __shared__ __align__(16) char smem[102400];

    int tid = threadIdx.x, bid = blockIdx.x;
    int w = tid >> 6, lane = tid & 63;

    if (bid >= NBLK){
        _Float16* Sh  = (_Float16*)smem;                 // [64*KPADX] = 41984 B
        int*      sidx= (int*)(smem + 41984);            // [TCH][64]
        int xb = bid - NBLK;
        int tc = xb >> 5;                 // 0..7
        int n0 = (xb & 31) * 64;
        int rA = lane & 15, kb = lane >> 4;

        for (int i = tid; i < TCH*64; i += 320){
            int tt = i >> 6, b = i & 63;
            sidx[tt*64 + b] = sent[b*SEQL + tc*TCH + tt];
        }
        for (int i = tid; i < 64*75; i += 320){
            int n = i / 75, c4 = i - (i/75)*75;
            float4 v = {0.f,0.f,0.f,0.f};
            if (n0 + n < 2000)
                v = *(const float4*)(Wih + (size_t)(n0+n)*300 + c4*4);
            _Float16* dst = &Sh[n*KPADX + c4*4];
            dst[0]=(_Float16)v.x; dst[1]=(_Float16)v.y; dst[2]=(_Float16)v.z; dst[3]=(_Float16)v.w;
        }
        for (int i = tid; i < 64*20; i += 320){   // zero pad k 300..319
            int n = i / 20, k = 300 + (i - (i/20)*20);
            Sh[n*KPADX + k] = (_Float16)0.f;
        }
        __syncthreads();
        half8 areg[10];
        float biasr[4];
        if (w < 4){
            #pragma unroll
            for (int ks = 0; ks < 10; ++ks)
                areg[ks] = *(const half8*)&Sh[(w*16 + rA)*KPADX + ks*32 + kb*8];
            #pragma unroll
            for (int r = 0; r < 4; ++r){
                int n = n0 + w*16 + kb*4 + r;
                biasr[r] = (n < 2000) ? b_ih[n] + b_hh[n] : 0.f;
            }
        }
        __syncthreads();   // all A reads done before B overwrites Sh

        for (int tt = 0; tt < TCH; ++tt){
            for (int i = tid; i < 64*75; i += 320){
                int m = i / 75, c4 = i - (i/75)*75;
                float4 v = *(const float4*)(table + (size_t)sidx[tt*64 + m]*300 + c4*4);
                _Float16* dst = &Sh[m*KPADX + c4*4];
                dst[0]=(_Float16)v.x; dst[1]=(_Float16)v.y; dst[2]=(_Float16)v.z; dst[3]=(_Float16)v.w;
            }
            for (int i = tid; i < 64*20; i += 320){
                int m = i / 20, k = 300 + (i - (i/20)*20);
                Sh[m*KPADX + k] = (_Float16)0.f;
            }
            __syncthreads();

            if (w < 4){
                f32x4 acc[4] = {};
                #pragma unroll
                for (int ks = 0; ks < 10; ++ks){
                    #pragma unroll
                    for (int mc = 0; mc < 4; ++mc){
                        half8 bf = *(const half8*)&Sh[(mc*16 + rA)*KPADX + ks*32 + kb*8];
                        acc[mc] = __builtin_amdgcn_mfma_f32_16x16x32_f16(areg[ks], bf, acc[mc], 0, 0, 0);
                    }
                }
                #pragma unroll
                for (int r = 0; r < 4; ++r){
                    int n = n0 + w*16 + kb*4 + r;
                    if (n < 2000){
                        #pragma unroll
                        for (int mc = 0; mc < 4; ++mc)
                            st_cc4(xgT + (size_t)n*MCOL + (tc*TCH+tt)*64 + mc*16 + rA,
                                   acc[mc][r] + biasr[r]);
                    }
                }
            }
            __syncthreads();
        }
        if (tid == 0)
            __hip_atomic_fetch_add(xgdone + tc*SLOTP, 1,
                                   __ATOMIC_RELAXED, __HIP_MEMORY_SCOPE_AGENT);
        return;
    }

    // ======== LSTM (r20 verbatim) ========
    _Float16* Wl  = (_Float16*)smem;                 // [80*512] swizzled, 81920 B
    float*    gl  = (float*)(smem + 81920);          // [4*80*16], 20480 B

    int grp = bid / BPG, ub = bid - grp*BPG;
    int u0  = ub * UPB8;

    int pb  = tid & 15, puu = tid >> 4;        // puu 0..19
    int pu  = u0 + puu;
    int gb  = grp*GBATCH + pb;                 // global batch row
    float cprev = c0[gb*HIDD + pu];
    float hprev = h0[gb*HIDD + pu];
    int   mylen = lens[gb];

    for (int i = tid; i < 80*512; i += 320){
        int m = i >> 9, k = i & 511;
        int g = m / UPB8, uu = m - g*UPB8;
        float v = (k < HIDD) ? Whh[(size_t)(g*HIDD + u0 + uu)*HIDD + k] : 0.f;
        int off = (i*2) ^ ((m & 7) << 4);
        *(_Float16*)((char*)Wl + off) = (_Float16)v;
    }
    pack_store_h(hF, 1, grp, u0, w, lane, hprev);
    if (ub == 0 && tid >= 128 && tid < 224){   // zero k-pad 500..511, both buffers
        int j = tid - 128;
        int buf = j / 48, r = j - buf*48;
        int b = r / 3, q = r - (r/3)*3;
        st_cc8(hF + ((size_t)(buf*GRP + grp)*GBATCH + b)*512 + 500 + q*4, 0ULL);
    }
    gbarA(slots, grp, ub, 1);

    const int mA = lane & 15, kb = lane >> 4;

    for (int t = 0; t < SEQL; ++t){
        if ((t & 3) == 0){
            if (tid == 0){
                const int* f = xgdone + (t >> 2)*SLOTP;
                while (__hip_atomic_load(f, __ATOMIC_RELAXED, __HIP_MEMORY_SCOPE_AGENT) < 32)
                    __builtin_amdgcn_s_sleep(1);
            }
            asm volatile("" ::: "memory");
            __syncthreads();
        }

        const _Float16* hsrc = hF + (size_t)(((t&1)^1)*GRP + grp)*GBATCH*512;

        float xgv[4];
        #pragma unroll
        for (int g = 0; g < 4; ++g)
            xgv[g] = ld_cc4(xgT + (size_t)(g*HIDD + pu)*MCOL + t*64 + gb);

        if (w < 4){
            half8 bf[4];
            #pragma unroll
            for (int ks4 = 0; ks4 < 4; ++ks4){
                int ke = (w*4 + ks4)*32 + kb*8;            // f16 element offset in row
                const unsigned long long* p =
                    (const unsigned long long*)(hsrc + mA*512 + ke);
                union { unsigned long long q[2]; half8 h; } u;
                u.q[0] = ld_cc8(p);
                u.q[1] = ld_cc8(p + 1);
                bf[ks4] = u.h;
            }
            f32x4 acc[5] = {};
            #pragma unroll
            for (int rt = 0; rt < 5; ++rt){
                #pragma unroll
                for (int ks4 = 0; ks4 < 4; ++ks4){
                    int kByte = (w*4 + ks4)*64 + kb*16;
                    int m = rt*16 + mA;
                    int aOff = (m*1024 + kByte) ^ ((m & 7) << 4);
                    half8 af = *(const half8*)((const char*)Wl + aOff);
                    acc[rt] = __builtin_amdgcn_mfma_f32_16x16x32_f16(af, bf[ks4], acc[rt], 0, 0, 0);
                }
            }
            #pragma unroll
            for (int rt = 0; rt < 5; ++rt)
                #pragma unroll
                for (int r = 0; r < 4; ++r)
                    gl[(w*80 + rt*16 + kb*4 + r)*16 + mA] = acc[rt][r];
        }
        __syncthreads();

        {
            float g4[4];
            #pragma unroll
            for (int g = 0; g < 4; ++g){
                int row = g*UPB8 + puu;
                float s = gl[(0*80 + row)*16 + pb] + gl[(1*80 + row)*16 + pb]
                        + gl[(2*80 + row)*16 + pb] + gl[(3*80 + row)*16 + pb];
                s += xgv[g];
                g4[g] = s;
            }
            float si = sigmf(g4[0]), sf = sigmf(g4[1]);
            float tg = tanhf(g4[2]), so = sigmf(g4[3]);
            float cn = sf*cprev + si*tg;
            float hn = so*tanhf(cn);
            if (t < mylen){ cprev = cn; hprev = hn; }
        }
        if (t == SEQL-1){
            hqB[(size_t)gb*512 + pu] = hprev;   // final h, [b][512] f32
        } else {
            pack_store_h(hF, t & 1, grp, u0, w, lane, hprev);
            gbarA(slots, grp, ub, t + 2);
        }
    }
}

// ---------------- k_pair4: qp + ip/jp + pair MFMA + final epilogue (spill-free, 2 blocks/CU) ----------------
__global__ __launch_bounds__(256, 2) void k_pair4(
    const float* __restrict__ hqB, const float* __restrict__ conv,
    const float* __restrict__ g1w, const float* __restrict__ g1b,
    const float* __restrict__ g2w, const float* __restrict__ g2b,
    const float* __restrict__ f1w, const float* __restrict__ f1b,
    const float* __restrict__ f2w, const float* __restrict__ f2b,
    float* __restrict__ part, int* __restrict__ pcnt, float* __restrict__ out)
{
    __shared__ __align__(16) char smem[SM_TOTAL];
    float*    convl = (float*)(smem + SM_CONV);
    float*    g1ij  = (float*)(smem + SM_G1IJ);
    float*    hb    = (float*)(smem + SM_HB);
    float*    qpl   = (float*)(smem + SM_QPL);
    _Float16* jpl   = (_Float16*)(smem + SM_JPL);
    _Float16* basel = (_Float16*)(smem + SM_BASEL);
    _Float16* g2h   = (_Float16*)(smem + SM_G2H);

    int b  = blockIdx.x >> 2;
    int ic = blockIdx.x & 3;
    int tid = threadIdx.x;
    int w = tid >> 6, lane = tid & 63;
    int ncol = lane & 15, kb = lane >> 4;

    // phase 1: stage shared inputs
    for (int i = tid; i < 24*64; i += 256)
        convl[i] = conv[(size_t)b*24*64 + i];
    for (int i = tid; i < 100*48; i += 256){
        int n = i/48, c = i - n*48;
        g1ij[n*48 + c] = g1w[(size_t)n*548 + 500 + c];
    }
    for (int i = tid; i < 512; i += 256) hb[i] = hqB[(size_t)b*512 + i];
    for (int i = tid; i < 112*136; i += 256){
        int n = i/136, k = i - n*136;
        g2h[n*136 + k] = (n < 100 && k < 100) ? (_Float16)g2w[n*GHID + k] : (_Float16)0.f;
    }
    __syncthreads();

    // phase 2: qpl (f32) + jpl (f16) for all 64 j's
    if (tid < 100){
        const float4* wr = (const float4*)(g1w + (size_t)tid*548);
        float s = g1b[tid];
        #pragma unroll 5
        for (int k4 = 0; k4 < 125; ++k4){
            float4 v = wr[k4];
            s += v.x*hb[k4*4] + v.y*hb[k4*4+1] + v.z*hb[k4*4+2] + v.w*hb[k4*4+3];
        }
        qpl[tid] = s;
    }
    for (int i = tid; i < NOBJ*100; i += 256){
        int o = i / 100, n = i - (i/100)*100;
        float sj = 0.f;
        #pragma unroll
        for (int c = 0; c < 24; ++c) sj += convl[c*64 + o] * g1ij[n*48 + c];
        jpl[o*136 + n] = (_Float16)sj;
    }
    for (int i = tid; i < NOBJ*36; i += 256)
        jpl[(i/36)*136 + 100 + (i - (i/36)*36)] = (_Float16)0.f;
    __syncthreads();   // qpl ready

    // phase 3: basel = f16(qpl + ip) for own 16 i-rows
    for (int i = tid; i < 16*136; i += 256){
        int il = i / 136, k = i - il*136;
        float v = 0.f;
        if (k < 100){
            float si = 0.f;
            int o = ic*16 + il;
            #pragma unroll
            for (int c = 0; c < 24; ++c) si += convl[c*64 + o] * g1ij[k*48 + 24 + c];
            v = qpl[k] + si;
        }
        basel[il*136 + k] = (_Float16)v;
    }
    float gb7[7];
    #pragma unroll
    for (int nt = 0; nt < 7; ++nt){
        int n = nt*16 + ncol;
        gb7[nt] = (n < 100) ? g2b[n] : 0.f;
    }
    __syncthreads();

    // phase 4: pair MFMA loop (unroll-1 outer loops -> one acc set live, no spill)
    f32x4 sacc[7] = {};
    #pragma unroll 1
    for (int it = 0; it < 4; ++it){
        int il = w*4 + it;
        #pragma unroll 1
        for (int jc = 0; jc < 4; ++jc){
            f32x4 acc[7] = {};
            int jrow = jc*16 + ncol;
            #pragma unroll
            for (int ks = 0; ks < 4; ++ks){
                int k0 = ks*32 + kb*8;
                half8 jv = *(const half8*)&jpl[jrow*136 + k0];
                half8 bv = *(const half8*)&basel[il*136 + k0];
                half8 af;
                #pragma unroll
                for (int e = 0; e < 8; ++e){
                    _Float16 s = jv[e] + bv[e];
                    af[e] = (s > (_Float16)0.f) ? s : (_Float16)0.f;
                }
                #pragma unroll
                for (int nt = 0; nt < 7; ++nt){
                    half8 bf = *(const half8*)&g2h[(nt*16 + ncol)*136 + k0];
                    acc[nt] = __builtin_amdgcn_mfma_f32_16x16x32_f16(af, bf, acc[nt], 0, 0, 0);
                }
            }
            #pragma unroll
            for (int nt = 0; nt < 7; ++nt)
                #pragma unroll
                for (int r = 0; r < 4; ++r)
                    sacc[nt][r] += fmaxf(acc[nt][r] + gb7[nt], 0.f);
        }
    }
    // staging region dead from here -> epilogue arrays alias it
    float* redx = (float*)(smem + SM_REDX);
    #pragma unroll
    for (int nt = 0; nt < 7; ++nt){
        float s = sacc[nt][0] + sacc[nt][1] + sacc[nt][2] + sacc[nt][3];
        s += __shfl_xor(s, 16);
        s += __shfl_xor(s, 32);
        if (lane < 16) redx[w*112 + nt*16 + lane] = s;
    }
    __syncthreads();
    if (tid < 100){
        float p = redx[0*112+tid] + redx[1*112+tid] + redx[2*112+tid] + redx[3*112+tid];
        st_cc4(part + (size_t)(b*4 + ic)*GHID + tid, p);
    }
    __syncthreads();   // drain part stores before counter RMW

    int* lastf = (int*)(smem + SM_LASTF);
    if (tid == 0){
        int old = __hip_atomic_fetch_add(pcnt + b*SLOTP, 1,
                                         __ATOMIC_ACQ_REL, __HIP_MEMORY_SCOPE_AGENT);
        *lastf = (old == 3);
    }
    __syncthreads();
    if (!*lastf) return;

    // ---- epilogue (last block for this b) ----
    float* gs  = (float*)(smem + SM_GS);
    float* fh  = (float*)(smem + SM_FH);
    float* lg  = (float*)(smem + SM_LG);
    float* red = (float*)(smem + SM_RED);
    float* red2= (float*)(smem + SM_RED2);

    if (tid < 100){
        float s = 0.f;
        #pragma unroll
        for (int ic2 = 0; ic2 < 4; ++ic2)
            s += ld_cc4(part + (size_t)(b*4 + ic2)*GHID + tid);
        gs[tid] = s;
    }
    __syncthreads();
    if (tid < 100){
        const float4* wr = (const float4*)(f1w + (size_t)tid*GHID);
        float s = f1b[tid];
        #pragma unroll 5
        for (int k4 = 0; k4 < 25; ++k4){
            float4 v = wr[k4];
            s += v.x*gs[k4*4] + v.y*gs[k4*4+1] + v.z*gs[k4*4+2] + v.w*gs[k4*4+3];
        }
        fh[tid] = fmaxf(s, 0.f);
    }
    __syncthreads();
    for (int n = tid; n < ANSN; n += 256){
        const float4* wr = (const float4*)(f2w + (size_t)n*GHID);
        float s = f2b[n];
        #pragma unroll 5
        for (int k4 = 0; k4 < 25; ++k4){
            float4 v = wr[k4];
            s += v.x*fh[k4*4] + v.y*fh[k4*4+1] + v.z*fh[k4*4+2] + v.w*fh[k4*4+3];
        }
        lg[n] = fmaxf(s, 0.f);
    }
    __syncthreads();
    float mx = -1e30f;
    for (int n = tid; n < ANSN; n += 256) mx = fmaxf(mx, lg[n]);
    #pragma unroll
    for (int off = 32; off > 0; off >>= 1) mx = fmaxf(mx, __shfl_xor(mx, off));
    if ((tid & 63) == 0) red[tid >> 6] = mx;
    __syncthreads();
    mx = fmaxf(fmaxf(red[0], red[1]), fmaxf(red[2], red[3]));
    float se = 0.f;
    for (int n = tid; n < ANSN; n += 256) se += expf(lg[n]-mx);
    #pragma unroll
    for (int off = 32; off > 0; off >>= 1) se += __shfl_xor(se, off);
    if ((tid & 63) == 0) red2[tid >> 6] = se;
    __syncthreads();
    se = red2[0]+red2[1]+red2[2]+red2[3];
    float lse = logf(se);
    for (int n = tid; n < ANSN; n += 256) out[(size_t)b*ANSN + n] = lg[n] - mx - lse;
}

extern "C" void kernel_launch(void* const* d_in, const int* in_sizes, int n_in,
                              void* d_out, int out_size, void* d_ws, size_t ws_size,
                              hipStream_t stream)
{
    const int*   sent  = (const int*)  d_in[0];
    const float* conv  = (const float*)d_in[1];
    const int*   lens  = (const int*)  d_in[2];
    const float* table = (const float*)d_in[3];
    const float* W_ih  = (const float*)d_in[4];
    const float* W_hh  = (const float*)d_in[5];
    const float* b_ih  = (const float*)d_in[6];
    const float* b_hh  = (const float*)d_in[7];
    const float* h0    = (const float*)d_in[8];
    const float* c0    = (const float*)d_in[9];
    const float* g1_w  = (const float*)d_in[10];
    const float* g1_b  = (const float*)d_in[11];
    const float* g2_w  = (const float*)d_in[12];
    const float* g2_b  = (const float*)d_in[13];
    const float* f1_w  = (const float*)d_in[14];
    const float* f1_b  = (const float*)d_in[15];
    const float* f2_w  = (const float*)d_in[16];
    const float* f2_b  = (const float*)d_in[17];
    float* out = (float*)d_out;

    float* ws    = (float*)d_ws;
    int*   slots = (int*)d_ws;                          // [0, 3200) ints
    int*   xgdone= (int*)d_ws + NBLK*SLOTP;             // [3200, 3456) ints
    int*   pcnt  = (int*)d_ws + NBLK*SLOTP + 8*SLOTP;   // [3456, 5504) ints
    _Float16* hF = (_Float16*)(ws + 16384);             // 2*4*16*512 f16 = 128 KB
    float* hqB  = ws + 16384 + 32768;                   // 64*512 f32
    float* xgT  = hqB + 64*512;                         // 2000*2048 f32
    float* part = xgT + (size_t)4*HIDD*MCOL;            // 256*100

    // 0. zero barrier slots + xg flags + pair counters (deterministic across replays)
    hipMemsetAsync(slots, 0, (NBLK + 8 + BATCH)*SLOTP*sizeof(int), stream);

    // 1. fused xg + LSTM: 356 blocks (100 lstm + 256 xg workers)
    k_mega<<<NBLK + NXG, 320, 0, stream>>>(sent, table, W_ih, b_ih, b_hh,
                                           hF, hqB, xgT, W_hh, h0, c0, lens,
                                           slots, xgdone);

    // 2. fused qp/ipjp + pair MFMA + final epilogue (256 blocks, 2 blocks/CU)
    k_pair4<<<BATCH*4, 256, 0, stream>>>(hqB, conv, g1_w, g1_b, g2_w, g2_b,
                                         f1_w, f1_b, f2_w, f2_b, part, pcnt, out);
}

// Round 22
// 212.842 us; speedup vs baseline: 1.6591x; 1.0103x over previous
//
#include <hip/hip_runtime.h>
#include <cmath>

#define BATCH 64
#define SEQL  32
#define EMBD  300
#define HIDD  500
#define NOBJ  64
#define GHID  100
#define ANSN  1000
#define MCOL  2048   // t*64+b column dimension

// partition: 4 batch-groups x 25 unit-blocks
#define GRP    4
#define GBATCH 16
#define BPG    25
#define UPB8   20
#define NBLK   (GRP*BPG)   // 100 lstm blocks
#define NXG    256         // xg worker blocks (8 tc x 32 n-tiles)
#define SLOTP  32          // slot padding in ints (128 B)

#define KPADX  328         // xg LDS row stride in f16 (656 B)
#define TCH    4           // timesteps per xg block

// k_pair4 LDS layout (pre-MFMA staging region aliased by epilogue arrays)
#define SM_CONV   0        // float [24][64]   = 6144
#define SM_G1IJ   6144     // float [100][48]  = 19200
#define SM_HB     25344    // float [512]      = 2048
#define SM_QPL    27392    // float [112]      = 448   (pre total 27840)
#define SM_REDX   0        // float [4][112]   = 1792  (post, aliases conv)
#define SM_GS     1792     // float [112]
#define SM_FH     2240     // float [112]
#define SM_LG     2688     // float [1000]
#define SM_RED    6688     // float [4]
#define SM_RED2   6704     // float [4]
#define SM_LASTF  6720     // int
#define SM_JPL    27840    // f16 [64][136]    = 17408
#define SM_BASEL  45248    // f16 [16][136]    = 4352
#define SM_G2H    49600    // f16 [112][136]   = 30464
#define SM_TOTAL  80064

typedef _Float16 half8 __attribute__((ext_vector_type(8)));
typedef float    f32x4 __attribute__((ext_vector_type(4)));

__device__ __forceinline__ float sigmf(float x){ return 1.f/(1.f+expf(-x)); }

// sc1 (coherence-point) primitives: RELAXED agent-scope atomics, no cache-wide fences
__device__ __forceinline__ unsigned long long ld_cc8(const unsigned long long* p){
    return __hip_atomic_load(p, __ATOMIC_RELAXED, __HIP_MEMORY_SCOPE_AGENT);
}
__device__ __forceinline__ void st_cc8(_Float16* p, unsigned long long v){
    __hip_atomic_store((unsigned long long*)p, v, __ATOMIC_RELAXED, __HIP_MEMORY_SCOPE_AGENT);
}
__device__ __forceinline__ float ld_cc4(const float* p){
    return __hip_atomic_load(p, __ATOMIC_RELAXED, __HIP_MEMORY_SCOPE_AGENT);
}
__device__ __forceinline__ void st_cc4(float* p, float v){
    __hip_atomic_store(p, v, __ATOMIC_RELAXED, __HIP_MEMORY_SCOPE_AGENT);
}

// group-local all-to-all barrier (one hop, fence-free; proven r8-r21)
__device__ __forceinline__ void gbarA(int* slots, int grp, int ub, int seq)
{
    __syncthreads();
    if (threadIdx.x == 0)
        __hip_atomic_store(slots + (grp*BPG + ub)*SLOTP, seq,
                           __ATOMIC_RELAXED, __HIP_MEMORY_SCOPE_AGENT);
    if (threadIdx.x < BPG){
        int* s = slots + (grp*BPG + threadIdx.x)*SLOTP;
        while (__hip_atomic_load(s, __ATOMIC_RELAXED, __HIP_MEMORY_SCOPE_AGENT) < seq)
            __builtin_amdgcn_s_sleep(1);
    }
    asm volatile("" ::: "memory");
    __syncthreads();
}

// wave-local h pack (r20-proven)
__device__ __forceinline__ void pack_store_h(
    _Float16* hF, int buf, int grp, int u0, int w, int lane, float hval)
{
    union { _Float16 f; unsigned short s; } cv;
    cv.f = (_Float16)hval;
    unsigned int h2 = cv.s;
    int base = lane & 15;
    unsigned int x0 = (unsigned int)__shfl((int)h2, base +  0, 64);
    unsigned int x1 = (unsigned int)__shfl((int)h2, base + 16, 64);
    unsigned int x2 = (unsigned int)__shfl((int)h2, base + 32, 64);
    unsigned int x3 = (unsigned int)__shfl((int)h2, base + 48, 64);
    if (lane < 16){
        unsigned long long v = (unsigned long long)(x0 & 0xFFFFu)
                             | ((unsigned long long)(x1 & 0xFFFFu) << 16)
                             | ((unsigned long long)(x2 & 0xFFFFu) << 32)
                             | ((unsigned long long)(x3 & 0xFFFFu) << 48);
        st_cc8(hF + ((size_t)(buf*GRP + grp)*GBATCH + lane)*512 + u0 + w*4, v);
    }
}

// ---------------- k_mega: blocks 0..99 = LSTM, 100..355 = xg workers (r21 verbatim) ----------------
__global__ __launch_bounds__(320, 1) void k_mega(
    const int* __restrict__ sent, const float* __restrict__ table,
    const float* __restrict__ Wih, const float* __restrict__ b_ih, const float* __restrict__ b_hh,
    _Float16* __restrict__ hF, float* __restrict__ hqB, float* __restrict__ xgT,
    const float* __restrict__ Whh, const float* __restrict__ h0, const float* __restrict__ c0,
    const int* __restrict__ lens, int* __restrict__ slots, int* __restrict__ xgdone)
{
    __shared__ __align__(16) char smem[102400];

    int tid = threadIdx.x, bid = blockIdx.x;
    int w = tid >> 6, lane = tid & 63;

    if (bid >= NBLK){
        _Float16* Sh  = (_Float16*)smem;                 // [64*KPADX] = 41984 B
        int*      sidx= (int*)(smem + 41984);            // [TCH][64]
        int xb = bid - NBLK;
        int tc = xb >> 5;                 // 0..7
        int n0 = (xb & 31) * 64;
        int rA = lane & 15, kb = lane >> 4;

        for (int i = tid; i < TCH*64; i += 320){
            int tt = i >> 6, b = i & 63;
            sidx[tt*64 + b] = sent[b*SEQL + tc*TCH + tt];
        }
        for (int i = tid; i < 64*75; i += 320){
            int n = i / 75, c4 = i - (i/75)*75;
            float4 v = {0.f,0.f,0.f,0.f};
            if (n0 + n < 2000)
                v = *(const float4*)(Wih + (size_t)(n0+n)*300 + c4*4);
            _Float16* dst = &Sh[n*KPADX + c4*4];
            dst[0]=(_Float16)v.x; dst[1]=(_Float16)v.y; dst[2]=(_Float16)v.z; dst[3]=(_Float16)v.w;
        }
        for (int i = tid; i < 64*20; i += 320){   // zero pad k 300..319
            int n = i / 20, k = 300 + (i - (i/20)*20);
            Sh[n*KPADX + k] = (_Float16)0.f;
        }
        __syncthreads();
        half8 areg[10];
        float biasr[4];
        if (w < 4){
            #pragma unroll
            for (int ks = 0; ks < 10; ++ks)
                areg[ks] = *(const half8*)&Sh[(w*16 + rA)*KPADX + ks*32 + kb*8];
            #pragma unroll
            for (int r = 0; r < 4; ++r){
                int n = n0 + w*16 + kb*4 + r;
                biasr[r] = (n < 2000) ? b_ih[n] + b_hh[n] : 0.f;
            }
        }
        __syncthreads();   // all A reads done before B overwrites Sh

        for (int tt = 0; tt < TCH; ++tt){
            for (int i = tid; i < 64*75; i += 320){
                int m = i / 75, c4 = i - (i/75)*75;
                float4 v = *(const float4*)(table + (size_t)sidx[tt*64 + m]*300 + c4*4);
                _Float16* dst = &Sh[m*KPADX + c4*4];
                dst[0]=(_Float16)v.x; dst[1]=(_Float16)v.y; dst[2]=(_Float16)v.z; dst[3]=(_Float16)v.w;
            }
            for (int i = tid; i < 64*20; i += 320){
                int m = i / 20, k = 300 + (i - (i/20)*20);
                Sh[m*KPADX + k] = (_Float16)0.f;
            }
            __syncthreads();

            if (w < 4){
                f32x4 acc[4] = {};
                #pragma unroll
                for (int ks = 0; ks < 10; ++ks){
                    #pragma unroll
                    for (int mc = 0; mc < 4; ++mc){
                        half8 bf = *(const half8*)&Sh[(mc*16 + rA)*KPADX + ks*32 + kb*8];
                        acc[mc] = __builtin_amdgcn_mfma_f32_16x16x32_f16(areg[ks], bf, acc[mc], 0, 0, 0);
                    }
                }
                #pragma unroll
                for (int r = 0; r < 4; ++r){
                    int n = n0 + w*16 + kb*4 + r;
                    if (n < 2000){
                        #pragma unroll
                        for (int mc = 0; mc < 4; ++mc)
                            st_cc4(xgT + (size_t)n*MCOL + (tc*TCH+tt)*64 + mc*16 + rA,
                                   acc[mc][r] + biasr[r]);
                    }
                }
            }
            __syncthreads();
        }
        if (tid == 0)
            __hip_atomic_fetch_add(xgdone + tc*SLOTP, 1,
                                   __ATOMIC_RELAXED, __HIP_MEMORY_SCOPE_AGENT);
        return;
    }

    // ======== LSTM (r21 verbatim) ========
    _Float16* Wl  = (_Float16*)smem;                 // [80*512] swizzled, 81920 B
    float*    gl  = (float*)(smem + 81920);          // [4*80*16], 20480 B

    int grp = bid / BPG, ub = bid - grp*BPG;
    int u0  = ub * UPB8;

    int pb  = tid & 15, puu = tid >> 4;        // puu 0..19
    int pu  = u0 + puu;
    int gb  = grp*GBATCH + pb;                 // global batch row
    float cprev = c0[gb*HIDD + pu];
    float hprev = h0[gb*HIDD + pu];
    int   mylen = lens[gb];

    for (int i = tid; i < 80*512; i += 320){
        int m = i >> 9, k = i & 511;
        int g = m / UPB8, uu = m - g*UPB8;
        float v = (k < HIDD) ? Whh[(size_t)(g*HIDD + u0 + uu)*HIDD + k] : 0.f;
        int off = (i*2) ^ ((m & 7) << 4);
        *(_Float16*)((char*)Wl + off) = (_Float16)v;
    }
    pack_store_h(hF, 1, grp, u0, w, lane, hprev);
    if (ub == 0 && tid >= 128 && tid < 224){   // zero k-pad 500..511, both buffers
        int j = tid - 128;
        int buf = j / 48, r = j - buf*48;
        int b = r / 3, q = r - (r/3)*3;
        st_cc8(hF + ((size_t)(buf*GRP + grp)*GBATCH + b)*512 + 500 + q*4, 0ULL);
    }
    gbarA(slots, grp, ub, 1);

    const int mA = lane & 15, kb = lane >> 4;

    for (int t = 0; t < SEQL; ++t){
        if ((t & 3) == 0){
            if (tid == 0){
                const int* f = xgdone + (t >> 2)*SLOTP;
                while (__hip_atomic_load(f, __ATOMIC_RELAXED, __HIP_MEMORY_SCOPE_AGENT) < 32)
                    __builtin_amdgcn_s_sleep(1);
            }
            asm volatile("" ::: "memory");
            __syncthreads();
        }

        const _Float16* hsrc = hF + (size_t)(((t&1)^1)*GRP + grp)*GBATCH*512;

        float xgv[4];
        #pragma unroll
        for (int g = 0; g < 4; ++g)
            xgv[g] = ld_cc4(xgT + (size_t)(g*HIDD + pu)*MCOL + t*64 + gb);

        if (w < 4){
            half8 bf[4];
            #pragma unroll
            for (int ks4 = 0; ks4 < 4; ++ks4){
                int ke = (w*4 + ks4)*32 + kb*8;            // f16 element offset in row
                const unsigned long long* p =
                    (const unsigned long long*)(hsrc + mA*512 + ke);
                union { unsigned long long q[2]; half8 h; } u;
                u.q[0] = ld_cc8(p);
                u.q[1] = ld_cc8(p + 1);
                bf[ks4] = u.h;
            }
            f32x4 acc[5] = {};
            #pragma unroll
            for (int rt = 0; rt < 5; ++rt){
                #pragma unroll
                for (int ks4 = 0; ks4 < 4; ++ks4){
                    int kByte = (w*4 + ks4)*64 + kb*16;
                    int m = rt*16 + mA;
                    int aOff = (m*1024 + kByte) ^ ((m & 7) << 4);
                    half8 af = *(const half8*)((const char*)Wl + aOff);
                    acc[rt] = __builtin_amdgcn_mfma_f32_16x16x32_f16(af, bf[ks4], acc[rt], 0, 0, 0);
                }
            }
            #pragma unroll
            for (int rt = 0; rt < 5; ++rt)
                #pragma unroll
                for (int r = 0; r < 4; ++r)
                    gl[(w*80 + rt*16 + kb*4 + r)*16 + mA] = acc[rt][r];
        }
        __syncthreads();

        {
            float g4[4];
            #pragma unroll
            for (int g = 0; g < 4; ++g){
                int row = g*UPB8 + puu;
                float s = gl[(0*80 + row)*16 + pb] + gl[(1*80 + row)*16 + pb]
                        + gl[(2*80 + row)*16 + pb] + gl[(3*80 + row)*16 + pb];
                s += xgv[g];
                g4[g] = s;
            }
            float si = sigmf(g4[0]), sf = sigmf(g4[1]);
            float tg = tanhf(g4[2]), so = sigmf(g4[3]);
            float cn = sf*cprev + si*tg;
            float hn = so*tanhf(cn);
            if (t < mylen){ cprev = cn; hprev = hn; }
        }
        if (t == SEQL-1){
            hqB[(size_t)gb*512 + pu] = hprev;   // final h, [b][512] f32
        } else {
            pack_store_h(hF, t & 1, grp, u0, w, lane, hprev);
            gbarA(slots, grp, ub, t + 2);
        }
    }
}

// ---------------- k_pair4: qp + ip/jp + pair MFMA + final epilogue ----------------
// (256,1): no VGPR cap -> no spill; 256 blocks on 256 CUs = 1/CU anyway.
// pcnt RMW relaxed: ordering via syncthreads vmcnt-drain + sc1 part loads (r8-proven chain).
__global__ __launch_bounds__(256, 1) void k_pair4(
    const float* __restrict__ hqB, const float* __restrict__ conv,
    const float* __restrict__ g1w, const float* __restrict__ g1b,
    const float* __restrict__ g2w, const float* __restrict__ g2b,
    const float* __restrict__ f1w, const float* __restrict__ f1b,
    const float* __restrict__ f2w, const float* __restrict__ f2b,
    float* __restrict__ part, int* __restrict__ pcnt, float* __restrict__ out)
{
    __shared__ __align__(16) char smem[SM_TOTAL];
    float*    convl = (float*)(smem + SM_CONV);
    float*    g1ij  = (float*)(smem + SM_G1IJ);
    float*    hb    = (float*)(smem + SM_HB);
    float*    qpl   = (float*)(smem + SM_QPL);
    _Float16* jpl   = (_Float16*)(smem + SM_JPL);
    _Float16* basel = (_Float16*)(smem + SM_BASEL);
    _Float16* g2h   = (_Float16*)(smem + SM_G2H);

    int b  = blockIdx.x >> 2;
    int ic = blockIdx.x & 3;
    int tid = threadIdx.x;
    int w = tid >> 6, lane = tid & 63;
    int ncol = lane & 15, kb = lane >> 4;

    // phase 1: stage shared inputs
    for (int i = tid; i < 24*64; i += 256)
        convl[i] = conv[(size_t)b*24*64 + i];
    for (int i = tid; i < 100*48; i += 256){
        int n = i/48, c = i - n*48;
        g1ij[n*48 + c] = g1w[(size_t)n*548 + 500 + c];
    }
    for (int i = tid; i < 512; i += 256) hb[i] = hqB[(size_t)b*512 + i];
    for (int i = tid; i < 112*136; i += 256){
        int n = i/136, k = i - n*136;
        g2h[n*136 + k] = (n < 100 && k < 100) ? (_Float16)g2w[n*GHID + k] : (_Float16)0.f;
    }
    __syncthreads();

    // phase 2: qpl (f32) + jpl (f16) for all 64 j's
    if (tid < 100){
        const float4* wr = (const float4*)(g1w + (size_t)tid*548);
        float s = g1b[tid];
        #pragma unroll 5
        for (int k4 = 0; k4 < 125; ++k4){
            float4 v = wr[k4];
            s += v.x*hb[k4*4] + v.y*hb[k4*4+1] + v.z*hb[k4*4+2] + v.w*hb[k4*4+3];
        }
        qpl[tid] = s;
    }
    for (int i = tid; i < NOBJ*100; i += 256){
        int o = i / 100, n = i - (i/100)*100;
        float sj = 0.f;
        #pragma unroll
        for (int c = 0; c < 24; ++c) sj += convl[c*64 + o] * g1ij[n*48 + c];
        jpl[o*136 + n] = (_Float16)sj;
    }
    for (int i = tid; i < NOBJ*36; i += 256)
        jpl[(i/36)*136 + 100 + (i - (i/36)*36)] = (_Float16)0.f;
    __syncthreads();   // qpl ready

    // phase 3: basel = f16(qpl + ip) for own 16 i-rows
    for (int i = tid; i < 16*136; i += 256){
        int il = i / 136, k = i - il*136;
        float v = 0.f;
        if (k < 100){
            float si = 0.f;
            int o = ic*16 + il;
            #pragma unroll
            for (int c = 0; c < 24; ++c) si += convl[c*64 + o] * g1ij[k*48 + 24 + c];
            v = qpl[k] + si;
        }
        basel[il*136 + k] = (_Float16)v;
    }
    float gb7[7];
    #pragma unroll
    for (int nt = 0; nt < 7; ++nt){
        int n = nt*16 + ncol;
        gb7[nt] = (n < 100) ? g2b[n] : 0.f;
    }
    __syncthreads();

    // phase 4: pair MFMA loop (unroll-1 outer loops -> one acc set live)
    f32x4 sacc[7] = {};
    #pragma unroll 1
    for (int it = 0; it < 4; ++it){
        int il = w*4 + it;
        #pragma unroll 1
        for (int jc = 0; jc < 4; ++jc){
            f32x4 acc[7] = {};
            int jrow = jc*16 + ncol;
            #pragma unroll
            for (int ks = 0; ks < 4; ++ks){
                int k0 = ks*32 + kb*8;
                half8 jv = *(const half8*)&jpl[jrow*136 + k0];
                half8 bv = *(const half8*)&basel[il*136 + k0];
                half8 af;
                #pragma unroll
                for (int e = 0; e < 8; ++e){
                    _Float16 s = jv[e] + bv[e];
                    af[e] = (s > (_Float16)0.f) ? s : (_Float16)0.f;
                }
                #pragma unroll
                for (int nt = 0; nt < 7; ++nt){
                    half8 bf = *(const half8*)&g2h[(nt*16 + ncol)*136 + k0];
                    acc[nt] = __builtin_amdgcn_mfma_f32_16x16x32_f16(af, bf, acc[nt], 0, 0, 0);
                }
            }
            #pragma unroll
            for (int nt = 0; nt < 7; ++nt)
                #pragma unroll
                for (int r = 0; r < 4; ++r)
                    sacc[nt][r] += fmaxf(acc[nt][r] + gb7[nt], 0.f);
        }
    }
    // staging region dead from here -> epilogue arrays alias it
    float* redx = (float*)(smem + SM_REDX);
    #pragma unroll
    for (int nt = 0; nt < 7; ++nt){
        float s = sacc[nt][0] + sacc[nt][1] + sacc[nt][2] + sacc[nt][3];
        s += __shfl_xor(s, 16);
        s += __shfl_xor(s, 32);
        if (lane < 16) redx[w*112 + nt*16 + lane] = s;
    }
    __syncthreads();
    if (tid < 100){
        float p = redx[0*112+tid] + redx[1*112+tid] + redx[2*112+tid] + redx[3*112+tid];
        st_cc4(part + (size_t)(b*4 + ic)*GHID + tid, p);
    }
    __syncthreads();   // drain part stores before counter RMW

    int* lastf = (int*)(smem + SM_LASTF);
    if (tid == 0){
        int old = __hip_atomic_fetch_add(pcnt + b*SLOTP, 1,
                                         __ATOMIC_RELAXED, __HIP_MEMORY_SCOPE_AGENT);
        *lastf = (old == 3);
    }
    __syncthreads();
    if (!*lastf) return;

    // ---- epilogue (last block for this b) ----
    float* gs  = (float*)(smem + SM_GS);
    float* fh  = (float*)(smem + SM_FH);
    float* lg  = (float*)(smem + SM_LG);
    float* red = (float*)(smem + SM_RED);
    float* red2= (float*)(smem + SM_RED2);

    if (tid < 100){
        float s = 0.f;
        #pragma unroll
        for (int ic2 = 0; ic2 < 4; ++ic2)
            s += ld_cc4(part + (size_t)(b*4 + ic2)*GHID + tid);
        gs[tid] = s;
    }
    __syncthreads();
    if (tid < 100){
        const float4* wr = (const float4*)(f1w + (size_t)tid*GHID);
        float s = f1b[tid];
        #pragma unroll 5
        for (int k4 = 0; k4 < 25; ++k4){
            float4 v = wr[k4];
            s += v.x*gs[k4*4] + v.y*gs[k4*4+1] + v.z*gs[k4*4+2] + v.w*gs[k4*4+3];
        }
        fh[tid] = fmaxf(s, 0.f);
    }
    __syncthreads();
    for (int n = tid; n < ANSN; n += 256){
        const float4* wr = (const float4*)(f2w + (size_t)n*GHID);
        float s = f2b[n];
        #pragma unroll 5
        for (int k4 = 0; k4 < 25; ++k4){
            float4 v = wr[k4];
            s += v.x*fh[k4*4] + v.y*fh[k4*4+1] + v.z*fh[k4*4+2] + v.w*fh[k4*4+3];
        }
        lg[n] = fmaxf(s, 0.f);
    }
    __syncthreads();
    float mx = -1e30f;
    for (int n = tid; n < ANSN; n += 256) mx = fmaxf(mx, lg[n]);
    #pragma unroll
    for (int off = 32; off > 0; off >>= 1) mx = fmaxf(mx, __shfl_xor(mx, off));
    if ((tid & 63) == 0) red[tid >> 6] = mx;
    __syncthreads();
    mx = fmaxf(fmaxf(red[0], red[1]), fmaxf(red[2], red[3]));
    float se = 0.f;
    for (int n = tid; n < ANSN; n += 256) se += expf(lg[n]-mx);
    #pragma unroll
    for (int off = 32; off > 0; off >>= 1) se += __shfl_xor(se, off);
    if ((tid & 63) == 0) red2[tid >> 6] = se;
    __syncthreads();
    se = red2[0]+red2[1]+red2[2]+red2[3];
    float lse = logf(se);
    for (int n = tid; n < ANSN; n += 256) out[(size_t)b*ANSN + n] = lg[n] - mx - lse;
}

extern "C" void kernel_launch(void* const* d_in, const int* in_sizes, int n_in,
                              void* d_out, int out_size, void* d_ws, size_t ws_size,
                              hipStream_t stream)
{
    const int*   sent  = (const int*)  d_in[0];
    const float* conv  = (const float*)d_in[1];
    const int*   lens  = (const int*)  d_in[2];
    const float* table = (const float*)d_in[3];
    const float* W_ih  = (const float*)d_in[4];
    const float* W_hh  = (const float*)d_in[5];
    const float* b_ih  = (const float*)d_in[6];
    const float* b_hh  = (const float*)d_in[7];
    const float* h0    = (const float*)d_in[8];
    const float* c0    = (const float*)d_in[9];
    const float* g1_w  = (const float*)d_in[10];
    const float* g1_b  = (const float*)d_in[11];
    const float* g2_w  = (const float*)d_in[12];
    const float* g2_b  = (const float*)d_in[13];
    const float* f1_w  = (const float*)d_in[14];
    const float* f1_b  = (const float*)d_in[15];
    const float* f2_w  = (const float*)d_in[16];
    const float* f2_b  = (const float*)d_in[17];
    float* out = (float*)d_out;

    float* ws    = (float*)d_ws;
    int*   slots = (int*)d_ws;                          // [0, 3200) ints
    int*   xgdone= (int*)d_ws + NBLK*SLOTP;             // [3200, 3456) ints
    int*   pcnt  = (int*)d_ws + NBLK*SLOTP + 8*SLOTP;   // [3456, 5504) ints
    _Float16* hF = (_Float16*)(ws + 16384);             // 2*4*16*512 f16 = 128 KB
    float* hqB  = ws + 16384 + 32768;                   // 64*512 f32
    float* xgT  = hqB + 64*512;                         // 2000*2048 f32
    float* part = xgT + (size_t)4*HIDD*MCOL;            // 256*100

    // 0. zero barrier slots + xg flags + pair counters (deterministic across replays)
    hipMemsetAsync(slots, 0, (NBLK + 8 + BATCH)*SLOTP*sizeof(int), stream);

    // 1. fused xg + LSTM: 356 blocks (100 lstm + 256 xg workers)
    k_mega<<<NBLK + NXG, 320, 0, stream>>>(sent, table, W_ih, b_ih, b_hh,
                                           hF, hqB, xgT, W_hh, h0, c0, lens,
                                           slots, xgdone);

    // 2. fused qp/ipjp + pair MFMA + final epilogue (256 blocks)
    k_pair4<<<BATCH*4, 256, 0, stream>>>(hqB, conv, g1_w, g1_b, g2_w, g2_b,
                                         f1_w, f1_b, f2_w, f2_b, part, pcnt, out);
}

// Round 23
// 212.535 us; speedup vs baseline: 1.6615x; 1.0014x over previous
//
#include <hip/hip_runtime.h>
#include <cmath>

#define BATCH 64
#define SEQL  32
#define EMBD  300
#define HIDD  500
#define NOBJ  64
#define GHID  100
#define ANSN  1000
#define MCOL  2048   // t*64+b column dimension

// partition: 4 batch-groups x 25 unit-blocks
#define GRP    4
#define GBATCH 16
#define BPG    25
#define UPB8   20
#define NBLK   (GRP*BPG)   // 100 lstm blocks
#define NXG    256         // xg worker blocks (8 tc x 32 n-tiles)
#define SLOTP  32          // slot padding in ints (128 B)

#define KPADX  328         // xg LDS row stride in f16 (656 B)
#define TCH    4           // timesteps per xg block

// k_pair5 LDS layout (pre-MFMA staging region aliased by epilogue arrays)
#define SM_CONV   0        // float [24][64]   = 6144
#define SM_G1IJ   6144     // float [100][48]  = 19200
#define SM_HB     25344    // float [512]      = 2048
#define SM_QPL    27392    // float [112]      = 448   (pre total 27840)
#define SM_REDX   0        // float [4][112]   = 1792  (post, aliases conv)
#define SM_GS     1792     // float [112]
#define SM_FH     2240     // float [112]
#define SM_LG     2688     // float [1000]
#define SM_RED    6688     // float [4]
#define SM_RED2   6704     // float [4]
#define SM_LASTF  6720     // int
#define SM_JPL    27840    // f16 [64][136]    = 17408
#define SM_BASEL  45248    // f16 [16][136]    = 4352
#define SM_G2H    49600    // f16 [112][136]   = 30464
#define SM_TOTAL  80064

typedef _Float16 half8 __attribute__((ext_vector_type(8)));
typedef float    f32x4 __attribute__((ext_vector_type(4)));

__device__ __forceinline__ float sigmf(float x){ return 1.f/(1.f+expf(-x)); }

// sc1 (coherence-point) primitives: RELAXED agent-scope atomics, no cache-wide fences
__device__ __forceinline__ unsigned long long ld_cc8(const unsigned long long* p){
    return __hip_atomic_load(p, __ATOMIC_RELAXED, __HIP_MEMORY_SCOPE_AGENT);
}
__device__ __forceinline__ void st_cc8(_Float16* p, unsigned long long v){
    __hip_atomic_store((unsigned long long*)p, v, __ATOMIC_RELAXED, __HIP_MEMORY_SCOPE_AGENT);
}
__device__ __forceinline__ float ld_cc4(const float* p){
    return __hip_atomic_load(p, __ATOMIC_RELAXED, __HIP_MEMORY_SCOPE_AGENT);
}
__device__ __forceinline__ void st_cc4(float* p, float v){
    __hip_atomic_store(p, v, __ATOMIC_RELAXED, __HIP_MEMORY_SCOPE_AGENT);
}

// group-local all-to-all barrier (one hop, fence-free; proven r8-r22)
__device__ __forceinline__ void gbarA(int* slots, int grp, int ub, int seq)
{
    __syncthreads();
    if (threadIdx.x == 0)
        __hip_atomic_store(slots + (grp*BPG + ub)*SLOTP, seq,
                           __ATOMIC_RELAXED, __HIP_MEMORY_SCOPE_AGENT);
    if (threadIdx.x < BPG){
        int* s = slots + (grp*BPG + threadIdx.x)*SLOTP;
        while (__hip_atomic_load(s, __ATOMIC_RELAXED, __HIP_MEMORY_SCOPE_AGENT) < seq)
            __builtin_amdgcn_s_sleep(1);
    }
    asm volatile("" ::: "memory");
    __syncthreads();
}

// wave-local h pack (r20-proven)
__device__ __forceinline__ void pack_store_h(
    _Float16* hF, int buf, int grp, int u0, int w, int lane, float hval)
{
    union { _Float16 f; unsigned short s; } cv;
    cv.f = (_Float16)hval;
    unsigned int h2 = cv.s;
    int base = lane & 15;
    unsigned int x0 = (unsigned int)__shfl((int)h2, base +  0, 64);
    unsigned int x1 = (unsigned int)__shfl((int)h2, base + 16, 64);
    unsigned int x2 = (unsigned int)__shfl((int)h2, base + 32, 64);
    unsigned int x3 = (unsigned int)__shfl((int)h2, base + 48, 64);
    if (lane < 16){
        unsigned long long v = (unsigned long long)(x0 & 0xFFFFu)
                             | ((unsigned long long)(x1 & 0xFFFFu) << 16)
                             | ((unsigned long long)(x2 & 0xFFFFu) << 32)
                             | ((unsigned long long)(x3 & 0xFFFFu) << 48);
        st_cc8(hF + ((size_t)(buf*GRP + grp)*GBATCH + lane)*512 + u0 + w*4, v);
    }
}

// ---------------- k_mega: blocks 0..99 = LSTM, 100..355 = xg workers (r22 verbatim) ----------------
__global__ __launch_bounds__(320, 1) void k_mega(
    const int* __restrict__ sent, const float* __restrict__ table,
    const float* __restrict__ Wih, const float* __restrict__ b_ih, const float* __restrict__ b_hh,
    _Float16* __restrict__ hF, float* __restrict__ hqB, float* __restrict__ xgT,
    const float* __restrict__ Whh, const float* __restrict__ h0, const float* __restrict__ c0,
    const int* __restrict__ lens, int* __restrict__ slots, int* __restrict__ xgdone)
{
    __shared__ __align__(16) char smem[102400];

    int tid = threadIdx.x, bid = blockIdx.x;
    int w = tid >> 6, lane = tid & 63;

    if (bid >= NBLK){
        _Float16* Sh  = (_Float16*)smem;                 // [64*KPADX] = 41984 B
        int*      sidx= (int*)(smem + 41984);            // [TCH][64]
        int xb = bid - NBLK;
        int tc = xb >> 5;                 // 0..7
        int n0 = (xb & 31) * 64;
        int rA = lane & 15, kb = lane >> 4;

        for (int i = tid; i < TCH*64; i += 320){
            int tt = i >> 6, b = i & 63;
            sidx[tt*64 + b] = sent[b*SEQL + tc*TCH + tt];
        }
        for (int i = tid; i < 64*75; i += 320){
            int n = i / 75, c4 = i - (i/75)*75;
            float4 v = {0.f,0.f,0.f,0.f};
            if (n0 + n < 2000)
                v = *(const float4*)(Wih + (size_t)(n0+n)*300 + c4*4);
            _Float16* dst = &Sh[n*KPADX + c4*4];
            dst[0]=(_Float16)v.x; dst[1]=(_Float16)v.y; dst[2]=(_Float16)v.z; dst[3]=(_Float16)v.w;
        }
        for (int i = tid; i < 64*20; i += 320){   // zero pad k 300..319
            int n = i / 20, k = 300 + (i - (i/20)*20);
            Sh[n*KPADX + k] = (_Float16)0.f;
        }
        __syncthreads();
        half8 areg[10];
        float biasr[4];
        if (w < 4){
            #pragma unroll
            for (int ks = 0; ks < 10; ++ks)
                areg[ks] = *(const half8*)&Sh[(w*16 + rA)*KPADX + ks*32 + kb*8];
            #pragma unroll
            for (int r = 0; r < 4; ++r){
                int n = n0 + w*16 + kb*4 + r;
                biasr[r] = (n < 2000) ? b_ih[n] + b_hh[n] : 0.f;
            }
        }
        __syncthreads();   // all A reads done before B overwrites Sh

        for (int tt = 0; tt < TCH; ++tt){
            for (int i = tid; i < 64*75; i += 320){
                int m = i / 75, c4 = i - (i/75)*75;
                float4 v = *(const float4*)(table + (size_t)sidx[tt*64 + m]*300 + c4*4);
                _Float16* dst = &Sh[m*KPADX + c4*4];
                dst[0]=(_Float16)v.x; dst[1]=(_Float16)v.y; dst[2]=(_Float16)v.z; dst[3]=(_Float16)v.w;
            }
            for (int i = tid; i < 64*20; i += 320){
                int m = i / 20, k = 300 + (i - (i/20)*20);
                Sh[m*KPADX + k] = (_Float16)0.f;
            }
            __syncthreads();

            if (w < 4){
                f32x4 acc[4] = {};
                #pragma unroll
                for (int ks = 0; ks < 10; ++ks){
                    #pragma unroll
                    for (int mc = 0; mc < 4; ++mc){
                        half8 bf = *(const half8*)&Sh[(mc*16 + rA)*KPADX + ks*32 + kb*8];
                        acc[mc] = __builtin_amdgcn_mfma_f32_16x16x32_f16(areg[ks], bf, acc[mc], 0, 0, 0);
                    }
                }
                #pragma unroll
                for (int r = 0; r < 4; ++r){
                    int n = n0 + w*16 + kb*4 + r;
                    if (n < 2000){
                        #pragma unroll
                        for (int mc = 0; mc < 4; ++mc)
                            st_cc4(xgT + (size_t)n*MCOL + (tc*TCH+tt)*64 + mc*16 + rA,
                                   acc[mc][r] + biasr[r]);
                    }
                }
            }
            __syncthreads();
        }
        if (tid == 0)
            __hip_atomic_fetch_add(xgdone + tc*SLOTP, 1,
                                   __ATOMIC_RELAXED, __HIP_MEMORY_SCOPE_AGENT);
        return;
    }

    // ======== LSTM (r22 verbatim) ========
    _Float16* Wl  = (_Float16*)smem;                 // [80*512] swizzled, 81920 B
    float*    gl  = (float*)(smem + 81920);          // [4*80*16], 20480 B

    int grp = bid / BPG, ub = bid - grp*BPG;
    int u0  = ub * UPB8;

    int pb  = tid & 15, puu = tid >> 4;        // puu 0..19
    int pu  = u0 + puu;
    int gb  = grp*GBATCH + pb;                 // global batch row
    float cprev = c0[gb*HIDD + pu];
    float hprev = h0[gb*HIDD + pu];
    int   mylen = lens[gb];

    for (int i = tid; i < 80*512; i += 320){
        int m = i >> 9, k = i & 511;
        int g = m / UPB8, uu = m - g*UPB8;
        float v = (k < HIDD) ? Whh[(size_t)(g*HIDD + u0 + uu)*HIDD + k] : 0.f;
        int off = (i*2) ^ ((m & 7) << 4);
        *(_Float16*)((char*)Wl + off) = (_Float16)v;
    }
    pack_store_h(hF, 1, grp, u0, w, lane, hprev);
    if (ub == 0 && tid >= 128 && tid < 224){   // zero k-pad 500..511, both buffers
        int j = tid - 128;
        int buf = j / 48, r = j - buf*48;
        int b = r / 3, q = r - (r/3)*3;
        st_cc8(hF + ((size_t)(buf*GRP + grp)*GBATCH + b)*512 + 500 + q*4, 0ULL);
    }
    gbarA(slots, grp, ub, 1);

    const int mA = lane & 15, kb = lane >> 4;

    for (int t = 0; t < SEQL; ++t){
        if ((t & 3) == 0){
            if (tid == 0){
                const int* f = xgdone + (t >> 2)*SLOTP;
                while (__hip_atomic_load(f, __ATOMIC_RELAXED, __HIP_MEMORY_SCOPE_AGENT) < 32)
                    __builtin_amdgcn_s_sleep(1);
            }
            asm volatile("" ::: "memory");
            __syncthreads();
        }

        const _Float16* hsrc = hF + (size_t)(((t&1)^1)*GRP + grp)*GBATCH*512;

        float xgv[4];
        #pragma unroll
        for (int g = 0; g < 4; ++g)
            xgv[g] = ld_cc4(xgT + (size_t)(g*HIDD + pu)*MCOL + t*64 + gb);

        if (w < 4){
            half8 bf[4];
            #pragma unroll
            for (int ks4 = 0; ks4 < 4; ++ks4){
                int ke = (w*4 + ks4)*32 + kb*8;            // f16 element offset in row
                const unsigned long long* p =
                    (const unsigned long long*)(hsrc + mA*512 + ke);
                union { unsigned long long q[2]; half8 h; } u;
                u.q[0] = ld_cc8(p);
                u.q[1] = ld_cc8(p + 1);
                bf[ks4] = u.h;
            }
            f32x4 acc[5] = {};
            #pragma unroll
            for (int rt = 0; rt < 5; ++rt){
                #pragma unroll
                for (int ks4 = 0; ks4 < 4; ++ks4){
                    int kByte = (w*4 + ks4)*64 + kb*16;
                    int m = rt*16 + mA;
                    int aOff = (m*1024 + kByte) ^ ((m & 7) << 4);
                    half8 af = *(const half8*)((const char*)Wl + aOff);
                    acc[rt] = __builtin_amdgcn_mfma_f32_16x16x32_f16(af, bf[ks4], acc[rt], 0, 0, 0);
                }
            }
            #pragma unroll
            for (int rt = 0; rt < 5; ++rt)
                #pragma unroll
                for (int r = 0; r < 4; ++r)
                    gl[(w*80 + rt*16 + kb*4 + r)*16 + mA] = acc[rt][r];
        }
        __syncthreads();

        {
            float g4[4];
            #pragma unroll
            for (int g = 0; g < 4; ++g){
                int row = g*UPB8 + puu;
                float s = gl[(0*80 + row)*16 + pb] + gl[(1*80 + row)*16 + pb]
                        + gl[(2*80 + row)*16 + pb] + gl[(3*80 + row)*16 + pb];
                s += xgv[g];
                g4[g] = s;
            }
            float si = sigmf(g4[0]), sf = sigmf(g4[1]);
            float tg = tanhf(g4[2]), so = sigmf(g4[3]);
            float cn = sf*cprev + si*tg;
            float hn = so*tanhf(cn);
            if (t < mylen){ cprev = cn; hprev = hn; }
        }
        if (t == SEQL-1){
            hqB[(size_t)gb*512 + pu] = hprev;   // final h, [b][512] f32
        } else {
            pack_store_h(hF, t & 1, grp, u0, w, lane, hprev);
            gbarA(slots, grp, ub, t + 2);
        }
    }
}

// ---------------- k_pair5: qp + ip/jp + pair MFMA (B-operands register-hoisted) + epilogue ----------------
__global__ __launch_bounds__(256, 1) void k_pair5(
    const float* __restrict__ hqB, const float* __restrict__ conv,
    const float* __restrict__ g1w, const float* __restrict__ g1b,
    const float* __restrict__ g2w, const float* __restrict__ g2b,
    const float* __restrict__ f1w, const float* __restrict__ f1b,
    const float* __restrict__ f2w, const float* __restrict__ f2b,
    float* __restrict__ part, int* __restrict__ pcnt, float* __restrict__ out)
{
    __shared__ __align__(16) char smem[SM_TOTAL];
    float*    convl = (float*)(smem + SM_CONV);
    float*    g1ij  = (float*)(smem + SM_G1IJ);
    float*    hb    = (float*)(smem + SM_HB);
    float*    qpl   = (float*)(smem + SM_QPL);
    _Float16* jpl   = (_Float16*)(smem + SM_JPL);
    _Float16* basel = (_Float16*)(smem + SM_BASEL);
    _Float16* g2h   = (_Float16*)(smem + SM_G2H);

    int b  = blockIdx.x >> 2;
    int ic = blockIdx.x & 3;
    int tid = threadIdx.x;
    int w = tid >> 6, lane = tid & 63;
    int ncol = lane & 15, kb = lane >> 4;

    // phase 1: stage shared inputs
    for (int i = tid; i < 24*64; i += 256)
        convl[i] = conv[(size_t)b*24*64 + i];
    for (int i = tid; i < 100*48; i += 256){
        int n = i/48, c = i - n*48;
        g1ij[n*48 + c] = g1w[(size_t)n*548 + 500 + c];
    }
    for (int i = tid; i < 512; i += 256) hb[i] = hqB[(size_t)b*512 + i];
    for (int i = tid; i < 112*136; i += 256){
        int n = i/136, k = i - n*136;
        g2h[n*136 + k] = (n < 100 && k < 100) ? (_Float16)g2w[n*GHID + k] : (_Float16)0.f;
    }
    __syncthreads();

    // phase 2: qpl (f32) + jpl (f16) for all 64 j's
    if (tid < 100){
        const float4* wr = (const float4*)(g1w + (size_t)tid*548);
        float s = g1b[tid];
        #pragma unroll 5
        for (int k4 = 0; k4 < 125; ++k4){
            float4 v = wr[k4];
            s += v.x*hb[k4*4] + v.y*hb[k4*4+1] + v.z*hb[k4*4+2] + v.w*hb[k4*4+3];
        }
        qpl[tid] = s;
    }
    for (int i = tid; i < NOBJ*100; i += 256){
        int o = i / 100, n = i - (i/100)*100;
        float sj = 0.f;
        #pragma unroll
        for (int c = 0; c < 24; ++c) sj += convl[c*64 + o] * g1ij[n*48 + c];
        jpl[o*136 + n] = (_Float16)sj;
    }
    for (int i = tid; i < NOBJ*36; i += 256)
        jpl[(i/36)*136 + 100 + (i - (i/36)*36)] = (_Float16)0.f;
    __syncthreads();   // qpl ready

    // phase 3: basel = f16(qpl + ip) for own 16 i-rows
    for (int i = tid; i < 16*136; i += 256){
        int il = i / 136, k = i - il*136;
        float v = 0.f;
        if (k < 100){
            float si = 0.f;
            int o = ic*16 + il;
            #pragma unroll
            for (int c = 0; c < 24; ++c) si += convl[c*64 + o] * g1ij[k*48 + 24 + c];
            v = qpl[k] + si;
        }
        basel[il*136 + k] = (_Float16)v;
    }
    float gb7[7];
    #pragma unroll
    for (int nt = 0; nt < 7; ++nt){
        int n = nt*16 + ncol;
        gb7[nt] = (n < 100) ? g2b[n] : 0.f;
    }
    __syncthreads();

    // phase 4: hoist g2h B-fragments (28 half8, invariant over it/jc) into registers
    half8 bfh[28];
    #pragma unroll
    for (int nt = 0; nt < 7; ++nt)
        #pragma unroll
        for (int ks = 0; ks < 4; ++ks)
            bfh[nt*4 + ks] = *(const half8*)&g2h[(nt*16 + ncol)*136 + ks*32 + kb*8];

    f32x4 sacc[7] = {};
    #pragma unroll 1
    for (int jc = 0; jc < 4; ++jc){
        int jrow = jc*16 + ncol;
        half8 jvh[4];
        #pragma unroll
        for (int ks = 0; ks < 4; ++ks)
            jvh[ks] = *(const half8*)&jpl[jrow*136 + ks*32 + kb*8];
        #pragma unroll 1
        for (int it = 0; it < 4; ++it){
            int il = w*4 + it;
            f32x4 acc[7] = {};
            #pragma unroll
            for (int ks = 0; ks < 4; ++ks){
                half8 bv = *(const half8*)&basel[il*136 + ks*32 + kb*8];
                half8 af;
                #pragma unroll
                for (int e = 0; e < 8; ++e){
                    _Float16 s = jvh[ks][e] + bv[e];
                    af[e] = (s > (_Float16)0.f) ? s : (_Float16)0.f;
                }
                #pragma unroll
                for (int nt = 0; nt < 7; ++nt)
                    acc[nt] = __builtin_amdgcn_mfma_f32_16x16x32_f16(af, bfh[nt*4 + ks], acc[nt], 0, 0, 0);
            }
            #pragma unroll
            for (int nt = 0; nt < 7; ++nt)
                #pragma unroll
                for (int r = 0; r < 4; ++r)
                    sacc[nt][r] += fmaxf(acc[nt][r] + gb7[nt], 0.f);
        }
    }
    // staging region dead from here -> epilogue arrays alias it
    float* redx = (float*)(smem + SM_REDX);
    #pragma unroll
    for (int nt = 0; nt < 7; ++nt){
        float s = sacc[nt][0] + sacc[nt][1] + sacc[nt][2] + sacc[nt][3];
        s += __shfl_xor(s, 16);
        s += __shfl_xor(s, 32);
        if (lane < 16) redx[w*112 + nt*16 + lane] = s;
    }
    __syncthreads();
    if (tid < 100){
        float p = redx[0*112+tid] + redx[1*112+tid] + redx[2*112+tid] + redx[3*112+tid];
        st_cc4(part + (size_t)(b*4 + ic)*GHID + tid, p);
    }
    __syncthreads();   // drain part stores before counter RMW

    int* lastf = (int*)(smem + SM_LASTF);
    if (tid == 0){
        int old = __hip_atomic_fetch_add(pcnt + b*SLOTP, 1,
                                         __ATOMIC_RELAXED, __HIP_MEMORY_SCOPE_AGENT);
        *lastf = (old == 3);
    }
    __syncthreads();
    if (!*lastf) return;

    // ---- epilogue (last block for this b) ----
    float* gs  = (float*)(smem + SM_GS);
    float* fh  = (float*)(smem + SM_FH);
    float* lg  = (float*)(smem + SM_LG);
    float* red = (float*)(smem + SM_RED);
    float* red2= (float*)(smem + SM_RED2);

    if (tid < 100){
        float s = 0.f;
        #pragma unroll
        for (int ic2 = 0; ic2 < 4; ++ic2)
            s += ld_cc4(part + (size_t)(b*4 + ic2)*GHID + tid);
        gs[tid] = s;
    }
    __syncthreads();
    if (tid < 100){
        const float4* wr = (const float4*)(f1w + (size_t)tid*GHID);
        float s = f1b[tid];
        #pragma unroll 5
        for (int k4 = 0; k4 < 25; ++k4){
            float4 v = wr[k4];
            s += v.x*gs[k4*4] + v.y*gs[k4*4+1] + v.z*gs[k4*4+2] + v.w*gs[k4*4+3];
        }
        fh[tid] = fmaxf(s, 0.f);
    }
    __syncthreads();
    for (int n = tid; n < ANSN; n += 256){
        const float4* wr = (const float4*)(f2w + (size_t)n*GHID);
        float s = f2b[n];
        #pragma unroll 5
        for (int k4 = 0; k4 < 25; ++k4){
            float4 v = wr[k4];
            s += v.x*fh[k4*4] + v.y*fh[k4*4+1] + v.z*fh[k4*4+2] + v.w*fh[k4*4+3];
        }
        lg[n] = fmaxf(s, 0.f);
    }
    __syncthreads();
    float mx = -1e30f;
    for (int n = tid; n < ANSN; n += 256) mx = fmaxf(mx, lg[n]);
    #pragma unroll
    for (int off = 32; off > 0; off >>= 1) mx = fmaxf(mx, __shfl_xor(mx, off));
    if ((tid & 63) == 0) red[tid >> 6] = mx;
    __syncthreads();
    mx = fmaxf(fmaxf(red[0], red[1]), fmaxf(red[2], red[3]));
    float se = 0.f;
    for (int n = tid; n < ANSN; n += 256) se += expf(lg[n]-mx);
    #pragma unroll
    for (int off = 32; off > 0; off >>= 1) se += __shfl_xor(se, off);
    if ((tid & 63) == 0) red2[tid >> 6] = se;
    __syncthreads();
    se = red2[0]+red2[1]+red2[2]+red2[3];
    float lse = logf(se);
    for (int n = tid; n < ANSN; n += 256) out[(size_t)b*ANSN + n] = lg[n] - mx - lse;
}

extern "C" void kernel_launch(void* const* d_in, const int* in_sizes, int n_in,
                              void* d_out, int out_size, void* d_ws, size_t ws_size,
                              hipStream_t stream)
{
    const int*   sent  = (const int*)  d_in[0];
    const float* conv  = (const float*)d_in[1];
    const int*   lens  = (const int*)  d_in[2];
    const float* table = (const float*)d_in[3];
    const float* W_ih  = (const float*)d_in[4];
    const float* W_hh  = (const float*)d_in[5];
    const float* b_ih  = (const float*)d_in[6];
    const float* b_hh  = (const float*)d_in[7];
    const float* h0    = (const float*)d_in[8];
    const float* c0    = (const float*)d_in[9];
    const float* g1_w  = (const float*)d_in[10];
    const float* g1_b  = (const float*)d_in[11];
    const float* g2_w  = (const float*)d_in[12];
    const float* g2_b  = (const float*)d_in[13];
    const float* f1_w  = (const float*)d_in[14];
    const float* f1_b  = (const float*)d_in[15];
    const float* f2_w  = (const float*)d_in[16];
    const float* f2_b  = (const float*)d_in[17];
    float* out = (float*)d_out;

    float* ws    = (float*)d_ws;
    int*   slots = (int*)d_ws;                          // [0, 3200) ints
    int*   xgdone= (int*)d_ws + NBLK*SLOTP;             // [3200, 3456) ints
    int*   pcnt  = (int*)d_ws + NBLK*SLOTP + 8*SLOTP;   // [3456, 5504) ints
    _Float16* hF = (_Float16*)(ws + 16384);             // 2*4*16*512 f16 = 128 KB
    float* hqB  = ws + 16384 + 32768;                   // 64*512 f32
    float* xgT  = hqB + 64*512;                         // 2000*2048 f32
    float* part = xgT + (size_t)4*HIDD*MCOL;            // 256*100

    // 0. zero barrier slots + xg flags + pair counters (deterministic across replays)
    hipMemsetAsync(slots, 0, (NBLK + 8 + BATCH)*SLOTP*sizeof(int), stream);

    // 1. fused xg + LSTM: 356 blocks (100 lstm + 256 xg workers)
    k_mega<<<NBLK + NXG, 320, 0, stream>>>(sent, table, W_ih, b_ih, b_hh,
                                           hF, hqB, xgT, W_hh, h0, c0, lens,
                                           slots, xgdone);

    // 2. fused qp/ipjp + pair MFMA + final epilogue (256 blocks)
    k_pair5<<<BATCH*4, 256, 0, stream>>>(hqB, conv, g1_w, g1_b, g2_w, g2_b,
                                         f1_w, f1_b, f2_w, f2_b, part, pcnt, out);
}